// Round 3
// baseline (11288.795 us; speedup 1.0000x reference)
//
#include <hip/hip_runtime.h>
#include <hip/hip_bf16.h>

#define B_ 32
#define L_ 4096
#define DIN 16
#define H_ 128
#define N2_ 32
#define NL_ 4
#define DOUT_ 8
#define CL 64   // chunk length
#define NC 64   // chunks per sequence (L/CL)

// ---- workspace layout (in floats) ----
#define OFF_U   ((size_t)0)
#define SZ_U    ((size_t)B_*H_*L_)            // activations, [b][h][l]
#define OFF_Y   (OFF_U + SZ_U)
#define SZ_Y    SZ_U                          // post-GELU SSM output
#define OFF_T1  (OFF_Y + SZ_Y)
#define SZ_T1   ((size_t)NL_*H_*64*64)        // [l][h][e][np]  w^e, e=0..63 (np = 2n+part)
#define OFF_T2  (OFF_T1 + SZ_T1)
#define SZ_T2   ((size_t)NL_*H_*64*68)        // [l][h][np][tau] w^{tau+1}, row pad 68
#define OFF_K   (OFF_T2 + SZ_T2)
#define SZ_K    ((size_t)NL_*H_*64)           // k[h][s], s<64
#define OFF_CP  (OFF_K + SZ_K)
#define SZ_CP   ((size_t)NL_*H_*64)           // C' [l][h][n][2]
#define OFF_W64 (OFF_CP + SZ_CP)
#define SZ_W64  ((size_t)NL_*H_*64)           // w^64 [l][h][n][2]
#define OFF_PL  (OFF_W64 + SZ_W64)
#define SZ_PL   ((size_t)B_*H_)

// ---------------------------------------------------------------------------
// P0a: per (layer,h,n) compute w=exp(dtA), C'=(C)*(w-1)/A, power tables
// ---------------------------------------------------------------------------
__global__ __launch_bounds__(256) void prep_tables(const float* log_dt, const float* log_A_real,
                                                   const float* A_imag, const float* C_re,
                                                   const float* C_im, float* ws) {
    int idx = blockIdx.x * 256 + threadIdx.x;        // flat (l,h,n)
    if (idx >= NL_ * H_ * N2_) return;
    int n  = idx & 31;
    int lh = idx >> 5;                               // l*128 + h

    float dt  = expf(log_dt[lh]);
    float Are = -expf(log_A_real[idx]);
    float Aim = A_imag[idx];
    float dre = Are * dt, dim = Aim * dt;
    float er  = expf(dre);
    float wre = er * cosf(dim), wim = er * sinf(dim);
    // (w-1)/A
    float nre = wre - 1.0f, nim = wim;
    float den = Are * Are + Aim * Aim;
    float qre = (nre * Are + nim * Aim) / den;
    float qim = (nim * Are - nre * Aim) / den;
    float cre = C_re[idx], cim = C_im[idx];
    float Cpre = cre * qre - cim * qim;
    float Cpim = cre * qim + cim * qre;

    float* t1  = ws + OFF_T1  + (size_t)lh * 64 * 64;
    float* t2  = ws + OFF_T2  + (size_t)lh * 64 * 68;
    float* cp  = ws + OFF_CP  + (size_t)lh * 64;
    float* w64 = ws + OFF_W64 + (size_t)lh * 64;
    cp[2 * n] = Cpre; cp[2 * n + 1] = Cpim;

    float pr = 1.0f, pi = 0.0f;                      // w^0
    for (int e = 0; e < 64; ++e) {
        t1[e * 64 + 2 * n]     = pr;                 // w^e
        t1[e * 64 + 2 * n + 1] = pi;
        float npr = pr * wre - pi * wim;
        float npi = pr * wim + pi * wre;
        pr = npr; pi = npi;                          // now w^{e+1}
        t2[(2 * n) * 68 + e]     = pr;               // w^{tau+1} at tau=e
        t2[(2 * n + 1) * 68 + e] = pi;
    }
    w64[2 * n] = pr; w64[2 * n + 1] = pi;            // w^64
}

// ---------------------------------------------------------------------------
// P0b: k[h][s] = 2*Re( sum_n C'_n w_n^s ),  s = 0..63 (local conv taps)
// ---------------------------------------------------------------------------
__global__ __launch_bounds__(256) void compute_k(float* ws) {
    int idx = blockIdx.x * 256 + threadIdx.x;        // (l,h,s)
    if (idx >= NL_ * H_ * 64) return;
    int s  = idx & 63;
    int lh = idx >> 6;
    const float* t1 = ws + OFF_T1 + (size_t)lh * 64 * 64 + (size_t)s * 64;
    const float* cp = ws + OFF_CP + (size_t)lh * 64;
    float acc = 0.0f;
    #pragma unroll
    for (int n = 0; n < 32; ++n)
        acc += cp[2 * n] * t1[2 * n] - cp[2 * n + 1] * t1[2 * n + 1];
    ws[OFF_K + (size_t)lh * 64 + s] = 2.0f * acc;
}

// ---------------------------------------------------------------------------
// Encoder: u[b][h][l] = enc_b[h] + sum_d x[b][l][d]*enc_w[h][d]
// ---------------------------------------------------------------------------
__global__ __launch_bounds__(256) void encoder_kernel(const float* x, const float* enc_w,
                                                      const float* enc_b, float* ws) {
    __shared__ float wlds[H_ * DIN];
    __shared__ float blds[H_];
    int t  = threadIdx.x;
    int b  = blockIdx.x >> 4;                        // 16 l-tiles of 256
    int l0 = (blockIdx.x & 15) * 256;
    for (int i = t; i < H_ * DIN; i += 256) wlds[i] = enc_w[i];
    if (t < H_) blds[t] = enc_b[t];
    float xr[16];
    const float* xp = x + ((size_t)b * L_ + l0 + t) * DIN;
    #pragma unroll
    for (int d = 0; d < 16; ++d) xr[d] = xp[d];
    __syncthreads();
    float* u = ws + OFF_U + (size_t)b * H_ * L_ + l0 + t;
    for (int h = 0; h < H_; ++h) {
        float acc = blds[h];
        #pragma unroll
        for (int d = 0; d < 16; ++d) acc += xr[d] * wlds[h * 16 + d];
        u[(size_t)h * L_] = acc;
    }
}

// ---------------------------------------------------------------------------
// S4D chunked scan, fused P1+P2+P3, one block per (b,h).
//   y[t] = GELU( conv(k, z)[t] + D*z[t] )
// Round-3: single reused tab[64] (VGPR<=128 w/ launch_bounds(256,4)),
// 4/8-way split accumulators, P2 unroll-8 prefetch.
// ---------------------------------------------------------------------------
__global__ __launch_bounds__(256, 4) void s4d_scan(const float* Dp, float* ws, int layer) {
    __shared__ float z_lds[L_];          // 16 KB
    __shared__ float eg_lds[NC * 64];    // 16 KB: E then g' in-place
    __shared__ float k_ext[128];         // zero-padded taps

    int t    = threadIdx.x;
    int b    = blockIdx.x >> 7;
    int h    = blockIdx.x & 127;
    int lh   = layer * H_ + h;
    int wv   = t >> 6;                   // wave 0..3
    int lane = t & 63;

    const float* u = ws + OFF_U + ((size_t)b * H_ + h) * L_;
    for (int i = t; i < L_ / 4; i += 256)
        ((float4*)z_lds)[i] = ((const float4*)u)[i];
    if (t < 64) k_ext[t] = 0.0f;
    else if (t < 128) k_ext[t] = ws[OFF_K + (size_t)lh * 64 + (t - 64)];

    float tab[64];                       // t1 column now; reloaded as t2 later
    {
        const float* t1 = ws + OFF_T1 + (size_t)lh * 4096 + lane;
        #pragma unroll
        for (int e = 0; e < 64; ++e) tab[e] = t1[e * 64];
    }
    __syncthreads();

    // ---- P1: chunk-local end states E_c[np] = sum_s w^{63-s} z[c*64+s]
    #pragma unroll 1
    for (int j = 0; j < 16; ++j) {
        int c = wv * 16 + j;
        float a0 = 0.f, a1 = 0.f, a2 = 0.f, a3 = 0.f;
        #pragma unroll
        for (int m = 0; m < 16; ++m) {
            float4 zv = *(const float4*)&z_lds[c * 64 + 60 - 4 * m];
            a0 = fmaf(tab[4 * m + 0], zv.w, a0);   // z[63-e]
            a1 = fmaf(tab[4 * m + 1], zv.z, a1);
            a2 = fmaf(tab[4 * m + 2], zv.y, a2);
            a3 = fmaf(tab[4 * m + 3], zv.x, a3);
        }
        eg_lds[c * 64 + lane] = (a0 + a1) + (a2 + a3);
    }
    __syncthreads();

    // ---- P2: scan S_{c+1} = w^64 * S_c + E_c; write g' = 2*C'*S_c (sign-folded)
    if (t < 32) {
        int n = t;
        const float* cp  = ws + OFF_CP  + (size_t)lh * 64;
        const float* w64 = ws + OFF_W64 + (size_t)lh * 64;
        float cre = cp[2 * n], cim = cp[2 * n + 1];
        float wr  = w64[2 * n], wi = w64[2 * n + 1];
        float sre = 0.0f, sim = 0.0f;
        #pragma unroll 1
        for (int c8 = 0; c8 < NC; c8 += 8) {
            float er[8], ei[8];
            #pragma unroll
            for (int k = 0; k < 8; ++k) {          // batch-issue independent reads
                er[k] = eg_lds[(c8 + k) * 64 + 2 * n];
                ei[k] = eg_lds[(c8 + k) * 64 + 2 * n + 1];
            }
            #pragma unroll
            for (int k = 0; k < 8; ++k) {
                eg_lds[(c8 + k) * 64 + 2 * n]     = 2.0f * (cre * sre - cim * sim);
                eg_lds[(c8 + k) * 64 + 2 * n + 1] = -2.0f * (cre * sim + cim * sre);
                float nr = fmaf(wr, sre, fmaf(-wi, sim, er[k]));
                float ni = fmaf(wr, sim, fmaf(wi, sre, ei[k]));
                sre = nr; sim = ni;
            }
        }
    }
    // reload tab with t2 column (global, independent of P2 -> overlaps on waves 1-3)
    {
        const float* t2 = ws + OFF_T2 + (size_t)lh * 64 * 68 + lane;
        #pragma unroll
        for (int np = 0; np < 64; ++np) tab[np] = t2[np * 68];
    }
    float Dh = Dp[lh];
    __syncthreads();

    // ---- P3: outputs
    float* y = ws + OFF_Y + ((size_t)b * H_ + h) * L_;
    #pragma unroll 1
    for (int j = 0; j < 16; ++j) {
        int c   = wv * 16 + j;
        int tau = lane;
        float zt = z_lds[c * 64 + tau];
        float s0 = 0.f, s1 = 0.f, s2 = 0.f, s3 = 0.f;
        float c0 = Dh * zt, c1 = 0.f, c2 = 0.f, c3 = 0.f;
        // state term: sum_np g'[np] * w^{tau+1}[np]
        #pragma unroll
        for (int m = 0; m < 16; ++m) {
            float4 gv = *(const float4*)&eg_lds[c * 64 + 4 * m];
            s0 = fmaf(gv.x, tab[4 * m + 0], s0);
            s1 = fmaf(gv.y, tab[4 * m + 1], s1);
            s2 = fmaf(gv.z, tab[4 * m + 2], s2);
            s3 = fmaf(gv.w, tab[4 * m + 3], s3);
        }
        // local conv: sum_sigma z[sigma] * k_ext[64 + tau - sigma]
        #pragma unroll
        for (int m = 0; m < 16; ++m) {
            float4 zv = *(const float4*)&z_lds[c * 64 + 4 * m];
            c0 = fmaf(zv.x, k_ext[64 + tau - 4 * m - 0], c0);
            c1 = fmaf(zv.y, k_ext[64 + tau - 4 * m - 1], c1);
            c2 = fmaf(zv.z, k_ext[64 + tau - 4 * m - 2], c2);
            c3 = fmaf(zv.w, k_ext[64 + tau - 4 * m - 3], c3);
        }
        float acc = ((s0 + s1) + (s2 + s3)) + ((c0 + c1) + (c2 + c3));
        float g = 0.5f * acc * (1.0f + erff(acc * 0.70710678118654752f));
        y[c * 64 + tau] = g;
    }
}

// ---------------------------------------------------------------------------
// Channel mix: v = conv_w @ y + conv_b ; GLU ; +residual u ; LayerNorm -> u
// One block = (b, 64 l-positions). fp32 register-tiled GEMM 256x64, K=128.
// ---------------------------------------------------------------------------
__global__ __launch_bounds__(256) void conv_glu_ln(const float* conv_w, const float* conv_b,
                                                   const float* ln_w, const float* ln_b,
                                                   float* ws, int layer) {
    __shared__ float Wlds[16 * 260];     // [k][o], pad 260
    __shared__ float Ylds[16 * 68];      // [k][l], pad 68

    int t    = threadIdx.x;
    int b    = blockIdx.x >> 6;
    int l0   = (blockIdx.x & 63) * 64;
    int ocol = t & 31;
    int lgrp = t >> 5;

    const float* Wg = conv_w + (size_t)layer * 256 * 128;
    const float* yg = ws + OFF_Y + (size_t)b * H_ * L_;

    float acc[8][8];
    #pragma unroll
    for (int j = 0; j < 8; ++j) {
        int o = (j < 4) ? (4 * ocol + j) : (124 + 4 * ocol + j);
        float cb = conv_b[layer * 256 + o];
        #pragma unroll
        for (int i = 0; i < 8; ++i) acc[j][i] = cb;
    }

    for (int k0 = 0; k0 < 128; k0 += 16) {
        __syncthreads();
        {   // stage W tile: [o=t][k0..k0+15]
            const float* wrow = Wg + (size_t)t * 128 + k0;
            float4 a = *(const float4*)(wrow);
            float4 bb = *(const float4*)(wrow + 4);
            float4 cc = *(const float4*)(wrow + 8);
            float4 dd = *(const float4*)(wrow + 12);
            float wv16[16] = {a.x,a.y,a.z,a.w, bb.x,bb.y,bb.z,bb.w,
                              cc.x,cc.y,cc.z,cc.w, dd.x,dd.y,dd.z,dd.w};
            #pragma unroll
            for (int kk = 0; kk < 16; ++kk) Wlds[kk * 260 + t] = wv16[kk];
        }
        {   // stage Y tile
            int kk = t >> 4, l4 = (t & 15) * 4;
            float4 v = *(const float4*)&yg[(size_t)(k0 + kk) * L_ + l0 + l4];
            *(float4*)&Ylds[kk * 68 + l4] = v;
        }
        __syncthreads();
        #pragma unroll
        for (int kk = 0; kk < 16; ++kk) {
            float4 w0 = *(const float4*)&Wlds[kk * 260 + 4 * ocol];
            float4 w1 = *(const float4*)&Wlds[kk * 260 + 4 * ocol + 128];
            float4 y0 = *(const float4*)&Ylds[kk * 68 + lgrp * 8];
            float4 y1 = *(const float4*)&Ylds[kk * 68 + lgrp * 8 + 4];
            float wj[8] = {w0.x, w0.y, w0.z, w0.w, w1.x, w1.y, w1.z, w1.w};
            float yi[8] = {y0.x, y0.y, y0.z, y0.w, y1.x, y1.y, y1.z, y1.w};
            #pragma unroll
            for (int j = 0; j < 8; ++j)
                #pragma unroll
                for (int i = 0; i < 8; ++i)
                    acc[j][i] += wj[j] * yi[i];
        }
    }

    // GLU + residual
    float* ug = ws + OFF_U + (size_t)b * H_ * L_;
    float r[4][8];
    #pragma unroll
    for (int j = 0; j < 4; ++j) {
        int hch = 4 * ocol + j;
        const float* up = ug + (size_t)hch * L_ + l0 + lgrp * 8;
        float4 u0 = *(const float4*)up;
        float4 u1 = *(const float4*)(up + 4);
        float ui[8] = {u0.x, u0.y, u0.z, u0.w, u1.x, u1.y, u1.z, u1.w};
        #pragma unroll
        for (int i = 0; i < 8; ++i) {
            float a = acc[j][i], g = acc[j + 4][i];
            float y2 = a / (1.0f + expf(-g));
            r[j][i] = y2 + ui[i];
        }
    }
    // LayerNorm stats across 128 channels (32 lanes x 4 ch each)
    float mu[8], s2[8];
    #pragma unroll
    for (int i = 0; i < 8; ++i) {
        float s = r[0][i] + r[1][i] + r[2][i] + r[3][i];
        float q = r[0][i] * r[0][i] + r[1][i] * r[1][i] + r[2][i] * r[2][i] + r[3][i] * r[3][i];
        #pragma unroll
        for (int m = 1; m <= 16; m <<= 1) {
            s += __shfl_xor(s, m, 64);
            q += __shfl_xor(q, m, 64);
        }
        mu[i] = s * (1.0f / 128.0f);
        s2[i] = q * (1.0f / 128.0f) - mu[i] * mu[i];
    }
    #pragma unroll
    for (int j = 0; j < 4; ++j) {
        int hch = 4 * ocol + j;
        float lw = ln_w[layer * 128 + hch], lb = ln_b[layer * 128 + hch];
        float o0[4], o1[4];
        #pragma unroll
        for (int i = 0; i < 8; ++i) {
            float rstd = rsqrtf(s2[i] + 1e-5f);
            float v = (r[j][i] - mu[i]) * rstd * lw + lb;
            if (i < 4) o0[i] = v; else o1[i - 4] = v;
        }
        float* up = ug + (size_t)hch * L_ + l0 + lgrp * 8;
        *(float4*)up       = make_float4(o0[0], o0[1], o0[2], o0[3]);
        *(float4*)(up + 4) = make_float4(o1[0], o1[1], o1[2], o1[3]);
    }
}

// ---------------------------------------------------------------------------
// Mean-pool over L per (b,h)
// ---------------------------------------------------------------------------
__global__ __launch_bounds__(256) void pool_kernel(float* ws) {
    int bh = blockIdx.x;
    const float* u = ws + OFF_U + (size_t)bh * L_;
    int t = threadIdx.x;
    float s = 0.0f;
    for (int i = t; i < L_; i += 256) s += u[i];
    #pragma unroll
    for (int m = 1; m <= 32; m <<= 1) s += __shfl_xor(s, m, 64);
    __shared__ float part[4];
    if ((t & 63) == 0) part[t >> 6] = s;
    __syncthreads();
    if (t == 0) ws[OFF_PL + bh] = (part[0] + part[1] + part[2] + part[3]) * (1.0f / L_);
}

// ---------------------------------------------------------------------------
// Decoder: pred[b][o] = sigmoid(pooled[b] . dec_w[o] + dec_b[o])  (f32 out)
// ---------------------------------------------------------------------------
__global__ __launch_bounds__(256) void decode_kernel(const float* dec_w, const float* dec_b,
                                                     const float* ws, float* out) {
    int t = threadIdx.x;
    int b = t >> 3, o = t & 7;
    const float* p = ws + OFF_PL + b * 128;
    float acc = dec_b[o];
    for (int h = 0; h < 128; ++h) acc += p[h] * dec_w[o * 128 + h];
    out[t] = 1.0f / (1.0f + expf(-acc));
}

// ---------------------------------------------------------------------------
// emb output: out[b][l][h] = u[b][h][l]  (f32, LDS tile transpose)
// ---------------------------------------------------------------------------
__global__ __launch_bounds__(256) void emb_out(const float* uws, float* out) {
    __shared__ float T[32 * 65];
    int t  = threadIdx.x;
    int bi = blockIdx.x;
    int lt = bi & 63;
    int ht = (bi >> 6) & 3;
    int b  = bi >> 8;
    int l0 = lt * 64, h0 = ht * 32;
    const float* u = uws + ((size_t)b * H_ + h0) * L_ + l0;
    #pragma unroll
    for (int p = 0; p < 8; ++p) {
        int rr = p * 4 + (t >> 6), cc = t & 63;
        T[rr * 65 + cc] = u[(size_t)rr * L_ + cc];
    }
    __syncthreads();
    #pragma unroll
    for (int q = 0; q < 8; ++q) {
        int hh = t & 31, ll = (t >> 5) + q * 8;
        out[((size_t)(b * L_) + l0 + ll) * H_ + h0 + hh] = T[hh * 65 + ll];
    }
}

// ---------------------------------------------------------------------------
extern "C" void kernel_launch(void* const* d_in, const int* in_sizes, int n_in,
                              void* d_out, int out_size, void* d_ws, size_t ws_size,
                              hipStream_t stream) {
    const float* x          = (const float*)d_in[0];
    // d_in[1] = times (unused by reference)
    const float* enc_w      = (const float*)d_in[2];
    const float* enc_b      = (const float*)d_in[3];
    const float* log_dt     = (const float*)d_in[4];
    const float* log_A_real = (const float*)d_in[5];
    const float* A_imag     = (const float*)d_in[6];
    const float* C_re       = (const float*)d_in[7];
    const float* C_im       = (const float*)d_in[8];
    const float* Dp         = (const float*)d_in[9];
    const float* conv_w     = (const float*)d_in[10];
    const float* conv_b     = (const float*)d_in[11];
    const float* ln_w       = (const float*)d_in[12];
    const float* ln_b       = (const float*)d_in[13];
    const float* dec_w      = (const float*)d_in[14];
    const float* dec_b      = (const float*)d_in[15];
    float* ws = (float*)d_ws;
    float* out = (float*)d_out;

    prep_tables<<<(NL_ * H_ * N2_ + 255) / 256, 256, 0, stream>>>(log_dt, log_A_real, A_imag,
                                                                  C_re, C_im, ws);
    compute_k<<<(NL_ * H_ * 64 + 255) / 256, 256, 0, stream>>>(ws);
    encoder_kernel<<<B_ * (L_ / 256), 256, 0, stream>>>(x, enc_w, enc_b, ws);
    for (int l = 0; l < NL_; ++l) {
        s4d_scan<<<B_ * H_, 256, 0, stream>>>(Dp, ws, l);
        conv_glu_ln<<<B_ * (L_ / 64), 256, 0, stream>>>(conv_w, conv_b, ln_w, ln_b, ws, l);
    }
    pool_kernel<<<B_ * H_, 256, 0, stream>>>(ws);
    decode_kernel<<<1, 256, 0, stream>>>(dec_w, dec_b, ws, out);
    emb_out<<<B_ * 4 * 64, 256, 0, stream>>>(ws + OFF_U, out + 256);
}

// Round 4
// 958.078 us; speedup vs baseline: 11.7828x; 11.7828x over previous
//
#include <hip/hip_runtime.h>
#include <hip/hip_bf16.h>

#define B_ 32
#define L_ 4096
#define DIN 16
#define H_ 128
#define N2_ 32
#define NL_ 4
#define DOUT_ 8
#define CL 64   // chunk length
#define NC 64   // chunks per sequence (L/CL)

// ---- workspace layout (in floats) ----
#define OFF_U   ((size_t)0)
#define SZ_U    ((size_t)B_*H_*L_)            // activations, [b][h][l]
#define OFF_Y   (OFF_U + SZ_U)
#define SZ_Y    SZ_U                          // post-GELU SSM output
#define OFF_T1  (OFF_Y + SZ_Y)
#define SZ_T1   ((size_t)NL_*H_*64*64)        // [l][h][e][np]  w^e, e=0..63 (np = 2n+part)
#define OFF_T2  (OFF_T1 + SZ_T1)
#define SZ_T2   ((size_t)NL_*H_*64*68)        // [l][h][np][tau] w^{tau+1}, row pad 68
#define OFF_K   (OFF_T2 + SZ_T2)
#define SZ_K    ((size_t)NL_*H_*64)           // k[h][s], s<64
#define OFF_CP  (OFF_K + SZ_K)
#define SZ_CP   ((size_t)NL_*H_*64)           // C' [l][h][n][2]
#define OFF_W64 (OFF_CP + SZ_CP)
#define SZ_W64  ((size_t)NL_*H_*64)           // w^64 [l][h][n][2]
#define OFF_PL  (OFF_W64 + SZ_W64)
#define SZ_PL   ((size_t)B_*H_)

// ---------------------------------------------------------------------------
// P0a: per (layer,h,n) compute w=exp(dtA), C'=(C)*(w-1)/A, power tables
// ---------------------------------------------------------------------------
__global__ __launch_bounds__(256) void prep_tables(const float* log_dt, const float* log_A_real,
                                                   const float* A_imag, const float* C_re,
                                                   const float* C_im, float* ws) {
    int idx = blockIdx.x * 256 + threadIdx.x;        // flat (l,h,n)
    if (idx >= NL_ * H_ * N2_) return;
    int n  = idx & 31;
    int lh = idx >> 5;                               // l*128 + h

    float dt  = expf(log_dt[lh]);
    float Are = -expf(log_A_real[idx]);
    float Aim = A_imag[idx];
    float dre = Are * dt, dim = Aim * dt;
    float er  = expf(dre);
    float wre = er * cosf(dim), wim = er * sinf(dim);
    // (w-1)/A
    float nre = wre - 1.0f, nim = wim;
    float den = Are * Are + Aim * Aim;
    float qre = (nre * Are + nim * Aim) / den;
    float qim = (nim * Are - nre * Aim) / den;
    float cre = C_re[idx], cim = C_im[idx];
    float Cpre = cre * qre - cim * qim;
    float Cpim = cre * qim + cim * qre;

    float* t1  = ws + OFF_T1  + (size_t)lh * 64 * 64;
    float* t2  = ws + OFF_T2  + (size_t)lh * 64 * 68;
    float* cp  = ws + OFF_CP  + (size_t)lh * 64;
    float* w64 = ws + OFF_W64 + (size_t)lh * 64;
    cp[2 * n] = Cpre; cp[2 * n + 1] = Cpim;

    float pr = 1.0f, pi = 0.0f;                      // w^0
    for (int e = 0; e < 64; ++e) {
        t1[e * 64 + 2 * n]     = pr;                 // w^e
        t1[e * 64 + 2 * n + 1] = pi;
        float npr = pr * wre - pi * wim;
        float npi = pr * wim + pi * wre;
        pr = npr; pi = npi;                          // now w^{e+1}
        t2[(2 * n) * 68 + e]     = pr;               // w^{tau+1} at tau=e
        t2[(2 * n + 1) * 68 + e] = pi;
    }
    w64[2 * n] = pr; w64[2 * n + 1] = pi;            // w^64
}

// ---------------------------------------------------------------------------
// P0b: k[h][s] = 2*Re( sum_n C'_n w_n^s ),  s = 0..63 (local conv taps)
// ---------------------------------------------------------------------------
__global__ __launch_bounds__(256) void compute_k(float* ws) {
    int idx = blockIdx.x * 256 + threadIdx.x;        // (l,h,s)
    if (idx >= NL_ * H_ * 64) return;
    int s  = idx & 63;
    int lh = idx >> 6;
    const float* t1 = ws + OFF_T1 + (size_t)lh * 64 * 64 + (size_t)s * 64;
    const float* cp = ws + OFF_CP + (size_t)lh * 64;
    float acc = 0.0f;
    #pragma unroll
    for (int n = 0; n < 32; ++n)
        acc += cp[2 * n] * t1[2 * n] - cp[2 * n + 1] * t1[2 * n + 1];
    ws[OFF_K + (size_t)lh * 64 + s] = 2.0f * acc;
}

// ---------------------------------------------------------------------------
// Encoder: u[b][h][l] = enc_b[h] + sum_d x[b][l][d]*enc_w[h][d]
// ---------------------------------------------------------------------------
__global__ __launch_bounds__(256) void encoder_kernel(const float* x, const float* enc_w,
                                                      const float* enc_b, float* ws) {
    __shared__ float wlds[H_ * DIN];
    __shared__ float blds[H_];
    int t  = threadIdx.x;
    int b  = blockIdx.x >> 4;                        // 16 l-tiles of 256
    int l0 = (blockIdx.x & 15) * 256;
    for (int i = t; i < H_ * DIN; i += 256) wlds[i] = enc_w[i];
    if (t < H_) blds[t] = enc_b[t];
    float xr[16];
    const float* xp = x + ((size_t)b * L_ + l0 + t) * DIN;
    #pragma unroll
    for (int d = 0; d < 16; ++d) xr[d] = xp[d];
    __syncthreads();
    float* u = ws + OFF_U + (size_t)b * H_ * L_ + l0 + t;
    for (int h = 0; h < H_; ++h) {
        float acc = blds[h];
        #pragma unroll
        for (int d = 0; d < 16; ++d) acc += xr[d] * wlds[h * 16 + d];
        u[(size_t)h * L_] = acc;
    }
}

// ---------------------------------------------------------------------------
// S4D chunked scan, register-tiled matmul form. One block per (b,h).
// Pass A (fused): E[c][np] = sum_s z[c][s] w^{63-s}[np]        (P1)
//                 Yconv[c][tau] = sum_s z[c][s] k[tau-s]       (P3b)
// P2: serial cross-chunk scan on 32 lanes, writes G in place.
// Pass B: Y[c][tau] += sum_np G[c][np] w^{tau+1}[np]           (P3a)
// Epilogue: + D*z, exact GELU, store.
// Each thread owns a 4x4 output tile; operands staged transposed in LDS.
// ---------------------------------------------------------------------------
__global__ __launch_bounds__(256) void s4d_tiled(const float* Dp, float* ws, int layer) {
    __shared__ float zt[64 * 68];        // zt[s][c] = z[c*64+s]
    __shared__ float et[64 * 68];        // et[np][c] : E then G in place
    __shared__ float tab[64 * 68];       // T1 (flipped) then T2
    __shared__ float kext[132];          // [0..63]=0, [64..127]=k taps

    int t  = threadIdx.x;
    int b  = blockIdx.x >> 7;
    int h  = blockIdx.x & 127;
    int lh = layer * H_ + h;
    int tc = t & 15;                     // c-tile   (rows 4tc..4tc+3)
    int tn = t >> 4;                     // np/tau-tile (cols 4tn..4tn+3)

    const float* u = ws + OFF_U + ((size_t)b * H_ + h) * L_;

    // ---- stage zt (transposed), tab = T1 flipped, kext
    {
        const float* t1g = ws + OFF_T1 + (size_t)lh * 4096;
        #pragma unroll
        for (int it = 0; it < 4; ++it) {
            int i = t + it * 256;                    // float4 index 0..1023
            int l = i * 4; int c = l >> 6, s = l & 63;
            float4 v = *(const float4*)&u[l];
            zt[(s + 0) * 68 + c] = v.x;
            zt[(s + 1) * 68 + c] = v.y;
            zt[(s + 2) * 68 + c] = v.z;
            zt[(s + 3) * 68 + c] = v.w;
            int row = i >> 4, col4 = (i & 15) * 4;
            *(float4*)&tab[row * 68 + col4] = *(const float4*)&t1g[(63 - row) * 64 + col4];
        }
        if (t < 64) kext[t] = 0.0f;
        else if (t < 128) kext[t] = ws[OFF_K + (size_t)lh * 64 + (t - 64)];
    }
    __syncthreads();

    // ---- Pass A: P1 (E) + P3b (conv) fused over shared zt stream
    float accE[4][4];
    float accY[4][4];
    #pragma unroll
    for (int i = 0; i < 4; ++i)
        #pragma unroll
        for (int j = 0; j < 4; ++j) { accE[i][j] = 0.f; accY[i][j] = 0.f; }

    #pragma unroll 4
    for (int kk = 0; kk < 64; ++kk) {
        float4 a  = *(const float4*)&zt[kk * 68 + 4 * tc];
        float4 bv = *(const float4*)&tab[kk * 68 + 4 * tn];
        float kw0 = kext[64 + 4 * tn + 0 - kk];
        float kw1 = kext[64 + 4 * tn + 1 - kk];
        float kw2 = kext[64 + 4 * tn + 2 - kk];
        float kw3 = kext[64 + 4 * tn + 3 - kk];
        float av[4] = {a.x, a.y, a.z, a.w};
        float bw[4] = {bv.x, bv.y, bv.z, bv.w};
        float kw[4] = {kw0, kw1, kw2, kw3};
        #pragma unroll
        for (int ci = 0; ci < 4; ++ci)
            #pragma unroll
            for (int nj = 0; nj < 4; ++nj) {
                accE[ci][nj] = fmaf(av[ci], bw[nj], accE[ci][nj]);
                accY[ci][nj] = fmaf(av[ci], kw[nj], accY[ci][nj]);
            }
    }
    // write E transposed: et[np][c]
    #pragma unroll
    for (int nj = 0; nj < 4; ++nj)
        *(float4*)&et[(4 * tn + nj) * 68 + 4 * tc] =
            make_float4(accE[0][nj], accE[1][nj], accE[2][nj], accE[3][nj]);
    __syncthreads();

    // ---- restage tab = T2  (all threads; overlaps P2 issue below)
    {
        const float* t2g = ws + OFF_T2 + (size_t)lh * 64 * 68;
        #pragma unroll
        for (int it = 0; it < 4; ++it) {
            int i = t + it * 256; int row = i >> 4, col4 = (i & 15) * 4;
            *(float4*)&tab[row * 68 + col4] = *(const float4*)&t2g[row * 68 + col4];
        }
    }
    // ---- P2: cross-chunk scan (32 lanes), G = 2*C'*S sign-folded, in place
    if (t < 32) {
        int n = t;
        const float* cp  = ws + OFF_CP  + (size_t)lh * 64;
        const float* w64 = ws + OFF_W64 + (size_t)lh * 64;
        float cre = cp[2 * n], cim = cp[2 * n + 1];
        float wr  = w64[2 * n], wi = w64[2 * n + 1];
        float sre = 0.0f, sim = 0.0f;
        float* rr = &et[(2 * n) * 68];
        float* ri = &et[(2 * n + 1) * 68];
        #pragma unroll 1
        for (int c8 = 0; c8 < NC; c8 += 8) {
            float er[8], ei[8];
            #pragma unroll
            for (int k = 0; k < 8; ++k) { er[k] = rr[c8 + k]; ei[k] = ri[c8 + k]; }
            #pragma unroll
            for (int k = 0; k < 8; ++k) {
                rr[c8 + k] = 2.0f * (cre * sre - cim * sim);
                ri[c8 + k] = -2.0f * (cre * sim + cim * sre);
                float nr = fmaf(wr, sre, fmaf(-wi, sim, er[k]));
                float ni = fmaf(wr, sim, fmaf(wi, sre, ei[k]));
                sre = nr; sim = ni;
            }
        }
    }
    float Dh = Dp[lh];
    __syncthreads();

    // ---- Pass B: state term Y += G x T2
    #pragma unroll 4
    for (int kk = 0; kk < 64; ++kk) {
        float4 g   = *(const float4*)&et[kk * 68 + 4 * tc];
        float4 t2v = *(const float4*)&tab[kk * 68 + 4 * tn];
        float gv[4] = {g.x, g.y, g.z, g.w};
        float tv[4] = {t2v.x, t2v.y, t2v.z, t2v.w};
        #pragma unroll
        for (int ci = 0; ci < 4; ++ci)
            #pragma unroll
            for (int tj = 0; tj < 4; ++tj)
                accY[ci][tj] = fmaf(gv[ci], tv[tj], accY[ci][tj]);
    }

    // ---- epilogue: + D*z, GELU, store y
    float* y = ws + OFF_Y + ((size_t)b * H_ + h) * L_;
    float zq[4][4];                      // zq[tj][ci] = z[4tc+ci][4tn+tj]
    #pragma unroll
    for (int tj = 0; tj < 4; ++tj) {
        float4 v = *(const float4*)&zt[(4 * tn + tj) * 68 + 4 * tc];
        zq[tj][0] = v.x; zq[tj][1] = v.y; zq[tj][2] = v.z; zq[tj][3] = v.w;
    }
    #pragma unroll
    for (int ci = 0; ci < 4; ++ci) {
        float o[4];
        #pragma unroll
        for (int tj = 0; tj < 4; ++tj) {
            float acc = fmaf(Dh, zq[tj][ci], accY[ci][tj]);
            o[tj] = 0.5f * acc * (1.0f + erff(acc * 0.70710678118654752f));
        }
        *(float4*)&y[(4 * tc + ci) * 64 + 4 * tn] = make_float4(o[0], o[1], o[2], o[3]);
    }
}

// ---------------------------------------------------------------------------
// Channel mix: v = conv_w @ y + conv_b ; GLU ; +residual u ; LayerNorm -> u
// One block = (b, 64 l-positions). fp32 register-tiled GEMM 256x64, K=128.
// ---------------------------------------------------------------------------
__global__ __launch_bounds__(256) void conv_glu_ln(const float* conv_w, const float* conv_b,
                                                   const float* ln_w, const float* ln_b,
                                                   float* ws, int layer) {
    __shared__ float Wlds[16 * 260];     // [k][o], pad 260
    __shared__ float Ylds[16 * 68];      // [k][l], pad 68

    int t    = threadIdx.x;
    int b    = blockIdx.x >> 6;
    int l0   = (blockIdx.x & 63) * 64;
    int ocol = t & 31;
    int lgrp = t >> 5;

    const float* Wg = conv_w + (size_t)layer * 256 * 128;
    const float* yg = ws + OFF_Y + (size_t)b * H_ * L_;

    float acc[8][8];
    #pragma unroll
    for (int j = 0; j < 8; ++j) {
        int o = (j < 4) ? (4 * ocol + j) : (124 + 4 * ocol + j);
        float cb = conv_b[layer * 256 + o];
        #pragma unroll
        for (int i = 0; i < 8; ++i) acc[j][i] = cb;
    }

    for (int k0 = 0; k0 < 128; k0 += 16) {
        __syncthreads();
        {   // stage W tile: [o=t][k0..k0+15]
            const float* wrow = Wg + (size_t)t * 128 + k0;
            float4 a = *(const float4*)(wrow);
            float4 bb = *(const float4*)(wrow + 4);
            float4 cc = *(const float4*)(wrow + 8);
            float4 dd = *(const float4*)(wrow + 12);
            float wv16[16] = {a.x,a.y,a.z,a.w, bb.x,bb.y,bb.z,bb.w,
                              cc.x,cc.y,cc.z,cc.w, dd.x,dd.y,dd.z,dd.w};
            #pragma unroll
            for (int kk = 0; kk < 16; ++kk) Wlds[kk * 260 + t] = wv16[kk];
        }
        {   // stage Y tile
            int kk = t >> 4, l4 = (t & 15) * 4;
            float4 v = *(const float4*)&yg[(size_t)(k0 + kk) * L_ + l0 + l4];
            *(float4*)&Ylds[kk * 68 + l4] = v;
        }
        __syncthreads();
        #pragma unroll
        for (int kk = 0; kk < 16; ++kk) {
            float4 w0 = *(const float4*)&Wlds[kk * 260 + 4 * ocol];
            float4 w1 = *(const float4*)&Wlds[kk * 260 + 4 * ocol + 128];
            float4 y0 = *(const float4*)&Ylds[kk * 68 + lgrp * 8];
            float4 y1 = *(const float4*)&Ylds[kk * 68 + lgrp * 8 + 4];
            float wj[8] = {w0.x, w0.y, w0.z, w0.w, w1.x, w1.y, w1.z, w1.w};
            float yi[8] = {y0.x, y0.y, y0.z, y0.w, y1.x, y1.y, y1.z, y1.w};
            #pragma unroll
            for (int j = 0; j < 8; ++j)
                #pragma unroll
                for (int i = 0; i < 8; ++i)
                    acc[j][i] += wj[j] * yi[i];
        }
    }

    // GLU + residual
    float* ug = ws + OFF_U + (size_t)b * H_ * L_;
    float r[4][8];
    #pragma unroll
    for (int j = 0; j < 4; ++j) {
        int hch = 4 * ocol + j;
        const float* up = ug + (size_t)hch * L_ + l0 + lgrp * 8;
        float4 u0 = *(const float4*)up;
        float4 u1 = *(const float4*)(up + 4);
        float ui[8] = {u0.x, u0.y, u0.z, u0.w, u1.x, u1.y, u1.z, u1.w};
        #pragma unroll
        for (int i = 0; i < 8; ++i) {
            float a = acc[j][i], g = acc[j + 4][i];
            float y2 = a / (1.0f + expf(-g));
            r[j][i] = y2 + ui[i];
        }
    }
    // LayerNorm stats across 128 channels (32 lanes x 4 ch each)
    float mu[8], s2[8];
    #pragma unroll
    for (int i = 0; i < 8; ++i) {
        float s = r[0][i] + r[1][i] + r[2][i] + r[3][i];
        float q = r[0][i] * r[0][i] + r[1][i] * r[1][i] + r[2][i] * r[2][i] + r[3][i] * r[3][i];
        #pragma unroll
        for (int m = 1; m <= 16; m <<= 1) {
            s += __shfl_xor(s, m, 64);
            q += __shfl_xor(q, m, 64);
        }
        mu[i] = s * (1.0f / 128.0f);
        s2[i] = q * (1.0f / 128.0f) - mu[i] * mu[i];
    }
    #pragma unroll
    for (int j = 0; j < 4; ++j) {
        int hch = 4 * ocol + j;
        float lw = ln_w[layer * 128 + hch], lb = ln_b[layer * 128 + hch];
        float o0[4], o1[4];
        #pragma unroll
        for (int i = 0; i < 8; ++i) {
            float rstd = rsqrtf(s2[i] + 1e-5f);
            float v = (r[j][i] - mu[i]) * rstd * lw + lb;
            if (i < 4) o0[i] = v; else o1[i - 4] = v;
        }
        float* up = ug + (size_t)hch * L_ + l0 + lgrp * 8;
        *(float4*)up       = make_float4(o0[0], o0[1], o0[2], o0[3]);
        *(float4*)(up + 4) = make_float4(o1[0], o1[1], o1[2], o1[3]);
    }
}

// ---------------------------------------------------------------------------
// Mean-pool over L per (b,h)
// ---------------------------------------------------------------------------
__global__ __launch_bounds__(256) void pool_kernel(float* ws) {
    int bh = blockIdx.x;
    const float* u = ws + OFF_U + (size_t)bh * L_;
    int t = threadIdx.x;
    float s = 0.0f;
    for (int i = t; i < L_; i += 256) s += u[i];
    #pragma unroll
    for (int m = 1; m <= 32; m <<= 1) s += __shfl_xor(s, m, 64);
    __shared__ float part[4];
    if ((t & 63) == 0) part[t >> 6] = s;
    __syncthreads();
    if (t == 0) ws[OFF_PL + bh] = (part[0] + part[1] + part[2] + part[3]) * (1.0f / L_);
}

// ---------------------------------------------------------------------------
// Decoder: pred[b][o] = sigmoid(pooled[b] . dec_w[o] + dec_b[o])  (f32 out)
// ---------------------------------------------------------------------------
__global__ __launch_bounds__(256) void decode_kernel(const float* dec_w, const float* dec_b,
                                                     const float* ws, float* out) {
    int t = threadIdx.x;
    int b = t >> 3, o = t & 7;
    const float* p = ws + OFF_PL + b * 128;
    float acc = dec_b[o];
    for (int h = 0; h < 128; ++h) acc += p[h] * dec_w[o * 128 + h];
    out[t] = 1.0f / (1.0f + expf(-acc));
}

// ---------------------------------------------------------------------------
// emb output: out[b][l][h] = u[b][h][l]  (f32, LDS tile transpose)
// ---------------------------------------------------------------------------
__global__ __launch_bounds__(256) void emb_out(const float* uws, float* out) {
    __shared__ float T[32 * 65];
    int t  = threadIdx.x;
    int bi = blockIdx.x;
    int lt = bi & 63;
    int ht = (bi >> 6) & 3;
    int b  = bi >> 8;
    int l0 = lt * 64, h0 = ht * 32;
    const float* u = uws + ((size_t)b * H_ + h0) * L_ + l0;
    #pragma unroll
    for (int p = 0; p < 8; ++p) {
        int rr = p * 4 + (t >> 6), cc = t & 63;
        T[rr * 65 + cc] = u[(size_t)rr * L_ + cc];
    }
    __syncthreads();
    #pragma unroll
    for (int q = 0; q < 8; ++q) {
        int hh = t & 31, ll = (t >> 5) + q * 8;
        out[((size_t)(b * L_) + l0 + ll) * H_ + h0 + hh] = T[hh * 65 + ll];
    }
}

// ---------------------------------------------------------------------------
extern "C" void kernel_launch(void* const* d_in, const int* in_sizes, int n_in,
                              void* d_out, int out_size, void* d_ws, size_t ws_size,
                              hipStream_t stream) {
    const float* x          = (const float*)d_in[0];
    // d_in[1] = times (unused by reference)
    const float* enc_w      = (const float*)d_in[2];
    const float* enc_b      = (const float*)d_in[3];
    const float* log_dt     = (const float*)d_in[4];
    const float* log_A_real = (const float*)d_in[5];
    const float* A_imag     = (const float*)d_in[6];
    const float* C_re       = (const float*)d_in[7];
    const float* C_im       = (const float*)d_in[8];
    const float* Dp         = (const float*)d_in[9];
    const float* conv_w     = (const float*)d_in[10];
    const float* conv_b     = (const float*)d_in[11];
    const float* ln_w       = (const float*)d_in[12];
    const float* ln_b       = (const float*)d_in[13];
    const float* dec_w      = (const float*)d_in[14];
    const float* dec_b      = (const float*)d_in[15];
    float* ws = (float*)d_ws;
    float* out = (float*)d_out;

    prep_tables<<<(NL_ * H_ * N2_ + 255) / 256, 256, 0, stream>>>(log_dt, log_A_real, A_imag,
                                                                  C_re, C_im, ws);
    compute_k<<<(NL_ * H_ * 64 + 255) / 256, 256, 0, stream>>>(ws);
    encoder_kernel<<<B_ * (L_ / 256), 256, 0, stream>>>(x, enc_w, enc_b, ws);
    for (int l = 0; l < NL_; ++l) {
        s4d_tiled<<<B_ * H_, 256, 0, stream>>>(Dp, ws, l);
        conv_glu_ln<<<B_ * (L_ / 64), 256, 0, stream>>>(conv_w, conv_b, ln_w, ln_b, ws, l);
    }
    pool_kernel<<<B_ * H_, 256, 0, stream>>>(ws);
    decode_kernel<<<1, 256, 0, stream>>>(dec_w, dec_b, ws, out);
    emb_out<<<B_ * 4 * 64, 256, 0, stream>>>(ws + OFF_U, out + 256);
}

// Round 5
// 655.497 us; speedup vs baseline: 17.2217x; 1.4616x over previous
//
#include <hip/hip_runtime.h>
#include <hip/hip_bf16.h>

#define B_ 32
#define L_ 4096
#define DIN 16
#define H_ 128
#define N2_ 32
#define NL_ 4
#define DOUT_ 8
#define CL 64   // chunk length
#define NC 64   // chunks per sequence (L/CL)

// ---- workspace layout (in floats) ----
#define OFF_U   ((size_t)0)
#define SZ_U    ((size_t)B_*H_*L_)            // activations, [b][h][l] f32
#define OFF_Y   (OFF_U + SZ_U)
#define SZ_Y    SZ_U                          // post-GELU SSM output (bf16, half-used)
#define OFF_T1  (OFF_Y + SZ_Y)
#define SZ_T1   ((size_t)NL_*H_*64*64)        // [l][h][e][np]  w^e, e=0..63 (np = 2n+part)
#define OFF_T2  (OFF_T1 + SZ_T1)
#define SZ_T2   ((size_t)NL_*H_*64*68)        // [l][h][np][tau] w^{tau+1}, row pad 68
#define OFF_K   (OFF_T2 + SZ_T2)
#define SZ_K    ((size_t)NL_*H_*64)           // k[h][s], s<64
#define OFF_CP  (OFF_K + SZ_K)
#define SZ_CP   ((size_t)NL_*H_*64)           // C' [l][h][n][2]
#define OFF_W64 (OFF_CP + SZ_CP)
#define SZ_W64  ((size_t)NL_*H_*64)           // w^64 [l][h][n][2]
#define OFF_PL  (OFF_W64 + SZ_W64)
#define SZ_PL   ((size_t)B_*H_)
#define OFF_WB  (OFF_PL + SZ_PL)
#define SZ_WB   ((size_t)NL_*256*128/2)       // conv_w in bf16 (ushort), as float slots

typedef __bf16 bf16_t;
typedef bf16_t bf16x8 __attribute__((ext_vector_type(8)));
typedef float f32x4 __attribute__((ext_vector_type(4)));
typedef unsigned short u16x8 __attribute__((ext_vector_type(8)));

__device__ __forceinline__ unsigned short f2bf(float f) {
    unsigned int u = __builtin_bit_cast(unsigned int, f);
    unsigned int r = (u + 0x7fffu + ((u >> 16) & 1u)) >> 16;   // RNE
    return (unsigned short)r;
}

// ---------------------------------------------------------------------------
// P0a: per (layer,h,n) compute w=exp(dtA), C'=(C)*(w-1)/A, power tables
// ---------------------------------------------------------------------------
__global__ __launch_bounds__(256) void prep_tables(const float* log_dt, const float* log_A_real,
                                                   const float* A_imag, const float* C_re,
                                                   const float* C_im, float* ws) {
    int idx = blockIdx.x * 256 + threadIdx.x;        // flat (l,h,n)
    if (idx >= NL_ * H_ * N2_) return;
    int n  = idx & 31;
    int lh = idx >> 5;                               // l*128 + h

    float dt  = expf(log_dt[lh]);
    float Are = -expf(log_A_real[idx]);
    float Aim = A_imag[idx];
    float dre = Are * dt, dim = Aim * dt;
    float er  = expf(dre);
    float wre = er * cosf(dim), wim = er * sinf(dim);
    float nre = wre - 1.0f, nim = wim;
    float den = Are * Are + Aim * Aim;
    float qre = (nre * Are + nim * Aim) / den;
    float qim = (nim * Are - nre * Aim) / den;
    float cre = C_re[idx], cim = C_im[idx];
    float Cpre = cre * qre - cim * qim;
    float Cpim = cre * qim + cim * qre;

    float* t1  = ws + OFF_T1  + (size_t)lh * 64 * 64;
    float* t2  = ws + OFF_T2  + (size_t)lh * 64 * 68;
    float* cp  = ws + OFF_CP  + (size_t)lh * 64;
    float* w64 = ws + OFF_W64 + (size_t)lh * 64;
    cp[2 * n] = Cpre; cp[2 * n + 1] = Cpim;

    float pr = 1.0f, pi = 0.0f;                      // w^0
    for (int e = 0; e < 64; ++e) {
        t1[e * 64 + 2 * n]     = pr;
        t1[e * 64 + 2 * n + 1] = pi;
        float npr = pr * wre - pi * wim;
        float npi = pr * wim + pi * wre;
        pr = npr; pi = npi;                          // now w^{e+1}
        t2[(2 * n) * 68 + e]     = pr;
        t2[(2 * n + 1) * 68 + e] = pi;
    }
    w64[2 * n] = pr; w64[2 * n + 1] = pi;
}

// ---------------------------------------------------------------------------
// P0b: k[h][s] = 2*Re( sum_n C'_n w_n^s )
// ---------------------------------------------------------------------------
__global__ __launch_bounds__(256) void compute_k(float* ws) {
    int idx = blockIdx.x * 256 + threadIdx.x;        // (l,h,s)
    if (idx >= NL_ * H_ * 64) return;
    int s  = idx & 63;
    int lh = idx >> 6;
    const float* t1 = ws + OFF_T1 + (size_t)lh * 64 * 64 + (size_t)s * 64;
    const float* cp = ws + OFF_CP + (size_t)lh * 64;
    float acc = 0.0f;
    #pragma unroll
    for (int n = 0; n < 32; ++n)
        acc += cp[2 * n] * t1[2 * n] - cp[2 * n + 1] * t1[2 * n + 1];
    ws[OFF_K + (size_t)lh * 64 + s] = 2.0f * acc;
}

// ---------------------------------------------------------------------------
// P0c: conv_w -> bf16
// ---------------------------------------------------------------------------
__global__ __launch_bounds__(256) void prep_wbf(const float* conv_w, float* ws) {
    int i = blockIdx.x * 256 + threadIdx.x;          // NL*256*128 = 131072
    ((unsigned short*)(ws + OFF_WB))[i] = f2bf(conv_w[i]);
}

// ---------------------------------------------------------------------------
// Encoder
// ---------------------------------------------------------------------------
__global__ __launch_bounds__(256) void encoder_kernel(const float* x, const float* enc_w,
                                                      const float* enc_b, float* ws) {
    __shared__ float wlds[H_ * DIN];
    __shared__ float blds[H_];
    int t  = threadIdx.x;
    int b  = blockIdx.x >> 4;
    int l0 = (blockIdx.x & 15) * 256;
    for (int i = t; i < H_ * DIN; i += 256) wlds[i] = enc_w[i];
    if (t < H_) blds[t] = enc_b[t];
    float xr[16];
    const float* xp = x + ((size_t)b * L_ + l0 + t) * DIN;
    #pragma unroll
    for (int d = 0; d < 16; ++d) xr[d] = xp[d];
    __syncthreads();
    float* u = ws + OFF_U + (size_t)b * H_ * L_ + l0 + t;
    for (int h = 0; h < H_; ++h) {
        float acc = blds[h];
        #pragma unroll
        for (int d = 0; d < 16; ++d) acc += xr[d] * wlds[h * 16 + d];
        u[(size_t)h * L_] = acc;
    }
}

// ---------------------------------------------------------------------------
// S4D chunked scan, register-tiled. One block per (b,h). Writes y as bf16.
// ---------------------------------------------------------------------------
__global__ __launch_bounds__(256) void s4d_tiled(const float* Dp, float* ws, int layer) {
    __shared__ float zt[64 * 68];
    __shared__ float et[64 * 68];
    __shared__ float tab[64 * 68];
    __shared__ float kext[132];

    int t  = threadIdx.x;
    int b  = blockIdx.x >> 7;
    int h  = blockIdx.x & 127;
    int lh = layer * H_ + h;
    int tc = t & 15;
    int tn = t >> 4;

    const float* u = ws + OFF_U + ((size_t)b * H_ + h) * L_;

    {
        const float* t1g = ws + OFF_T1 + (size_t)lh * 4096;
        #pragma unroll
        for (int it = 0; it < 4; ++it) {
            int i = t + it * 256;
            int l = i * 4; int c = l >> 6, s = l & 63;
            float4 v = *(const float4*)&u[l];
            zt[(s + 0) * 68 + c] = v.x;
            zt[(s + 1) * 68 + c] = v.y;
            zt[(s + 2) * 68 + c] = v.z;
            zt[(s + 3) * 68 + c] = v.w;
            int row = i >> 4, col4 = (i & 15) * 4;
            *(float4*)&tab[row * 68 + col4] = *(const float4*)&t1g[(63 - row) * 64 + col4];
        }
        if (t < 64) kext[t] = 0.0f;
        else if (t < 128) kext[t] = ws[OFF_K + (size_t)lh * 64 + (t - 64)];
    }
    __syncthreads();

    float accE[4][4];
    float accY[4][4];
    #pragma unroll
    for (int i = 0; i < 4; ++i)
        #pragma unroll
        for (int j = 0; j < 4; ++j) { accE[i][j] = 0.f; accY[i][j] = 0.f; }

    #pragma unroll 4
    for (int kk = 0; kk < 64; ++kk) {
        float4 a  = *(const float4*)&zt[kk * 68 + 4 * tc];
        float4 bv = *(const float4*)&tab[kk * 68 + 4 * tn];
        float kw0 = kext[64 + 4 * tn + 0 - kk];
        float kw1 = kext[64 + 4 * tn + 1 - kk];
        float kw2 = kext[64 + 4 * tn + 2 - kk];
        float kw3 = kext[64 + 4 * tn + 3 - kk];
        float av[4] = {a.x, a.y, a.z, a.w};
        float bw[4] = {bv.x, bv.y, bv.z, bv.w};
        float kw[4] = {kw0, kw1, kw2, kw3};
        #pragma unroll
        for (int ci = 0; ci < 4; ++ci)
            #pragma unroll
            for (int nj = 0; nj < 4; ++nj) {
                accE[ci][nj] = fmaf(av[ci], bw[nj], accE[ci][nj]);
                accY[ci][nj] = fmaf(av[ci], kw[nj], accY[ci][nj]);
            }
    }
    #pragma unroll
    for (int nj = 0; nj < 4; ++nj)
        *(float4*)&et[(4 * tn + nj) * 68 + 4 * tc] =
            make_float4(accE[0][nj], accE[1][nj], accE[2][nj], accE[3][nj]);
    __syncthreads();

    {
        const float* t2g = ws + OFF_T2 + (size_t)lh * 64 * 68;
        #pragma unroll
        for (int it = 0; it < 4; ++it) {
            int i = t + it * 256; int row = i >> 4, col4 = (i & 15) * 4;
            *(float4*)&tab[row * 68 + col4] = *(const float4*)&t2g[row * 68 + col4];
        }
    }
    if (t < 32) {
        int n = t;
        const float* cp  = ws + OFF_CP  + (size_t)lh * 64;
        const float* w64 = ws + OFF_W64 + (size_t)lh * 64;
        float cre = cp[2 * n], cim = cp[2 * n + 1];
        float wr  = w64[2 * n], wi = w64[2 * n + 1];
        float sre = 0.0f, sim = 0.0f;
        float* rr = &et[(2 * n) * 68];
        float* ri = &et[(2 * n + 1) * 68];
        #pragma unroll 1
        for (int c8 = 0; c8 < NC; c8 += 8) {
            float er[8], ei[8];
            #pragma unroll
            for (int k = 0; k < 8; ++k) { er[k] = rr[c8 + k]; ei[k] = ri[c8 + k]; }
            #pragma unroll
            for (int k = 0; k < 8; ++k) {
                rr[c8 + k] = 2.0f * (cre * sre - cim * sim);
                ri[c8 + k] = -2.0f * (cre * sim + cim * sre);
                float nr = fmaf(wr, sre, fmaf(-wi, sim, er[k]));
                float ni = fmaf(wr, sim, fmaf(wi, sre, ei[k]));
                sre = nr; sim = ni;
            }
        }
    }
    float Dh = Dp[lh];
    __syncthreads();

    #pragma unroll 4
    for (int kk = 0; kk < 64; ++kk) {
        float4 g   = *(const float4*)&et[kk * 68 + 4 * tc];
        float4 t2v = *(const float4*)&tab[kk * 68 + 4 * tn];
        float gv[4] = {g.x, g.y, g.z, g.w};
        float tv[4] = {t2v.x, t2v.y, t2v.z, t2v.w};
        #pragma unroll
        for (int ci = 0; ci < 4; ++ci)
            #pragma unroll
            for (int tj = 0; tj < 4; ++tj)
                accY[ci][tj] = fmaf(gv[ci], tv[tj], accY[ci][tj]);
    }

    // epilogue: + D*z, GELU, store y as bf16
    unsigned short* yb = (unsigned short*)(ws + OFF_Y) + ((size_t)b * H_ + h) * L_;
    float zq[4][4];
    #pragma unroll
    for (int tj = 0; tj < 4; ++tj) {
        float4 v = *(const float4*)&zt[(4 * tn + tj) * 68 + 4 * tc];
        zq[tj][0] = v.x; zq[tj][1] = v.y; zq[tj][2] = v.z; zq[tj][3] = v.w;
    }
    #pragma unroll
    for (int ci = 0; ci < 4; ++ci) {
        ushort4 pk;
        float o[4];
        #pragma unroll
        for (int tj = 0; tj < 4; ++tj) {
            float acc = fmaf(Dh, zq[tj][ci], accY[ci][tj]);
            o[tj] = 0.5f * acc * (1.0f + erff(acc * 0.70710678118654752f));
        }
        pk.x = f2bf(o[0]); pk.y = f2bf(o[1]); pk.z = f2bf(o[2]); pk.w = f2bf(o[3]);
        *(ushort4*)&yb[(4 * tc + ci) * 64 + 4 * tn] = pk;
    }
}

// ---------------------------------------------------------------------------
// Channel mix via bf16 MFMA: v = Wbf @ y_bf16 + b ; GLU ; +resid ; LN -> u
// Block = (b, 64 l). 4 waves; wave w owns channels [w*32,w*32+32) (a-half)
// and [128+w*32, ...) (g-half) so GLU pairs are lane-local.
// ---------------------------------------------------------------------------
__global__ __launch_bounds__(256) void conv_glu_ln_mfma(const float* conv_b, const float* ln_w,
                                                        const float* ln_b, float* ws, int layer) {
    __shared__ unsigned short yt[128 * 66];   // [h][l], stride 66
    __shared__ float wsum[4][64];
    __shared__ float wsq[4][64];

    int t    = threadIdx.x;
    int b    = blockIdx.x >> 6;
    int l0   = (blockIdx.x & 63) * 64;
    int w    = t >> 6;
    int lam  = t & 63;
    int g4   = lam >> 4;
    int ncol = lam & 15;

    const unsigned short* yg = (const unsigned short*)(ws + OFF_Y) + (size_t)b * H_ * L_;
    const unsigned short* wb = (const unsigned short*)(ws + OFF_WB) + (size_t)layer * 256 * 128;

    // ---- stage y tile [128][64] -> yt[h][l] (stride 66; conflict-free u16 gather)
    #pragma unroll
    for (int it = 0; it < 4; ++it) {
        int flat = t + it * 256;                 // 0..1023
        int h = flat >> 3, l8 = (flat & 7) * 8;
        u16x8 v = *(const u16x8*)&yg[(size_t)h * L_ + l0 + l8];
        unsigned int* dst = (unsigned int*)&yt[h * 66 + l8];
        uint4 uv = __builtin_bit_cast(uint4, v);
        dst[0] = uv.x; dst[1] = uv.y; dst[2] = uv.z; dst[3] = uv.w;
    }

    // ---- preload A fragments (W, bf16) from global
    bf16x8 aA[4][2], aG[4][2];
    #pragma unroll
    for (int kt = 0; kt < 4; ++kt)
        #pragma unroll
        for (int oa = 0; oa < 2; ++oa) {
            int oA = w * 32 + oa * 16 + ncol;
            aA[kt][oa] = __builtin_bit_cast(bf16x8,
                *(const u16x8*)&wb[(size_t)oA * 128 + kt * 32 + g4 * 8]);
            aG[kt][oa] = __builtin_bit_cast(bf16x8,
                *(const u16x8*)&wb[(size_t)(128 + oA) * 128 + kt * 32 + g4 * 8]);
        }

    // ---- bias init
    const float* cb = conv_b + layer * 256;
    f32x4 dA[2][4], dG[2][4];
    #pragma unroll
    for (int oa = 0; oa < 2; ++oa) {
        int ba = w * 32 + oa * 16 + g4 * 4;
        f32x4 bA, bG;
        #pragma unroll
        for (int r = 0; r < 4; ++r) { bA[r] = cb[ba + r]; bG[r] = cb[128 + ba + r]; }
        #pragma unroll
        for (int nt = 0; nt < 4; ++nt) { dA[oa][nt] = bA; dG[oa][nt] = bG; }
    }
    __syncthreads();

    // ---- K loop: 4 x (gather 4 B frags + 16 MFMA)
    #pragma unroll
    for (int kt = 0; kt < 4; ++kt) {
        bf16x8 bfr[4];
        #pragma unroll
        for (int nt = 0; nt < 4; ++nt) {
            int l = nt * 16 + ncol;
            int hb = kt * 32 + g4 * 8;
            u16x8 tmp;
            #pragma unroll
            for (int i = 0; i < 8; ++i) tmp[i] = yt[(hb + i) * 66 + l];
            bfr[nt] = __builtin_bit_cast(bf16x8, tmp);
        }
        #pragma unroll
        for (int nt = 0; nt < 4; ++nt)
            #pragma unroll
            for (int oa = 0; oa < 2; ++oa) {
                dA[oa][nt] = __builtin_amdgcn_mfma_f32_16x16x32_bf16(aA[kt][oa], bfr[nt], dA[oa][nt], 0, 0, 0);
                dG[oa][nt] = __builtin_amdgcn_mfma_f32_16x16x32_bf16(aG[kt][oa], bfr[nt], dG[oa][nt], 0, 0, 0);
            }
    }

    // ---- epilogue: GLU + residual; LN over 128 channels
    float* ug = ws + OFF_U + (size_t)b * H_ * L_;
    float lwv[2][4], lbv[2][4];
    #pragma unroll
    for (int oa = 0; oa < 2; ++oa)
        #pragma unroll
        for (int r = 0; r < 4; ++r) {
            int hh = layer * 128 + w * 32 + oa * 16 + g4 * 4 + r;
            lwv[oa][r] = ln_w[hh]; lbv[oa][r] = ln_b[hh];
        }

    #pragma unroll
    for (int nt = 0; nt < 4; ++nt) {
        int l = l0 + nt * 16 + ncol;
        float s = 0.f, q = 0.f;
        #pragma unroll
        for (int oa = 0; oa < 2; ++oa)
            #pragma unroll
            for (int r = 0; r < 4; ++r) {
                int h = w * 32 + oa * 16 + g4 * 4 + r;
                float a = dA[oa][nt][r], g = dG[oa][nt][r];
                float val = a / (1.0f + expf(-g)) + ug[(size_t)h * L_ + l];
                dA[oa][nt][r] = val;           // reuse acc regs to hold r-values
                s += val; q += val * val;
            }
        s += __shfl_xor(s, 16, 64); q += __shfl_xor(q, 16, 64);
        s += __shfl_xor(s, 32, 64); q += __shfl_xor(q, 32, 64);
        if (g4 == 0) { wsum[w][nt * 16 + ncol] = s; wsq[w][nt * 16 + ncol] = q; }
    }
    __syncthreads();

    #pragma unroll
    for (int nt = 0; nt < 4; ++nt) {
        int ll = nt * 16 + ncol;
        int l  = l0 + ll;
        float S = wsum[0][ll] + wsum[1][ll] + wsum[2][ll] + wsum[3][ll];
        float Q = wsq[0][ll] + wsq[1][ll] + wsq[2][ll] + wsq[3][ll];
        float mu = S * (1.0f / 128.0f);
        float var = Q * (1.0f / 128.0f) - mu * mu;
        float rstd = rsqrtf(var + 1e-5f);
        #pragma unroll
        for (int oa = 0; oa < 2; ++oa)
            #pragma unroll
            for (int r = 0; r < 4; ++r) {
                int h = w * 32 + oa * 16 + g4 * 4 + r;
                float v = (dA[oa][nt][r] - mu) * rstd * lwv[oa][r] + lbv[oa][r];
                ug[(size_t)h * L_ + l] = v;
            }
    }
}

// ---------------------------------------------------------------------------
// Mean-pool over L per (b,h)
// ---------------------------------------------------------------------------
__global__ __launch_bounds__(256) void pool_kernel(float* ws) {
    int bh = blockIdx.x;
    const float* u = ws + OFF_U + (size_t)bh * L_;
    int t = threadIdx.x;
    float s = 0.0f;
    for (int i = t; i < L_; i += 256) s += u[i];
    #pragma unroll
    for (int m = 1; m <= 32; m <<= 1) s += __shfl_xor(s, m, 64);
    __shared__ float part[4];
    if ((t & 63) == 0) part[t >> 6] = s;
    __syncthreads();
    if (t == 0) ws[OFF_PL + bh] = (part[0] + part[1] + part[2] + part[3]) * (1.0f / L_);
}

// ---------------------------------------------------------------------------
// Decoder (f32 out)
// ---------------------------------------------------------------------------
__global__ __launch_bounds__(256) void decode_kernel(const float* dec_w, const float* dec_b,
                                                     const float* ws, float* out) {
    int t = threadIdx.x;
    int b = t >> 3, o = t & 7;
    const float* p = ws + OFF_PL + b * 128;
    float acc = dec_b[o];
    for (int h = 0; h < 128; ++h) acc += p[h] * dec_w[o * 128 + h];
    out[t] = 1.0f / (1.0f + expf(-acc));
}

// ---------------------------------------------------------------------------
// emb output: out[b][l][h] = u[b][h][l]  (f32, LDS tile transpose)
// ---------------------------------------------------------------------------
__global__ __launch_bounds__(256) void emb_out(const float* uws, float* out) {
    __shared__ float T[32 * 65];
    int t  = threadIdx.x;
    int bi = blockIdx.x;
    int lt = bi & 63;
    int ht = (bi >> 6) & 3;
    int b  = bi >> 8;
    int l0 = lt * 64, h0 = ht * 32;
    const float* u = uws + ((size_t)b * H_ + h0) * L_ + l0;
    #pragma unroll
    for (int p = 0; p < 8; ++p) {
        int rr = p * 4 + (t >> 6), cc = t & 63;
        T[rr * 65 + cc] = u[(size_t)rr * L_ + cc];
    }
    __syncthreads();
    #pragma unroll
    for (int q = 0; q < 8; ++q) {
        int hh = t & 31, ll = (t >> 5) + q * 8;
        out[((size_t)(b * L_) + l0 + ll) * H_ + h0 + hh] = T[hh * 65 + ll];
    }
}

// ---------------------------------------------------------------------------
extern "C" void kernel_launch(void* const* d_in, const int* in_sizes, int n_in,
                              void* d_out, int out_size, void* d_ws, size_t ws_size,
                              hipStream_t stream) {
    const float* x          = (const float*)d_in[0];
    const float* enc_w      = (const float*)d_in[2];
    const float* enc_b      = (const float*)d_in[3];
    const float* log_dt     = (const float*)d_in[4];
    const float* log_A_real = (const float*)d_in[5];
    const float* A_imag     = (const float*)d_in[6];
    const float* C_re       = (const float*)d_in[7];
    const float* C_im       = (const float*)d_in[8];
    const float* Dp         = (const float*)d_in[9];
    const float* conv_w     = (const float*)d_in[10];
    const float* conv_b     = (const float*)d_in[11];
    const float* ln_w       = (const float*)d_in[12];
    const float* ln_b       = (const float*)d_in[13];
    const float* dec_w      = (const float*)d_in[14];
    const float* dec_b      = (const float*)d_in[15];
    float* ws = (float*)d_ws;
    float* out = (float*)d_out;

    prep_tables<<<(NL_ * H_ * N2_ + 255) / 256, 256, 0, stream>>>(log_dt, log_A_real, A_imag,
                                                                  C_re, C_im, ws);
    compute_k<<<(NL_ * H_ * 64 + 255) / 256, 256, 0, stream>>>(ws);
    prep_wbf<<<(NL_ * 256 * 128) / 256, 256, 0, stream>>>(conv_w, ws);
    encoder_kernel<<<B_ * (L_ / 256), 256, 0, stream>>>(x, enc_w, enc_b, ws);
    for (int l = 0; l < NL_; ++l) {
        s4d_tiled<<<B_ * H_, 256, 0, stream>>>(Dp, ws, l);
        conv_glu_ln_mfma<<<B_ * (L_ / 64), 256, 0, stream>>>(conv_b, ln_w, ln_b, ws, l);
    }
    pool_kernel<<<B_ * H_, 256, 0, stream>>>(ws);
    decode_kernel<<<1, 256, 0, stream>>>(dec_w, dec_b, ws, out);
    emb_out<<<B_ * 4 * 64, 256, 0, stream>>>(ws + OFF_U, out + 256);
}

// Round 6
// 515.975 us; speedup vs baseline: 21.8786x; 1.2704x over previous
//
#include <hip/hip_runtime.h>
#include <hip/hip_bf16.h>

#define B_ 32
#define L_ 4096
#define DIN 16
#define H_ 128
#define N2_ 32
#define NL_ 4
#define CL 64
#define NC 64

// ---- workspace layout (float slots) ----
#define OFF_UH  ((size_t)0)                   // u hi (u16), [b][h][l]
#define SZ_UH   ((size_t)B_*H_*L_/2)
#define OFF_UL  (OFF_UH + SZ_UH)              // u lo (u16)
#define SZ_UL   SZ_UH
#define OFF_Y   (OFF_UL + SZ_UL)              // y bf16 (u16), [b][h][l]
#define SZ_Y    ((size_t)B_*H_*L_/2)
#define OFF_T1  (OFF_Y + SZ_Y)                // f32 [lh][e][np] for compute_k
#define SZ_T1   ((size_t)NL_*H_*64*64)
#define OFF_K   (OFF_T1 + SZ_T1)
#define SZ_K    ((size_t)NL_*H_*64)
#define OFF_CP  (OFF_K + SZ_K)
#define SZ_CP   ((size_t)NL_*H_*64)
#define OFF_W64 (OFF_CP + SZ_CP)
#define SZ_W64  ((size_t)NL_*H_*64)
#define OFF_PL  (OFF_W64 + SZ_W64)
#define SZ_PL   ((size_t)B_*H_)
#define OFF_WB  (OFF_PL + SZ_PL)
#define SZ_WB   ((size_t)NL_*256*128/2)
// frag tables: per (lh): 8192 u16 = 4096 float slots. layout: (k>>3)*1024 + col*16 + (k&7), +8 = lo
#define OFF_T1F (OFF_WB + SZ_WB)
#define SZ_TF   ((size_t)NL_*H_*4096)
#define OFF_TKF (OFF_T1F + SZ_TF)
#define OFF_T2F (OFF_TKF + SZ_TF)

#define ZP 72   // u16 pitch, z/G hi-lo LDS
#define EP 68   // f32 pitch, E/G LDS

typedef __bf16 bf16_t;
typedef bf16_t bf16x8 __attribute__((ext_vector_type(8)));
typedef float f32x4 __attribute__((ext_vector_type(4)));
typedef unsigned short u16x8 __attribute__((ext_vector_type(8)));

#define MFMA(a, b, c) __builtin_amdgcn_mfma_f32_16x16x32_bf16(a, b, c, 0, 0, 0)
#define BCB(v) __builtin_bit_cast(bf16x8, v)

__device__ __forceinline__ unsigned short f2bf(float f) {
    unsigned int u = __builtin_bit_cast(unsigned int, f);
    unsigned int r = (u + 0x7fffu + ((u >> 16) & 1u)) >> 16;   // RNE
    return (unsigned short)r;
}
__device__ __forceinline__ float bf2f(unsigned short u) {
    return __builtin_bit_cast(float, (unsigned int)u << 16);
}
__device__ __forceinline__ void store_hl(unsigned short* p, int idx, float v) {
    unsigned short hi = f2bf(v);
    p[idx]     = hi;
    p[idx + 8] = f2bf(v - bf2f(hi));
}

// ---------------------------------------------------------------------------
// P0a: w=exp(dtA), C'=(C)(w-1)/A; T1 f32; T1F/T2F bf16 hi/lo frag tables
// ---------------------------------------------------------------------------
__global__ __launch_bounds__(256) void prep_tables(const float* log_dt, const float* log_A_real,
                                                   const float* A_imag, const float* C_re,
                                                   const float* C_im, float* ws) {
    int idx = blockIdx.x * 256 + threadIdx.x;        // (l,h,n)
    if (idx >= NL_ * H_ * N2_) return;
    int n  = idx & 31;
    int lh = idx >> 5;

    float dt  = expf(log_dt[lh]);
    float Are = -expf(log_A_real[idx]);
    float Aim = A_imag[idx];
    float dre = Are * dt, dim = Aim * dt;
    float er  = expf(dre);
    float wre = er * cosf(dim), wim = er * sinf(dim);
    float nre = wre - 1.0f, nim = wim;
    float den = Are * Are + Aim * Aim;
    float qre = (nre * Are + nim * Aim) / den;
    float qim = (nim * Are - nre * Aim) / den;
    float cre = C_re[idx], cim = C_im[idx];
    float Cpre = cre * qre - cim * qim;
    float Cpim = cre * qim + cim * qre;

    float* t1  = ws + OFF_T1  + (size_t)lh * 4096;
    float* cp  = ws + OFF_CP  + (size_t)lh * 64;
    float* w64 = ws + OFF_W64 + (size_t)lh * 64;
    unsigned short* t1f = (unsigned short*)(ws + OFF_T1F) + (size_t)lh * 8192;
    unsigned short* t2f = (unsigned short*)(ws + OFF_T2F) + (size_t)lh * 8192;
    cp[2 * n] = Cpre; cp[2 * n + 1] = Cpim;

    float pr = 1.0f, pi = 0.0f;                      // w^0
    for (int e = 0; e < 64; ++e) {
        t1[e * 64 + 2 * n]     = pr;                 // f32 for compute_k
        t1[e * 64 + 2 * n + 1] = pi;
        // T1F[k=63-e][np] = w^e
        int k1 = 63 - e;
        store_hl(t1f, (k1 >> 3) * 1024 + (2 * n) * 16 + (k1 & 7), pr);
        store_hl(t1f, (k1 >> 3) * 1024 + (2 * n + 1) * 16 + (k1 & 7), pi);
        float npr = pr * wre - pi * wim;
        float npi = pr * wim + pi * wre;
        pr = npr; pi = npi;                          // w^{e+1}
        // T2F[np][tau=e] = w^{e+1}
        store_hl(t2f, ((2 * n) >> 3) * 1024 + e * 16 + ((2 * n) & 7), pr);
        store_hl(t2f, ((2 * n + 1) >> 3) * 1024 + e * 16 + ((2 * n + 1) & 7), pi);
    }
    w64[2 * n] = pr; w64[2 * n + 1] = pi;
}

// ---------------------------------------------------------------------------
// P0b: k[h][s] = 2*Re( sum_n C'_n w_n^s )
// ---------------------------------------------------------------------------
__global__ __launch_bounds__(256) void compute_k(float* ws) {
    int idx = blockIdx.x * 256 + threadIdx.x;        // (l,h,s)
    if (idx >= NL_ * H_ * 64) return;
    int s  = idx & 63;
    int lh = idx >> 6;
    const float* t1 = ws + OFF_T1 + (size_t)lh * 4096 + (size_t)s * 64;
    const float* cp = ws + OFF_CP + (size_t)lh * 64;
    float acc = 0.0f;
    #pragma unroll
    for (int n = 0; n < 32; ++n)
        acc += cp[2 * n] * t1[2 * n] - cp[2 * n + 1] * t1[2 * n + 1];
    ws[OFF_K + (size_t)lh * 64 + s] = 2.0f * acc;
}

// ---------------------------------------------------------------------------
// P0c: Toeplitz frag table TKF[s][tau] = (tau>=s) ? k[tau-s] : 0
// ---------------------------------------------------------------------------
__global__ __launch_bounds__(256) void prep_tkf(float* ws) {
    int idx = blockIdx.x * 256 + threadIdx.x;        // (lh, s)
    if (idx >= NL_ * H_ * 64) return;
    int s  = idx & 63;
    int lh = idx >> 6;
    const float* kp = ws + OFF_K + (size_t)lh * 64;
    unsigned short* dst = (unsigned short*)(ws + OFF_TKF) + (size_t)lh * 8192;
    int rb = (s >> 3) * 1024 + (s & 7);
    for (int tau = 0; tau < 64; ++tau) {
        float v = (tau >= s) ? kp[tau - s] : 0.0f;
        store_hl(dst, rb + tau * 16, v);
    }
}

// ---------------------------------------------------------------------------
// P0d: conv_w -> bf16
// ---------------------------------------------------------------------------
__global__ __launch_bounds__(256) void prep_wbf(const float* conv_w, float* ws) {
    int i = blockIdx.x * 256 + threadIdx.x;
    ((unsigned short*)(ws + OFF_WB))[i] = f2bf(conv_w[i]);
}

// ---------------------------------------------------------------------------
// Encoder -> u hi/lo
// ---------------------------------------------------------------------------
__global__ __launch_bounds__(256) void encoder_kernel(const float* x, const float* enc_w,
                                                      const float* enc_b, float* ws) {
    __shared__ float wlds[H_ * DIN];
    __shared__ float blds[H_];
    int t  = threadIdx.x;
    int b  = blockIdx.x >> 4;
    int l0 = (blockIdx.x & 15) * 256;
    for (int i = t; i < H_ * DIN; i += 256) wlds[i] = enc_w[i];
    if (t < H_) blds[t] = enc_b[t];
    float xr[16];
    const float* xp = x + ((size_t)b * L_ + l0 + t) * DIN;
    #pragma unroll
    for (int d = 0; d < 16; ++d) xr[d] = xp[d];
    __syncthreads();
    unsigned short* uh = (unsigned short*)(ws + OFF_UH) + (size_t)b * H_ * L_ + l0 + t;
    unsigned short* ul = (unsigned short*)(ws + OFF_UL) + (size_t)b * H_ * L_ + l0 + t;
    for (int h = 0; h < H_; ++h) {
        float acc = blds[h];
        #pragma unroll
        for (int d = 0; d < 16; ++d) acc += xr[d] * wlds[h * 16 + d];
        unsigned short hi = f2bf(acc);
        uh[(size_t)h * L_] = hi;
        ul[(size_t)h * L_] = f2bf(acc - bf2f(hi));
    }
}

// ---------------------------------------------------------------------------
// S4D via split-bf16 MFMA. One block per (b,h), 4 waves; wave w owns tau/np
// quarter [16w,16w+16). y = GELU(z*T1F -> scan -> G*T2F + z*TKF + D*z)
// ---------------------------------------------------------------------------
__global__ __launch_bounds__(256) void s4d_mfma(const float* Dp, float* ws, int layer) {
    __shared__ unsigned short zsh[64 * ZP];   // z hi, then G hi
    __shared__ unsigned short zsl[64 * ZP];   // z lo, then G lo
    __shared__ float eg[64 * EP];             // E then G (f32)

    int t  = threadIdx.x;
    int b  = blockIdx.x >> 7;
    int h  = blockIdx.x & 127;
    int lh = layer * H_ + h;
    int w  = t >> 6;
    int l  = t & 63;
    int lr = l & 15;
    int lg = l >> 4;

    const unsigned short* uhg = (const unsigned short*)(ws + OFF_UH) + ((size_t)b * H_ + h) * L_;
    const unsigned short* ulg = (const unsigned short*)(ws + OFF_UL) + ((size_t)b * H_ + h) * L_;

    // stage z hi/lo
    {
        int c = t >> 2, s0 = (t & 3) * 16;
        u16x8 a0 = *(const u16x8*)&uhg[c * 64 + s0];
        u16x8 a1 = *(const u16x8*)&uhg[c * 64 + s0 + 8];
        u16x8 b0 = *(const u16x8*)&ulg[c * 64 + s0];
        u16x8 b1 = *(const u16x8*)&ulg[c * 64 + s0 + 8];
        *(u16x8*)&zsh[c * ZP + s0]     = a0;
        *(u16x8*)&zsh[c * ZP + s0 + 8] = a1;
        *(u16x8*)&zsl[c * ZP + s0]     = b0;
        *(u16x8*)&zsl[c * ZP + s0 + 8] = b1;
    }

    // preload B-frags (global, L2-hot): T1F + TKF, kblk 0/1
    const unsigned short* t1f = (const unsigned short*)(ws + OFF_T1F) + (size_t)lh * 8192;
    const unsigned short* tkf = (const unsigned short*)(ws + OFF_TKF) + (size_t)lh * 8192;
    const unsigned short* t2f = (const unsigned short*)(ws + OFF_T2F) + (size_t)lh * 8192;
    int bo = lg * 1024 + (w * 16 + lr) * 16;
    bf16x8 T1h0 = BCB(*(const u16x8*)&t1f[bo]);
    bf16x8 T1l0 = BCB(*(const u16x8*)&t1f[bo + 8]);
    bf16x8 T1h1 = BCB(*(const u16x8*)&t1f[bo + 4096]);
    bf16x8 T1l1 = BCB(*(const u16x8*)&t1f[bo + 4096 + 8]);
    bf16x8 TKh0 = BCB(*(const u16x8*)&tkf[bo]);
    bf16x8 TKl0 = BCB(*(const u16x8*)&tkf[bo + 8]);
    bf16x8 TKh1 = BCB(*(const u16x8*)&tkf[bo + 4096]);
    bf16x8 TKl1 = BCB(*(const u16x8*)&tkf[bo + 4096 + 8]);

    f32x4 accE[4], accC[4];
    #pragma unroll
    for (int ct = 0; ct < 4; ++ct) { accE[ct] = (f32x4)0.0f; accC[ct] = (f32x4)0.0f; }

    __syncthreads();

    // ---- Pass A: E = z x T1F ; Yconv = z x TKF
    #pragma unroll
    for (int ct = 0; ct < 4; ++ct) {
        int ar = (ct * 16 + lr) * ZP;
        bf16x8 ah0 = BCB(*(const u16x8*)&zsh[ar + lg * 8]);
        bf16x8 al0 = BCB(*(const u16x8*)&zsl[ar + lg * 8]);
        bf16x8 ah1 = BCB(*(const u16x8*)&zsh[ar + 32 + lg * 8]);
        bf16x8 al1 = BCB(*(const u16x8*)&zsl[ar + 32 + lg * 8]);
        accE[ct] = MFMA(ah0, T1h0, accE[ct]);
        accE[ct] = MFMA(al0, T1h0, accE[ct]);
        accE[ct] = MFMA(ah0, T1l0, accE[ct]);
        accE[ct] = MFMA(ah1, T1h1, accE[ct]);
        accE[ct] = MFMA(al1, T1h1, accE[ct]);
        accE[ct] = MFMA(ah1, T1l1, accE[ct]);
        accC[ct] = MFMA(ah0, TKh0, accC[ct]);
        accC[ct] = MFMA(al0, TKh0, accC[ct]);
        accC[ct] = MFMA(ah0, TKl0, accC[ct]);
        accC[ct] = MFMA(ah1, TKh1, accC[ct]);
        accC[ct] = MFMA(al1, TKh1, accC[ct]);
        accC[ct] = MFMA(ah1, TKl1, accC[ct]);
    }
    // write E (D-frag: row=(lg*4+r), col=lr)
    #pragma unroll
    for (int ct = 0; ct < 4; ++ct)
        #pragma unroll
        for (int r = 0; r < 4; ++r)
            eg[(ct * 16 + lg * 4 + r) * EP + w * 16 + lr] = accE[ct][r];

    // preload T2F frags; pre-extract epilogue z values (zsh/zsl reused for G)
    bf16x8 T2h0 = BCB(*(const u16x8*)&t2f[bo]);
    bf16x8 T2l0 = BCB(*(const u16x8*)&t2f[bo + 8]);
    bf16x8 T2h1 = BCB(*(const u16x8*)&t2f[bo + 4096]);
    bf16x8 T2l1 = BCB(*(const u16x8*)&t2f[bo + 4096 + 8]);
    float zep[16];
    #pragma unroll
    for (int ct = 0; ct < 4; ++ct)
        #pragma unroll
        for (int r = 0; r < 4; ++r) {
            int c = ct * 16 + lg * 4 + r, tau = w * 16 + lr;
            zep[ct * 4 + r] = bf2f(zsh[c * ZP + tau]) + bf2f(zsl[c * ZP + tau]);
        }
    __syncthreads();

    // ---- P2: cross-chunk scan (32 lanes), G = 2*C'*S sign-folded, in place
    if (t < 32) {
        int n = t;
        const float* cp  = ws + OFF_CP  + (size_t)lh * 64;
        const float* w64 = ws + OFF_W64 + (size_t)lh * 64;
        float cre = cp[2 * n], cim = cp[2 * n + 1];
        float wr  = w64[2 * n], wi = w64[2 * n + 1];
        float sre = 0.0f, sim = 0.0f;
        #pragma unroll 1
        for (int c8 = 0; c8 < NC; c8 += 8) {
            float er[8], ei[8];
            #pragma unroll
            for (int k = 0; k < 8; ++k) {
                er[k] = eg[(c8 + k) * EP + 2 * n];
                ei[k] = eg[(c8 + k) * EP + 2 * n + 1];
            }
            #pragma unroll
            for (int k = 0; k < 8; ++k) {
                eg[(c8 + k) * EP + 2 * n]     = 2.0f * (cre * sre - cim * sim);
                eg[(c8 + k) * EP + 2 * n + 1] = -2.0f * (cre * sim + cim * sre);
                float nr = fmaf(wr, sre, fmaf(-wi, sim, er[k]));
                float ni = fmaf(wr, sim, fmaf(wi, sre, ei[k]));
                sre = nr; sim = ni;
            }
        }
    }
    float Dh = Dp[lh];
    __syncthreads();

    // ---- cooperative cvt G f32 -> hi/lo into zsh/zsl
    {
        int c = t >> 2, np0 = (t & 3) * 16;
        #pragma unroll
        for (int half = 0; half < 2; ++half) {
            u16x8 gh, gl;
            #pragma unroll
            for (int j = 0; j < 8; ++j) {
                float v = eg[c * EP + np0 + half * 8 + j];
                unsigned short hi = f2bf(v);
                gh[j] = hi;
                gl[j] = f2bf(v - bf2f(hi));
            }
            *(u16x8*)&zsh[c * ZP + np0 + half * 8] = gh;
            *(u16x8*)&zsl[c * ZP + np0 + half * 8] = gl;
        }
    }
    __syncthreads();

    // ---- Pass B: Y += G x T2F
    #pragma unroll
    for (int ct = 0; ct < 4; ++ct) {
        int ar = (ct * 16 + lr) * ZP;
        bf16x8 gh0 = BCB(*(const u16x8*)&zsh[ar + lg * 8]);
        bf16x8 gl0 = BCB(*(const u16x8*)&zsl[ar + lg * 8]);
        bf16x8 gh1 = BCB(*(const u16x8*)&zsh[ar + 32 + lg * 8]);
        bf16x8 gl1 = BCB(*(const u16x8*)&zsl[ar + 32 + lg * 8]);
        accC[ct] = MFMA(gh0, T2h0, accC[ct]);
        accC[ct] = MFMA(gl0, T2h0, accC[ct]);
        accC[ct] = MFMA(gh0, T2l0, accC[ct]);
        accC[ct] = MFMA(gh1, T2h1, accC[ct]);
        accC[ct] = MFMA(gl1, T2h1, accC[ct]);
        accC[ct] = MFMA(gh1, T2l1, accC[ct]);
    }

    // ---- epilogue: + D*z, GELU, store y bf16
    unsigned short* yb = (unsigned short*)(ws + OFF_Y) + ((size_t)b * H_ + h) * L_;
    #pragma unroll
    for (int ct = 0; ct < 4; ++ct)
        #pragma unroll
        for (int r = 0; r < 4; ++r) {
            float acc = fmaf(Dh, zep[ct * 4 + r], accC[ct][r]);
            float g = 0.5f * acc * (1.0f + erff(acc * 0.70710678118654752f));
            yb[(ct * 16 + lg * 4 + r) * 64 + w * 16 + lr] = f2bf(g);
        }
}

// ---------------------------------------------------------------------------
// Channel mix via bf16 MFMA + GLU + residual + LN; u stored hi/lo
// ---------------------------------------------------------------------------
__global__ __launch_bounds__(256) void conv_glu_ln_mfma(const float* conv_b, const float* ln_w,
                                                        const float* ln_b, float* ws, int layer) {
    __shared__ unsigned short yt[128 * 66];
    __shared__ float wsum[4][64];
    __shared__ float wsq[4][64];

    int t    = threadIdx.x;
    int b    = blockIdx.x >> 6;
    int l0   = (blockIdx.x & 63) * 64;
    int w    = t >> 6;
    int lam  = t & 63;
    int g4   = lam >> 4;
    int ncol = lam & 15;

    const unsigned short* yg = (const unsigned short*)(ws + OFF_Y) + (size_t)b * H_ * L_;
    const unsigned short* wb = (const unsigned short*)(ws + OFF_WB) + (size_t)layer * 256 * 128;

    #pragma unroll
    for (int it = 0; it < 4; ++it) {
        int flat = t + it * 256;
        int h = flat >> 3, l8 = (flat & 7) * 8;
        u16x8 v = *(const u16x8*)&yg[(size_t)h * L_ + l0 + l8];
        unsigned int* dst = (unsigned int*)&yt[h * 66 + l8];
        uint4 uv = __builtin_bit_cast(uint4, v);
        dst[0] = uv.x; dst[1] = uv.y; dst[2] = uv.z; dst[3] = uv.w;
    }

    bf16x8 aA[4][2], aG[4][2];
    #pragma unroll
    for (int kt = 0; kt < 4; ++kt)
        #pragma unroll
        for (int oa = 0; oa < 2; ++oa) {
            int oA = w * 32 + oa * 16 + ncol;
            aA[kt][oa] = __builtin_bit_cast(bf16x8,
                *(const u16x8*)&wb[(size_t)oA * 128 + kt * 32 + g4 * 8]);
            aG[kt][oa] = __builtin_bit_cast(bf16x8,
                *(const u16x8*)&wb[(size_t)(128 + oA) * 128 + kt * 32 + g4 * 8]);
        }

    const float* cb = conv_b + layer * 256;
    f32x4 dA[2][4], dG[2][4];
    #pragma unroll
    for (int oa = 0; oa < 2; ++oa) {
        int ba = w * 32 + oa * 16 + g4 * 4;
        f32x4 bA, bG;
        #pragma unroll
        for (int r = 0; r < 4; ++r) { bA[r] = cb[ba + r]; bG[r] = cb[128 + ba + r]; }
        #pragma unroll
        for (int nt = 0; nt < 4; ++nt) { dA[oa][nt] = bA; dG[oa][nt] = bG; }
    }
    __syncthreads();

    #pragma unroll
    for (int kt = 0; kt < 4; ++kt) {
        bf16x8 bfr[4];
        #pragma unroll
        for (int nt = 0; nt < 4; ++nt) {
            int l = nt * 16 + ncol;
            int hb = kt * 32 + g4 * 8;
            u16x8 tmp;
            #pragma unroll
            for (int i = 0; i < 8; ++i) tmp[i] = yt[(hb + i) * 66 + l];
            bfr[nt] = __builtin_bit_cast(bf16x8, tmp);
        }
        #pragma unroll
        for (int nt = 0; nt < 4; ++nt)
            #pragma unroll
            for (int oa = 0; oa < 2; ++oa) {
                dA[oa][nt] = MFMA(aA[kt][oa], bfr[nt], dA[oa][nt]);
                dG[oa][nt] = MFMA(aG[kt][oa], bfr[nt], dG[oa][nt]);
            }
    }

    unsigned short* uhg = (unsigned short*)(ws + OFF_UH) + (size_t)b * H_ * L_;
    unsigned short* ulg = (unsigned short*)(ws + OFF_UL) + (size_t)b * H_ * L_;
    float lwv[2][4], lbv[2][4];
    #pragma unroll
    for (int oa = 0; oa < 2; ++oa)
        #pragma unroll
        for (int r = 0; r < 4; ++r) {
            int hh = layer * 128 + w * 32 + oa * 16 + g4 * 4 + r;
            lwv[oa][r] = ln_w[hh]; lbv[oa][r] = ln_b[hh];
        }

    #pragma unroll
    for (int nt = 0; nt < 4; ++nt) {
        int l = l0 + nt * 16 + ncol;
        float s = 0.f, q = 0.f;
        #pragma unroll
        for (int oa = 0; oa < 2; ++oa)
            #pragma unroll
            for (int r = 0; r < 4; ++r) {
                int h = w * 32 + oa * 16 + g4 * 4 + r;
                float a = dA[oa][nt][r], g = dG[oa][nt][r];
                size_t ui = (size_t)h * L_ + l;
                float val = a / (1.0f + expf(-g)) + bf2f(uhg[ui]) + bf2f(ulg[ui]);
                dA[oa][nt][r] = val;
                s += val; q += val * val;
            }
        s += __shfl_xor(s, 16, 64); q += __shfl_xor(q, 16, 64);
        s += __shfl_xor(s, 32, 64); q += __shfl_xor(q, 32, 64);
        if (g4 == 0) { wsum[w][nt * 16 + ncol] = s; wsq[w][nt * 16 + ncol] = q; }
    }
    __syncthreads();

    #pragma unroll
    for (int nt = 0; nt < 4; ++nt) {
        int ll = nt * 16 + ncol;
        int l  = l0 + ll;
        float S = wsum[0][ll] + wsum[1][ll] + wsum[2][ll] + wsum[3][ll];
        float Q = wsq[0][ll] + wsq[1][ll] + wsq[2][ll] + wsq[3][ll];
        float mu = S * (1.0f / 128.0f);
        float var = Q * (1.0f / 128.0f) - mu * mu;
        float rstd = rsqrtf(var + 1e-5f);
        #pragma unroll
        for (int oa = 0; oa < 2; ++oa)
            #pragma unroll
            for (int r = 0; r < 4; ++r) {
                int h = w * 32 + oa * 16 + g4 * 4 + r;
                float v = (dA[oa][nt][r] - mu) * rstd * lwv[oa][r] + lbv[oa][r];
                size_t ui = (size_t)h * L_ + l;
                unsigned short hi = f2bf(v);
                uhg[ui] = hi;
                ulg[ui] = f2bf(v - bf2f(hi));
            }
    }
}

// ---------------------------------------------------------------------------
// Mean-pool over L per (b,h)
// ---------------------------------------------------------------------------
__global__ __launch_bounds__(256) void pool_kernel(float* ws) {
    int bh = blockIdx.x;
    const unsigned short* uh = (const unsigned short*)(ws + OFF_UH) + (size_t)bh * L_;
    const unsigned short* ul = (const unsigned short*)(ws + OFF_UL) + (size_t)bh * L_;
    int t = threadIdx.x;
    float s = 0.0f;
    for (int i = t; i < L_; i += 256) s += bf2f(uh[i]) + bf2f(ul[i]);
    #pragma unroll
    for (int m = 1; m <= 32; m <<= 1) s += __shfl_xor(s, m, 64);
    __shared__ float part[4];
    if ((t & 63) == 0) part[t >> 6] = s;
    __syncthreads();
    if (t == 0) ws[OFF_PL + bh] = (part[0] + part[1] + part[2] + part[3]) * (1.0f / L_);
}

// ---------------------------------------------------------------------------
// Decoder (f32 out)
// ---------------------------------------------------------------------------
__global__ __launch_bounds__(256) void decode_kernel(const float* dec_w, const float* dec_b,
                                                     const float* ws, float* out) {
    int t = threadIdx.x;
    int b = t >> 3, o = t & 7;
    const float* p = ws + OFF_PL + b * 128;
    float acc = dec_b[o];
    for (int h = 0; h < 128; ++h) acc += p[h] * dec_w[o * 128 + h];
    out[t] = 1.0f / (1.0f + expf(-acc));
}

// ---------------------------------------------------------------------------
// emb output: out[b][l][h] = u[b][h][l]  (hi+lo reconstruct, LDS transpose)
// ---------------------------------------------------------------------------
__global__ __launch_bounds__(256) void emb_out(const float* ws, float* out) {
    __shared__ float T[32 * 65];
    int t  = threadIdx.x;
    int bi = blockIdx.x;
    int lt = bi & 63;
    int ht = (bi >> 6) & 3;
    int b  = bi >> 8;
    int l0 = lt * 64, h0 = ht * 32;
    const unsigned short* uh = (const unsigned short*)(ws + OFF_UH) + ((size_t)b * H_ + h0) * L_ + l0;
    const unsigned short* ul = (const unsigned short*)(ws + OFF_UL) + ((size_t)b * H_ + h0) * L_ + l0;
    #pragma unroll
    for (int p = 0; p < 8; ++p) {
        int rr = p * 4 + (t >> 6), cc = t & 63;
        size_t ui = (size_t)rr * L_ + cc;
        T[rr * 65 + cc] = bf2f(uh[ui]) + bf2f(ul[ui]);
    }
    __syncthreads();
    #pragma unroll
    for (int q = 0; q < 8; ++q) {
        int hh = t & 31, ll = (t >> 5) + q * 8;
        out[((size_t)(b * L_) + l0 + ll) * H_ + h0 + hh] = T[hh * 65 + ll];
    }
}

// ---------------------------------------------------------------------------
extern "C" void kernel_launch(void* const* d_in, const int* in_sizes, int n_in,
                              void* d_out, int out_size, void* d_ws, size_t ws_size,
                              hipStream_t stream) {
    const float* x          = (const float*)d_in[0];
    const float* enc_w      = (const float*)d_in[2];
    const float* enc_b      = (const float*)d_in[3];
    const float* log_dt     = (const float*)d_in[4];
    const float* log_A_real = (const float*)d_in[5];
    const float* A_imag     = (const float*)d_in[6];
    const float* C_re       = (const float*)d_in[7];
    const float* C_im       = (const float*)d_in[8];
    const float* Dp         = (const float*)d_in[9];
    const float* conv_w     = (const float*)d_in[10];
    const float* conv_b     = (const float*)d_in[11];
    const float* ln_w       = (const float*)d_in[12];
    const float* ln_b       = (const float*)d_in[13];
    const float* dec_w      = (const float*)d_in[14];
    const float* dec_b      = (const float*)d_in[15];
    float* ws = (float*)d_ws;
    float* out = (float*)d_out;

    prep_tables<<<(NL_ * H_ * N2_ + 255) / 256, 256, 0, stream>>>(log_dt, log_A_real, A_imag,
                                                                  C_re, C_im, ws);
    compute_k<<<(NL_ * H_ * 64 + 255) / 256, 256, 0, stream>>>(ws);
    prep_tkf<<<(NL_ * H_ * 64 + 255) / 256, 256, 0, stream>>>(ws);
    prep_wbf<<<(NL_ * 256 * 128) / 256, 256, 0, stream>>>(conv_w, ws);
    encoder_kernel<<<B_ * (L_ / 256), 256, 0, stream>>>(x, enc_w, enc_b, ws);
    for (int l = 0; l < NL_; ++l) {
        s4d_mfma<<<B_ * H_, 256, 0, stream>>>(Dp, ws, l);
        conv_glu_ln_mfma<<<B_ * (L_ / 64), 256, 0, stream>>>(conv_b, ln_w, ln_b, ws, l);
    }
    pool_kernel<<<B_ * H_, 256, 0, stream>>>(ws);
    decode_kernel<<<1, 256, 0, stream>>>(dec_w, dec_b, ws, out);
    emb_out<<<B_ * 4 * 64, 256, 0, stream>>>(ws, out + 256);
}

// Round 7
// 489.136 us; speedup vs baseline: 23.0791x; 1.0549x over previous
//
#include <hip/hip_runtime.h>
#include <hip/hip_bf16.h>

#define B_ 32
#define L_ 4096
#define DIN 16
#define H_ 128
#define N2_ 32
#define NL_ 4
#define CL 64
#define NC 64

// ---- workspace layout (float slots) ----
#define OFF_U   ((size_t)0)                   // u f32, [b][h][l]
#define SZ_U    ((size_t)B_*H_*L_)
#define OFF_Y   (OFF_U + SZ_U)                // y bf16 (u16), [b][h][l]
#define SZ_Y    ((size_t)B_*H_*L_/2)
#define OFF_T1  (OFF_Y + SZ_Y)                // f32 [lh][e][np] for compute_k
#define SZ_T1   ((size_t)NL_*H_*64*64)
#define OFF_K   (OFF_T1 + SZ_T1)
#define SZ_K    ((size_t)NL_*H_*64)
#define OFF_CP  (OFF_K + SZ_K)
#define SZ_CP   ((size_t)NL_*H_*64)
#define OFF_W64 (OFF_CP + SZ_CP)
#define SZ_W64  ((size_t)NL_*H_*64)
#define OFF_PL  (OFF_W64 + SZ_W64)
#define SZ_PL   ((size_t)B_*H_)
#define OFF_WB  (OFF_PL + SZ_PL)
#define SZ_WB   ((size_t)NL_*256*128/2)
// frag tables: per (lh): 8192 u16 = 4096 float slots. layout: (k>>3)*1024 + col*16 + (k&7), +8 = lo
#define OFF_T1F (OFF_WB + SZ_WB)
#define SZ_TF   ((size_t)NL_*H_*4096)
#define OFF_TKF (OFF_T1F + SZ_TF)
#define OFF_T2F (OFF_TKF + SZ_TF)

#define ZP 72   // u16 pitch, z/G hi-lo LDS
#define EP 68   // f32 pitch, E/G LDS

typedef __bf16 bf16_t;
typedef bf16_t bf16x8 __attribute__((ext_vector_type(8)));
typedef float f32x4 __attribute__((ext_vector_type(4)));
typedef unsigned short u16x8 __attribute__((ext_vector_type(8)));

#define MFMA(a, b, c) __builtin_amdgcn_mfma_f32_16x16x32_bf16(a, b, c, 0, 0, 0)
#define BCB(v) __builtin_bit_cast(bf16x8, v)

__device__ __forceinline__ unsigned short f2bf(float f) {
    unsigned int u = __builtin_bit_cast(unsigned int, f);
    unsigned int r = (u + 0x7fffu + ((u >> 16) & 1u)) >> 16;   // RNE
    return (unsigned short)r;
}
__device__ __forceinline__ float bf2f(unsigned short u) {
    return __builtin_bit_cast(float, (unsigned int)u << 16);
}
__device__ __forceinline__ void store_hl(unsigned short* p, int idx, float v) {
    unsigned short hi = f2bf(v);
    p[idx]     = hi;
    p[idx + 8] = f2bf(v - bf2f(hi));
}
// yt[l][h] XOR swizzle (u16 index); h must be mult of 8 for 16B access
__device__ __forceinline__ int yswz(int l, int h) {
    return (l * 128 + h) ^ ((l & 7) << 3);
}

// ---------------------------------------------------------------------------
// P0a: w=exp(dtA), C'=(C)(w-1)/A; T1 f32; T1F/T2F bf16 hi/lo frag tables
// ---------------------------------------------------------------------------
__global__ __launch_bounds__(256) void prep_tables(const float* log_dt, const float* log_A_real,
                                                   const float* A_imag, const float* C_re,
                                                   const float* C_im, float* ws) {
    int idx = blockIdx.x * 256 + threadIdx.x;        // (l,h,n)
    if (idx >= NL_ * H_ * N2_) return;
    int n  = idx & 31;
    int lh = idx >> 5;

    float dt  = expf(log_dt[lh]);
    float Are = -expf(log_A_real[idx]);
    float Aim = A_imag[idx];
    float dre = Are * dt, dim = Aim * dt;
    float er  = expf(dre);
    float wre = er * cosf(dim), wim = er * sinf(dim);
    float nre = wre - 1.0f, nim = wim;
    float den = Are * Are + Aim * Aim;
    float qre = (nre * Are + nim * Aim) / den;
    float qim = (nim * Are - nre * Aim) / den;
    float cre = C_re[idx], cim = C_im[idx];
    float Cpre = cre * qre - cim * qim;
    float Cpim = cre * qim + cim * qre;

    float* t1  = ws + OFF_T1  + (size_t)lh * 4096;
    float* cp  = ws + OFF_CP  + (size_t)lh * 64;
    float* w64 = ws + OFF_W64 + (size_t)lh * 64;
    unsigned short* t1f = (unsigned short*)(ws + OFF_T1F) + (size_t)lh * 8192;
    unsigned short* t2f = (unsigned short*)(ws + OFF_T2F) + (size_t)lh * 8192;
    cp[2 * n] = Cpre; cp[2 * n + 1] = Cpim;

    float pr = 1.0f, pi = 0.0f;                      // w^0
    for (int e = 0; e < 64; ++e) {
        t1[e * 64 + 2 * n]     = pr;
        t1[e * 64 + 2 * n + 1] = pi;
        int k1 = 63 - e;                             // T1F[k=63-e][np] = w^e
        store_hl(t1f, (k1 >> 3) * 1024 + (2 * n) * 16 + (k1 & 7), pr);
        store_hl(t1f, (k1 >> 3) * 1024 + (2 * n + 1) * 16 + (k1 & 7), pi);
        float npr = pr * wre - pi * wim;
        float npi = pr * wim + pi * wre;
        pr = npr; pi = npi;                          // w^{e+1}
        store_hl(t2f, ((2 * n) >> 3) * 1024 + e * 16 + ((2 * n) & 7), pr);
        store_hl(t2f, ((2 * n + 1) >> 3) * 1024 + e * 16 + ((2 * n + 1) & 7), pi);
    }
    w64[2 * n] = pr; w64[2 * n + 1] = pi;
}

// ---------------------------------------------------------------------------
// P0b: k[h][s] = 2*Re( sum_n C'_n w_n^s )
// ---------------------------------------------------------------------------
__global__ __launch_bounds__(256) void compute_k(float* ws) {
    int idx = blockIdx.x * 256 + threadIdx.x;        // (l,h,s)
    if (idx >= NL_ * H_ * 64) return;
    int s  = idx & 63;
    int lh = idx >> 6;
    const float* t1 = ws + OFF_T1 + (size_t)lh * 4096 + (size_t)s * 64;
    const float* cp = ws + OFF_CP + (size_t)lh * 64;
    float acc = 0.0f;
    #pragma unroll
    for (int n = 0; n < 32; ++n)
        acc += cp[2 * n] * t1[2 * n] - cp[2 * n + 1] * t1[2 * n + 1];
    ws[OFF_K + (size_t)lh * 64 + s] = 2.0f * acc;
}

// ---------------------------------------------------------------------------
// P0c: Toeplitz frag table TKF[s][tau] = (tau>=s) ? k[tau-s] : 0
// ---------------------------------------------------------------------------
__global__ __launch_bounds__(256) void prep_tkf(float* ws) {
    int idx = blockIdx.x * 256 + threadIdx.x;        // (lh, s)
    if (idx >= NL_ * H_ * 64) return;
    int s  = idx & 63;
    int lh = idx >> 6;
    const float* kp = ws + OFF_K + (size_t)lh * 64;
    unsigned short* dst = (unsigned short*)(ws + OFF_TKF) + (size_t)lh * 8192;
    int rb = (s >> 3) * 1024 + (s & 7);
    for (int tau = 0; tau < 64; ++tau) {
        float v = (tau >= s) ? kp[tau - s] : 0.0f;
        store_hl(dst, rb + tau * 16, v);
    }
}

// ---------------------------------------------------------------------------
// P0d: conv_w -> bf16
// ---------------------------------------------------------------------------
__global__ __launch_bounds__(256) void prep_wbf(const float* conv_w, float* ws) {
    int i = blockIdx.x * 256 + threadIdx.x;
    ((unsigned short*)(ws + OFF_WB))[i] = f2bf(conv_w[i]);
}

// ---------------------------------------------------------------------------
// Encoder -> u f32
// ---------------------------------------------------------------------------
__global__ __launch_bounds__(256) void encoder_kernel(const float* x, const float* enc_w,
                                                      const float* enc_b, float* ws) {
    __shared__ float wlds[H_ * DIN];
    __shared__ float blds[H_];
    int t  = threadIdx.x;
    int b  = blockIdx.x >> 4;
    int l0 = (blockIdx.x & 15) * 256;
    for (int i = t; i < H_ * DIN; i += 256) wlds[i] = enc_w[i];
    if (t < H_) blds[t] = enc_b[t];
    float xr[16];
    const float* xp = x + ((size_t)b * L_ + l0 + t) * DIN;
    #pragma unroll
    for (int d = 0; d < 16; ++d) xr[d] = xp[d];
    __syncthreads();
    float* u = ws + OFF_U + (size_t)b * H_ * L_ + l0 + t;
    for (int h = 0; h < H_; ++h) {
        float acc = blds[h];
        #pragma unroll
        for (int d = 0; d < 16; ++d) acc += xr[d] * wlds[h * 16 + d];
        u[(size_t)h * L_] = acc;
    }
}

// ---------------------------------------------------------------------------
// S4D via split-bf16 MFMA. One block per (b,h). z split f32->hi/lo at staging.
// ---------------------------------------------------------------------------
__global__ __launch_bounds__(256) void s4d_mfma(const float* Dp, float* ws, int layer) {
    __shared__ unsigned short zsh[64 * ZP];   // z hi, then G hi
    __shared__ unsigned short zsl[64 * ZP];   // z lo, then G lo
    __shared__ float eg[64 * EP];             // E then G (f32)

    int t  = threadIdx.x;
    int b  = blockIdx.x >> 7;
    int h  = blockIdx.x & 127;
    int lh = layer * H_ + h;
    int w  = t >> 6;
    int l  = t & 63;
    int lr = l & 15;
    int lg = l >> 4;

    const float* ug = ws + OFF_U + ((size_t)b * H_ + h) * L_;

    // stage z: f32 -> hi/lo (16 consecutive elements per thread)
    {
        int base = t * 16;
        int c = base >> 6, s0 = base & 63;
        u16x8 hh0, hh1, ll0, ll1;
        #pragma unroll
        for (int j = 0; j < 8; ++j) {
            float f = ug[base + j];
            unsigned short hi = f2bf(f);
            hh0[j] = hi; ll0[j] = f2bf(f - bf2f(hi));
        }
        #pragma unroll
        for (int j = 0; j < 8; ++j) {
            float f = ug[base + 8 + j];
            unsigned short hi = f2bf(f);
            hh1[j] = hi; ll1[j] = f2bf(f - bf2f(hi));
        }
        *(u16x8*)&zsh[c * ZP + s0]     = hh0;
        *(u16x8*)&zsh[c * ZP + s0 + 8] = hh1;
        *(u16x8*)&zsl[c * ZP + s0]     = ll0;
        *(u16x8*)&zsl[c * ZP + s0 + 8] = ll1;
    }

    // preload B-frags (global, L2-hot): T1F + TKF, kblk 0/1
    const unsigned short* t1f = (const unsigned short*)(ws + OFF_T1F) + (size_t)lh * 8192;
    const unsigned short* tkf = (const unsigned short*)(ws + OFF_TKF) + (size_t)lh * 8192;
    const unsigned short* t2f = (const unsigned short*)(ws + OFF_T2F) + (size_t)lh * 8192;
    int bo = lg * 1024 + (w * 16 + lr) * 16;
    bf16x8 T1h0 = BCB(*(const u16x8*)&t1f[bo]);
    bf16x8 T1l0 = BCB(*(const u16x8*)&t1f[bo + 8]);
    bf16x8 T1h1 = BCB(*(const u16x8*)&t1f[bo + 4096]);
    bf16x8 T1l1 = BCB(*(const u16x8*)&t1f[bo + 4096 + 8]);
    bf16x8 TKh0 = BCB(*(const u16x8*)&tkf[bo]);
    bf16x8 TKl0 = BCB(*(const u16x8*)&tkf[bo + 8]);
    bf16x8 TKh1 = BCB(*(const u16x8*)&tkf[bo + 4096]);
    bf16x8 TKl1 = BCB(*(const u16x8*)&tkf[bo + 4096 + 8]);

    f32x4 accE[4], accC[4];
    #pragma unroll
    for (int ct = 0; ct < 4; ++ct) { accE[ct] = (f32x4)0.0f; accC[ct] = (f32x4)0.0f; }

    __syncthreads();

    // ---- Pass A: E = z x T1F ; Yconv = z x TKF
    #pragma unroll
    for (int ct = 0; ct < 4; ++ct) {
        int ar = (ct * 16 + lr) * ZP;
        bf16x8 ah0 = BCB(*(const u16x8*)&zsh[ar + lg * 8]);
        bf16x8 al0 = BCB(*(const u16x8*)&zsl[ar + lg * 8]);
        bf16x8 ah1 = BCB(*(const u16x8*)&zsh[ar + 32 + lg * 8]);
        bf16x8 al1 = BCB(*(const u16x8*)&zsl[ar + 32 + lg * 8]);
        accE[ct] = MFMA(ah0, T1h0, accE[ct]);
        accE[ct] = MFMA(al0, T1h0, accE[ct]);
        accE[ct] = MFMA(ah0, T1l0, accE[ct]);
        accE[ct] = MFMA(ah1, T1h1, accE[ct]);
        accE[ct] = MFMA(al1, T1h1, accE[ct]);
        accE[ct] = MFMA(ah1, T1l1, accE[ct]);
        accC[ct] = MFMA(ah0, TKh0, accC[ct]);
        accC[ct] = MFMA(al0, TKh0, accC[ct]);
        accC[ct] = MFMA(ah0, TKl0, accC[ct]);
        accC[ct] = MFMA(ah1, TKh1, accC[ct]);
        accC[ct] = MFMA(al1, TKh1, accC[ct]);
        accC[ct] = MFMA(ah1, TKl1, accC[ct]);
    }
    // write E (D-frag: row=(lg*4+r), col=lr)
    #pragma unroll
    for (int ct = 0; ct < 4; ++ct)
        #pragma unroll
        for (int r = 0; r < 4; ++r)
            eg[(ct * 16 + lg * 4 + r) * EP + w * 16 + lr] = accE[ct][r];

    // preload T2F frags; pre-extract epilogue z (zsh/zsl reused for G after)
    bf16x8 T2h0 = BCB(*(const u16x8*)&t2f[bo]);
    bf16x8 T2l0 = BCB(*(const u16x8*)&t2f[bo + 8]);
    bf16x8 T2h1 = BCB(*(const u16x8*)&t2f[bo + 4096]);
    bf16x8 T2l1 = BCB(*(const u16x8*)&t2f[bo + 4096 + 8]);
    float zep[16];
    #pragma unroll
    for (int ct = 0; ct < 4; ++ct)
        #pragma unroll
        for (int r = 0; r < 4; ++r) {
            int c = ct * 16 + lg * 4 + r, tau = w * 16 + lr;
            zep[ct * 4 + r] = bf2f(zsh[c * ZP + tau]) + bf2f(zsl[c * ZP + tau]);
        }
    __syncthreads();

    // ---- P2: cross-chunk scan (32 lanes), G = 2*C'*S sign-folded, in place
    if (t < 32) {
        int n = t;
        const float* cp  = ws + OFF_CP  + (size_t)lh * 64;
        const float* w64 = ws + OFF_W64 + (size_t)lh * 64;
        float cre = cp[2 * n], cim = cp[2 * n + 1];
        float wr  = w64[2 * n], wi = w64[2 * n + 1];
        float sre = 0.0f, sim = 0.0f;
        #pragma unroll 1
        for (int c8 = 0; c8 < NC; c8 += 8) {
            float er[8], ei[8];
            #pragma unroll
            for (int k = 0; k < 8; ++k) {
                er[k] = eg[(c8 + k) * EP + 2 * n];
                ei[k] = eg[(c8 + k) * EP + 2 * n + 1];
            }
            #pragma unroll
            for (int k = 0; k < 8; ++k) {
                eg[(c8 + k) * EP + 2 * n]     = 2.0f * (cre * sre - cim * sim);
                eg[(c8 + k) * EP + 2 * n + 1] = -2.0f * (cre * sim + cim * sre);
                float nr = fmaf(wr, sre, fmaf(-wi, sim, er[k]));
                float ni = fmaf(wr, sim, fmaf(wi, sre, ei[k]));
                sre = nr; sim = ni;
            }
        }
    }
    float Dh = Dp[lh];
    __syncthreads();

    // ---- cooperative cvt G f32 -> hi/lo into zsh/zsl
    {
        int c = t >> 2, np0 = (t & 3) * 16;
        #pragma unroll
        for (int half = 0; half < 2; ++half) {
            u16x8 gh, gl;
            #pragma unroll
            for (int j = 0; j < 8; ++j) {
                float v = eg[c * EP + np0 + half * 8 + j];
                unsigned short hi = f2bf(v);
                gh[j] = hi;
                gl[j] = f2bf(v - bf2f(hi));
            }
            *(u16x8*)&zsh[c * ZP + np0 + half * 8] = gh;
            *(u16x8*)&zsl[c * ZP + np0 + half * 8] = gl;
        }
    }
    __syncthreads();

    // ---- Pass B: Y += G x T2F
    #pragma unroll
    for (int ct = 0; ct < 4; ++ct) {
        int ar = (ct * 16 + lr) * ZP;
        bf16x8 gh0 = BCB(*(const u16x8*)&zsh[ar + lg * 8]);
        bf16x8 gl0 = BCB(*(const u16x8*)&zsl[ar + lg * 8]);
        bf16x8 gh1 = BCB(*(const u16x8*)&zsh[ar + 32 + lg * 8]);
        bf16x8 gl1 = BCB(*(const u16x8*)&zsl[ar + 32 + lg * 8]);
        accC[ct] = MFMA(gh0, T2h0, accC[ct]);
        accC[ct] = MFMA(gl0, T2h0, accC[ct]);
        accC[ct] = MFMA(gh0, T2l0, accC[ct]);
        accC[ct] = MFMA(gh1, T2h1, accC[ct]);
        accC[ct] = MFMA(gl1, T2h1, accC[ct]);
        accC[ct] = MFMA(gh1, T2l1, accC[ct]);
    }

    // ---- epilogue: + D*z, GELU, store y bf16
    unsigned short* yb = (unsigned short*)(ws + OFF_Y) + ((size_t)b * H_ + h) * L_;
    #pragma unroll
    for (int ct = 0; ct < 4; ++ct)
        #pragma unroll
        for (int r = 0; r < 4; ++r) {
            float acc = fmaf(Dh, zep[ct * 4 + r], accC[ct][r]);
            float g = 0.5f * acc * (1.0f + erff(acc * 0.70710678118654752f));
            yb[(ct * 16 + lg * 4 + r) * 64 + w * 16 + lr] = f2bf(g);
        }
}

// ---------------------------------------------------------------------------
// Channel mix via bf16 MFMA + GLU + residual(f32) + LN. B-frags from
// transposed XOR-swizzled LDS yt[l][h]; vector b128 reads, balanced banks.
// ---------------------------------------------------------------------------
__global__ __launch_bounds__(256) void conv_glu_ln_mfma(const float* conv_b, const float* ln_w,
                                                        const float* ln_b, float* ws, int layer) {
    __shared__ unsigned short yt[64 * 128];   // [l][h], swizzled
    __shared__ float wsum[4][64];
    __shared__ float wsq[4][64];

    int t    = threadIdx.x;
    int b    = blockIdx.x >> 6;
    int l0   = (blockIdx.x & 63) * 64;
    int w    = t >> 6;
    int lam  = t & 63;
    int g4   = lam >> 4;
    int ncol = lam & 15;

    const unsigned short* yg = (const unsigned short*)(ws + OFF_Y) + (size_t)b * H_ * L_;
    const unsigned short* wb = (const unsigned short*)(ws + OFF_WB) + (size_t)layer * 256 * 128;

    // ---- stage y transposed: column loads (coalesced across lanes), b128 writes
    {
        int ll = t & 63;
        int hb = (t >> 6) * 32;
        const unsigned short* ycol = yg + l0 + ll;
        #pragma unroll
        for (int g = 0; g < 4; ++g) {
            u16x8 tmp;
            #pragma unroll
            for (int i = 0; i < 8; ++i)
                tmp[i] = ycol[(size_t)(hb + g * 8 + i) * L_];
            *(u16x8*)&yt[yswz(ll, hb + g * 8)] = tmp;
        }
    }

    // ---- bias init
    const float* cb = conv_b + layer * 256;
    f32x4 dA[2][4], dG[2][4];
    #pragma unroll
    for (int oa = 0; oa < 2; ++oa) {
        int ba = w * 32 + oa * 16 + g4 * 4;
        f32x4 bA, bG;
        #pragma unroll
        for (int r = 0; r < 4; ++r) { bA[r] = cb[ba + r]; bG[r] = cb[128 + ba + r]; }
        #pragma unroll
        for (int nt = 0; nt < 4; ++nt) { dA[oa][nt] = bA; dG[oa][nt] = bG; }
    }
    __syncthreads();

    // ---- K loop: per kt, A-frags from global (L2), B-frags via b128 LDS reads
    #pragma unroll
    for (int kt = 0; kt < 4; ++kt) {
        bf16x8 aAk[2], aGk[2];
        #pragma unroll
        for (int oa = 0; oa < 2; ++oa) {
            int oA = w * 32 + oa * 16 + ncol;
            aAk[oa] = BCB(*(const u16x8*)&wb[(size_t)oA * 128 + kt * 32 + g4 * 8]);
            aGk[oa] = BCB(*(const u16x8*)&wb[(size_t)(128 + oA) * 128 + kt * 32 + g4 * 8]);
        }
        #pragma unroll
        for (int nt = 0; nt < 4; ++nt) {
            bf16x8 bfr = BCB(*(const u16x8*)&yt[yswz(nt * 16 + ncol, kt * 32 + g4 * 8)]);
            #pragma unroll
            for (int oa = 0; oa < 2; ++oa) {
                dA[oa][nt] = MFMA(aAk[oa], bfr, dA[oa][nt]);
                dG[oa][nt] = MFMA(aGk[oa], bfr, dG[oa][nt]);
            }
        }
    }

    // ---- epilogue: GLU + residual (f32); LN over 128 channels
    float* ug = ws + OFF_U + (size_t)b * H_ * L_;
    float lwv[2][4], lbv[2][4];
    #pragma unroll
    for (int oa = 0; oa < 2; ++oa)
        #pragma unroll
        for (int r = 0; r < 4; ++r) {
            int hh = layer * 128 + w * 32 + oa * 16 + g4 * 4 + r;
            lwv[oa][r] = ln_w[hh]; lbv[oa][r] = ln_b[hh];
        }

    #pragma unroll
    for (int nt = 0; nt < 4; ++nt) {
        int l = l0 + nt * 16 + ncol;
        float s = 0.f, q = 0.f;
        #pragma unroll
        for (int oa = 0; oa < 2; ++oa)
            #pragma unroll
            for (int r = 0; r < 4; ++r) {
                int h = w * 32 + oa * 16 + g4 * 4 + r;
                float a = dA[oa][nt][r], g = dG[oa][nt][r];
                float val = a / (1.0f + expf(-g)) + ug[(size_t)h * L_ + l];
                dA[oa][nt][r] = val;
                s += val; q += val * val;
            }
        s += __shfl_xor(s, 16, 64); q += __shfl_xor(q, 16, 64);
        s += __shfl_xor(s, 32, 64); q += __shfl_xor(q, 32, 64);
        if (g4 == 0) { wsum[w][nt * 16 + ncol] = s; wsq[w][nt * 16 + ncol] = q; }
    }
    __syncthreads();

    #pragma unroll
    for (int nt = 0; nt < 4; ++nt) {
        int ll = nt * 16 + ncol;
        int l  = l0 + ll;
        float S = wsum[0][ll] + wsum[1][ll] + wsum[2][ll] + wsum[3][ll];
        float Q = wsq[0][ll] + wsq[1][ll] + wsq[2][ll] + wsq[3][ll];
        float mu = S * (1.0f / 128.0f);
        float var = Q * (1.0f / 128.0f) - mu * mu;
        float rstd = rsqrtf(var + 1e-5f);
        #pragma unroll
        for (int oa = 0; oa < 2; ++oa)
            #pragma unroll
            for (int r = 0; r < 4; ++r) {
                int h = w * 32 + oa * 16 + g4 * 4 + r;
                float v = (dA[oa][nt][r] - mu) * rstd * lwv[oa][r] + lbv[oa][r];
                ug[(size_t)h * L_ + l] = v;
            }
    }
}

// ---------------------------------------------------------------------------
// Mean-pool over L per (b,h)
// ---------------------------------------------------------------------------
__global__ __launch_bounds__(256) void pool_kernel(float* ws) {
    int bh = blockIdx.x;
    const float* u = ws + OFF_U + (size_t)bh * L_;
    int t = threadIdx.x;
    float s = 0.0f;
    for (int i = t; i < L_; i += 256) s += u[i];
    #pragma unroll
    for (int m = 1; m <= 32; m <<= 1) s += __shfl_xor(s, m, 64);
    __shared__ float part[4];
    if ((t & 63) == 0) part[t >> 6] = s;
    __syncthreads();
    if (t == 0) ws[OFF_PL + bh] = (part[0] + part[1] + part[2] + part[3]) * (1.0f / L_);
}

// ---------------------------------------------------------------------------
// Decoder (f32 out)
// ---------------------------------------------------------------------------
__global__ __launch_bounds__(256) void decode_kernel(const float* dec_w, const float* dec_b,
                                                     const float* ws, float* out) {
    int t = threadIdx.x;
    int b = t >> 3, o = t & 7;
    const float* p = ws + OFF_PL + b * 128;
    float acc = dec_b[o];
    for (int h = 0; h < 128; ++h) acc += p[h] * dec_w[o * 128 + h];
    out[t] = 1.0f / (1.0f + expf(-acc));
}

// ---------------------------------------------------------------------------
// emb output: out[b][l][h] = u[b][h][l]  (f32, LDS tile transpose)
// ---------------------------------------------------------------------------
__global__ __launch_bounds__(256) void emb_out(const float* uws, float* out) {
    __shared__ float T[32 * 65];
    int t  = threadIdx.x;
    int bi = blockIdx.x;
    int lt = bi & 63;
    int ht = (bi >> 6) & 3;
    int b  = bi >> 8;
    int l0 = lt * 64, h0 = ht * 32;
    const float* u = uws + ((size_t)b * H_ + h0) * L_ + l0;
    #pragma unroll
    for (int p = 0; p < 8; ++p) {
        int rr = p * 4 + (t >> 6), cc = t & 63;
        T[rr * 65 + cc] = u[(size_t)rr * L_ + cc];
    }
    __syncthreads();
    #pragma unroll
    for (int q = 0; q < 8; ++q) {
        int hh = t & 31, ll = (t >> 5) + q * 8;
        out[((size_t)(b * L_) + l0 + ll) * H_ + h0 + hh] = T[hh * 65 + ll];
    }
}

// ---------------------------------------------------------------------------
extern "C" void kernel_launch(void* const* d_in, const int* in_sizes, int n_in,
                              void* d_out, int out_size, void* d_ws, size_t ws_size,
                              hipStream_t stream) {
    const float* x          = (const float*)d_in[0];
    const float* enc_w      = (const float*)d_in[2];
    const float* enc_b      = (const float*)d_in[3];
    const float* log_dt     = (const float*)d_in[4];
    const float* log_A_real = (const float*)d_in[5];
    const float* A_imag     = (const float*)d_in[6];
    const float* C_re       = (const float*)d_in[7];
    const float* C_im       = (const float*)d_in[8];
    const float* Dp         = (const float*)d_in[9];
    const float* conv_w     = (const float*)d_in[10];
    const float* conv_b     = (const float*)d_in[11];
    const float* ln_w       = (const float*)d_in[12];
    const float* ln_b       = (const float*)d_in[13];
    const float* dec_w      = (const float*)d_in[14];
    const float* dec_b      = (const float*)d_in[15];
    float* ws = (float*)d_ws;
    float* out = (float*)d_out;

    prep_tables<<<(NL_ * H_ * N2_ + 255) / 256, 256, 0, stream>>>(log_dt, log_A_real, A_imag,
                                                                  C_re, C_im, ws);
    compute_k<<<(NL_ * H_ * 64 + 255) / 256, 256, 0, stream>>>(ws);
    prep_tkf<<<(NL_ * H_ * 64 + 255) / 256, 256, 0, stream>>>(ws);
    prep_wbf<<<(NL_ * 256 * 128) / 256, 256, 0, stream>>>(conv_w, ws);
    encoder_kernel<<<B_ * (L_ / 256), 256, 0, stream>>>(x, enc_w, enc_b, ws);
    for (int l = 0; l < NL_; ++l) {
        s4d_mfma<<<B_ * H_, 256, 0, stream>>>(Dp, ws, l);
        conv_glu_ln_mfma<<<B_ * (L_ / 64), 256, 0, stream>>>(conv_b, ln_w, ln_b, ws, l);
    }
    pool_kernel<<<B_ * H_, 256, 0, stream>>>(ws);
    decode_kernel<<<1, 256, 0, stream>>>(dec_w, dec_b, ws, out);
    emb_out<<<B_ * 4 * 64, 256, 0, stream>>>(ws + OFF_U, out + 256);
}

// Round 8
// 457.017 us; speedup vs baseline: 24.7010x; 1.0703x over previous
//
#include <hip/hip_runtime.h>
#include <hip/hip_bf16.h>

#define B_ 32
#define L_ 4096
#define DIN 16
#define H_ 128
#define N2_ 32
#define NL_ 4
#define CL 64
#define NC 64

// ---- workspace layout (float slots) ----
#define OFF_U   ((size_t)0)                   // u f32, [b][h][l]
#define SZ_U    ((size_t)B_*H_*L_)
#define OFF_Y   (OFF_U + SZ_U)                // y bf16 (u16), [b][h][l]
#define SZ_Y    ((size_t)B_*H_*L_/2)
#define OFF_T1  (OFF_Y + SZ_Y)                // f32 [lh][e][np] for compute_k
#define SZ_T1   ((size_t)NL_*H_*64*64)
#define OFF_K   (OFF_T1 + SZ_T1)
#define SZ_K    ((size_t)NL_*H_*64)
#define OFF_CP  (OFF_K + SZ_K)
#define SZ_CP   ((size_t)NL_*H_*64)
#define OFF_W64 (OFF_CP + SZ_CP)
#define SZ_W64  ((size_t)NL_*H_*64)
#define OFF_W5  (OFF_W64 + SZ_W64)            // w^512 [lh][n][2]
#define SZ_W5   ((size_t)NL_*H_*64)
#define OFF_PL  (OFF_W5 + SZ_W5)
#define SZ_PL   ((size_t)B_*H_)
#define OFF_WB  (OFF_PL + SZ_PL)
#define SZ_WB   ((size_t)NL_*256*128/2)
// frag tables: per (lh): 8192 u16 = 4096 float slots. layout: (k>>3)*1024 + col*16 + (k&7), +8 = lo
#define OFF_T1F (OFF_WB + SZ_WB)
#define SZ_TF   ((size_t)NL_*H_*4096)
#define OFF_TKF (OFF_T1F + SZ_TF)
#define OFF_T2F (OFF_TKF + SZ_TF)

#define ZP 72   // u16 pitch, z/G hi-lo LDS
#define EP 68   // f32 pitch, E LDS

typedef __bf16 bf16_t;
typedef bf16_t bf16x8 __attribute__((ext_vector_type(8)));
typedef float f32x4 __attribute__((ext_vector_type(4)));
typedef unsigned short u16x8 __attribute__((ext_vector_type(8)));

#define MFMA(a, b, c) __builtin_amdgcn_mfma_f32_16x16x32_bf16(a, b, c, 0, 0, 0)
#define BCB(v) __builtin_bit_cast(bf16x8, v)

__device__ __forceinline__ unsigned short f2bf(float f) {
    return __builtin_bit_cast(unsigned short, (__bf16)f);   // native RNE cvt
}
__device__ __forceinline__ float bf2f(unsigned short u) {
    return __builtin_bit_cast(float, (unsigned int)u << 16);
}
__device__ __forceinline__ void store_hl(unsigned short* p, int idx, float v) {
    unsigned short hi = f2bf(v);
    p[idx]     = hi;
    p[idx + 8] = f2bf(v - bf2f(hi));
}
// yt[l][h] XOR swizzle (u16 index); h must be mult of 8 for 16B access
__device__ __forceinline__ int yswz(int l, int h) {
    return (l * 128 + h) ^ ((l & 7) << 3);
}

// ---------------------------------------------------------------------------
// P0a: w=exp(dtA), C'=(C)(w-1)/A; T1 f32; T1F/T2F frag tables; w64, w512
// ---------------------------------------------------------------------------
__global__ __launch_bounds__(256) void prep_tables(const float* log_dt, const float* log_A_real,
                                                   const float* A_imag, const float* C_re,
                                                   const float* C_im, float* ws) {
    int idx = blockIdx.x * 256 + threadIdx.x;        // (l,h,n)
    if (idx >= NL_ * H_ * N2_) return;
    int n  = idx & 31;
    int lh = idx >> 5;

    float dt  = expf(log_dt[lh]);
    float Are = -expf(log_A_real[idx]);
    float Aim = A_imag[idx];
    float dre = Are * dt, dim = Aim * dt;
    float er  = expf(dre);
    float wre = er * cosf(dim), wim = er * sinf(dim);
    float nre = wre - 1.0f, nim = wim;
    float den = Are * Are + Aim * Aim;
    float qre = (nre * Are + nim * Aim) / den;
    float qim = (nim * Are - nre * Aim) / den;
    float cre = C_re[idx], cim = C_im[idx];
    float Cpre = cre * qre - cim * qim;
    float Cpim = cre * qim + cim * qre;

    float* t1  = ws + OFF_T1  + (size_t)lh * 4096;
    float* cp  = ws + OFF_CP  + (size_t)lh * 64;
    float* w64 = ws + OFF_W64 + (size_t)lh * 64;
    float* w5  = ws + OFF_W5  + (size_t)lh * 64;
    unsigned short* t1f = (unsigned short*)(ws + OFF_T1F) + (size_t)lh * 8192;
    unsigned short* t2f = (unsigned short*)(ws + OFF_T2F) + (size_t)lh * 8192;
    cp[2 * n] = Cpre; cp[2 * n + 1] = Cpim;

    float pr = 1.0f, pi = 0.0f;                      // w^0
    for (int e = 0; e < 64; ++e) {
        t1[e * 64 + 2 * n]     = pr;
        t1[e * 64 + 2 * n + 1] = pi;
        int k1 = 63 - e;                             // T1F[k=63-e][np] = w^e
        store_hl(t1f, (k1 >> 3) * 1024 + (2 * n) * 16 + (k1 & 7), pr);
        store_hl(t1f, (k1 >> 3) * 1024 + (2 * n + 1) * 16 + (k1 & 7), pi);
        float npr = pr * wre - pi * wim;
        float npi = pr * wim + pi * wre;
        pr = npr; pi = npi;                          // w^{e+1}
        store_hl(t2f, ((2 * n) >> 3) * 1024 + e * 16 + ((2 * n) & 7), pr);
        store_hl(t2f, ((2 * n + 1) >> 3) * 1024 + e * 16 + ((2 * n + 1) & 7), pi);
    }
    w64[2 * n] = pr; w64[2 * n + 1] = pi;
    // w^512 = ((w64^2)^2)^2
    float ar = pr, ai = pi;
    #pragma unroll
    for (int q = 0; q < 3; ++q) {
        float nr = ar * ar - ai * ai;
        float ni = 2.0f * ar * ai;
        ar = nr; ai = ni;
    }
    w5[2 * n] = ar; w5[2 * n + 1] = ai;
}

// ---------------------------------------------------------------------------
// P0b: k[h][s] = 2*Re( sum_n C'_n w_n^s )
// ---------------------------------------------------------------------------
__global__ __launch_bounds__(256) void compute_k(float* ws) {
    int idx = blockIdx.x * 256 + threadIdx.x;        // (l,h,s)
    if (idx >= NL_ * H_ * 64) return;
    int s  = idx & 63;
    int lh = idx >> 6;
    const float* t1 = ws + OFF_T1 + (size_t)lh * 4096 + (size_t)s * 64;
    const float* cp = ws + OFF_CP + (size_t)lh * 64;
    float acc = 0.0f;
    #pragma unroll
    for (int n = 0; n < 32; ++n)
        acc += cp[2 * n] * t1[2 * n] - cp[2 * n + 1] * t1[2 * n + 1];
    ws[OFF_K + (size_t)lh * 64 + s] = 2.0f * acc;
}

// ---------------------------------------------------------------------------
// P0c: Toeplitz frag table TKF[s][tau] = (tau>=s) ? k[tau-s] : 0
// ---------------------------------------------------------------------------
__global__ __launch_bounds__(256) void prep_tkf(float* ws) {
    int idx = blockIdx.x * 256 + threadIdx.x;        // (lh, s)
    if (idx >= NL_ * H_ * 64) return;
    int s  = idx & 63;
    int lh = idx >> 6;
    const float* kp = ws + OFF_K + (size_t)lh * 64;
    unsigned short* dst = (unsigned short*)(ws + OFF_TKF) + (size_t)lh * 8192;
    int rb = (s >> 3) * 1024 + (s & 7);
    for (int tau = 0; tau < 64; ++tau) {
        float v = (tau >= s) ? kp[tau - s] : 0.0f;
        store_hl(dst, rb + tau * 16, v);
    }
}

// ---------------------------------------------------------------------------
// P0d: conv_w -> bf16
// ---------------------------------------------------------------------------
__global__ __launch_bounds__(256) void prep_wbf(const float* conv_w, float* ws) {
    int i = blockIdx.x * 256 + threadIdx.x;
    ((unsigned short*)(ws + OFF_WB))[i] = f2bf(conv_w[i]);
}

// ---------------------------------------------------------------------------
// Encoder -> u f32
// ---------------------------------------------------------------------------
__global__ __launch_bounds__(256) void encoder_kernel(const float* x, const float* enc_w,
                                                      const float* enc_b, float* ws) {
    __shared__ float wlds[H_ * DIN];
    __shared__ float blds[H_];
    int t  = threadIdx.x;
    int b  = blockIdx.x >> 4;
    int l0 = (blockIdx.x & 15) * 256;
    for (int i = t; i < H_ * DIN; i += 256) wlds[i] = enc_w[i];
    if (t < H_) blds[t] = enc_b[t];
    float xr[16];
    const float* xp = x + ((size_t)b * L_ + l0 + t) * DIN;
    #pragma unroll
    for (int d = 0; d < 16; ++d) xr[d] = xp[d];
    __syncthreads();
    float* u = ws + OFF_U + (size_t)b * H_ * L_ + l0 + t;
    for (int h = 0; h < H_; ++h) {
        float acc = blds[h];
        #pragma unroll
        for (int d = 0; d < 16; ++d) acc += xr[d] * wlds[h * 16 + d];
        u[(size_t)h * L_] = acc;
    }
}

// ---------------------------------------------------------------------------
// S4D via split-bf16 MFMA. One block per (b,h).
// Parallel 3-level cross-chunk scan: 256 threads = 32 n x 8 octaves.
// ---------------------------------------------------------------------------
__global__ __launch_bounds__(256) void s4d_mfma(const float* Dp, float* ws, int layer) {
    __shared__ unsigned short zsh[64 * ZP];   // z hi, then G hi
    __shared__ unsigned short zsl[64 * ZP];   // z lo, then G lo
    __shared__ float eg[64 * EP];             // E (f32)
    __shared__ float tex[8][64];              // octave totals (complex packed [o][2n])
    __shared__ float bex[8][64];              // exclusive octave bases

    int t  = threadIdx.x;
    int b  = blockIdx.x >> 7;
    int h  = blockIdx.x & 127;
    int lh = layer * H_ + h;
    int w  = t >> 6;
    int l  = t & 63;
    int lr = l & 15;
    int lg = l >> 4;

    const float* ug = ws + OFF_U + ((size_t)b * H_ + h) * L_;

    // stage z: f32 -> hi/lo (16 consecutive elements per thread)
    {
        int base = t * 16;
        int c = base >> 6, s0 = base & 63;
        u16x8 hh0, hh1, ll0, ll1;
        #pragma unroll
        for (int j = 0; j < 8; ++j) {
            float f = ug[base + j];
            unsigned short hi = f2bf(f);
            hh0[j] = hi; ll0[j] = f2bf(f - bf2f(hi));
        }
        #pragma unroll
        for (int j = 0; j < 8; ++j) {
            float f = ug[base + 8 + j];
            unsigned short hi = f2bf(f);
            hh1[j] = hi; ll1[j] = f2bf(f - bf2f(hi));
        }
        *(u16x8*)&zsh[c * ZP + s0]     = hh0;
        *(u16x8*)&zsh[c * ZP + s0 + 8] = hh1;
        *(u16x8*)&zsl[c * ZP + s0]     = ll0;
        *(u16x8*)&zsl[c * ZP + s0 + 8] = ll1;
    }

    // preload B-frags (global, L2-hot): T1F + TKF, kblk 0/1
    const unsigned short* t1f = (const unsigned short*)(ws + OFF_T1F) + (size_t)lh * 8192;
    const unsigned short* tkf = (const unsigned short*)(ws + OFF_TKF) + (size_t)lh * 8192;
    const unsigned short* t2f = (const unsigned short*)(ws + OFF_T2F) + (size_t)lh * 8192;
    int bo = lg * 1024 + (w * 16 + lr) * 16;
    bf16x8 T1h0 = BCB(*(const u16x8*)&t1f[bo]);
    bf16x8 T1l0 = BCB(*(const u16x8*)&t1f[bo + 8]);
    bf16x8 T1h1 = BCB(*(const u16x8*)&t1f[bo + 4096]);
    bf16x8 T1l1 = BCB(*(const u16x8*)&t1f[bo + 4096 + 8]);
    bf16x8 TKh0 = BCB(*(const u16x8*)&tkf[bo]);
    bf16x8 TKl0 = BCB(*(const u16x8*)&tkf[bo + 8]);
    bf16x8 TKh1 = BCB(*(const u16x8*)&tkf[bo + 4096]);
    bf16x8 TKl1 = BCB(*(const u16x8*)&tkf[bo + 4096 + 8]);

    f32x4 accE[4], accC[4];
    #pragma unroll
    for (int ct = 0; ct < 4; ++ct) { accE[ct] = (f32x4)0.0f; accC[ct] = (f32x4)0.0f; }

    __syncthreads();

    // ---- Pass A: E = z x T1F ; Yconv = z x TKF
    #pragma unroll
    for (int ct = 0; ct < 4; ++ct) {
        int ar = (ct * 16 + lr) * ZP;
        bf16x8 ah0 = BCB(*(const u16x8*)&zsh[ar + lg * 8]);
        bf16x8 al0 = BCB(*(const u16x8*)&zsl[ar + lg * 8]);
        bf16x8 ah1 = BCB(*(const u16x8*)&zsh[ar + 32 + lg * 8]);
        bf16x8 al1 = BCB(*(const u16x8*)&zsl[ar + 32 + lg * 8]);
        accE[ct] = MFMA(ah0, T1h0, accE[ct]);
        accE[ct] = MFMA(al0, T1h0, accE[ct]);
        accE[ct] = MFMA(ah0, T1l0, accE[ct]);
        accE[ct] = MFMA(ah1, T1h1, accE[ct]);
        accE[ct] = MFMA(al1, T1h1, accE[ct]);
        accE[ct] = MFMA(ah1, T1l1, accE[ct]);
        accC[ct] = MFMA(ah0, TKh0, accC[ct]);
        accC[ct] = MFMA(al0, TKh0, accC[ct]);
        accC[ct] = MFMA(ah0, TKl0, accC[ct]);
        accC[ct] = MFMA(ah1, TKh1, accC[ct]);
        accC[ct] = MFMA(al1, TKh1, accC[ct]);
        accC[ct] = MFMA(ah1, TKl1, accC[ct]);
    }
    // write E (D-frag: row=(lg*4+r), col=lr)
    #pragma unroll
    for (int ct = 0; ct < 4; ++ct)
        #pragma unroll
        for (int r = 0; r < 4; ++r)
            eg[(ct * 16 + lg * 4 + r) * EP + w * 16 + lr] = accE[ct][r];

    // preload T2F frags; pre-extract epilogue z (zsh/zsl reused for G after)
    bf16x8 T2h0 = BCB(*(const u16x8*)&t2f[bo]);
    bf16x8 T2l0 = BCB(*(const u16x8*)&t2f[bo + 8]);
    bf16x8 T2h1 = BCB(*(const u16x8*)&t2f[bo + 4096]);
    bf16x8 T2l1 = BCB(*(const u16x8*)&t2f[bo + 4096 + 8]);
    float zep[16];
    #pragma unroll
    for (int ct = 0; ct < 4; ++ct)
        #pragma unroll
        for (int r = 0; r < 4; ++r) {
            int c = ct * 16 + lg * 4 + r, tau = w * 16 + lr;
            zep[ct * 4 + r] = bf2f(zsh[c * ZP + tau]) + bf2f(zsl[c * ZP + tau]);
        }
    __syncthreads();

    // ---- Parallel scan: thread = (n = t&31, oct = t>>5); 8 chunks each
    {
        int n   = t & 31;
        int oct = t >> 5;
        const float* cp   = ws + OFF_CP  + (size_t)lh * 64;
        const float* w64p = ws + OFF_W64 + (size_t)lh * 64;
        const float* w5p  = ws + OFF_W5  + (size_t)lh * 64;
        float cre = cp[2 * n], cim = cp[2 * n + 1];
        float wr  = w64p[2 * n], wi = w64p[2 * n + 1];
        float2 e[8];
        float sre = 0.f, sim = 0.f;
        #pragma unroll
        for (int j = 0; j < 8; ++j) {                 // local octave scan
            e[j] = *(const float2*)&eg[(8 * oct + j) * EP + 2 * n];
            float nr = fmaf(wr, sre, fmaf(-wi, sim, e[j].x));
            float ni = fmaf(wr, sim, fmaf(wi, sre, e[j].y));
            sre = nr; sim = ni;
        }
        *(float2*)&tex[oct][2 * n] = make_float2(sre, sim);
        __syncthreads();
        if (t < 32) {                                 // exclusive base scan over octaves
            float Wr = w5p[2 * n], Wi = w5p[2 * n + 1];
            float br = 0.f, bi = 0.f;
            #pragma unroll
            for (int o = 0; o < 8; ++o) {
                *(float2*)&bex[o][2 * n] = make_float2(br, bi);
                float2 T = *(const float2*)&tex[o][2 * n];
                float nr = fmaf(Wr, br, fmaf(-Wi, bi, T.x));
                float ni = fmaf(Wr, bi, fmaf(Wi, br, T.y));
                br = nr; bi = ni;
            }
        }
        __syncthreads();
        float2 Sb = *(const float2*)&bex[oct][2 * n];
        sre = Sb.x; sim = Sb.y;
        #pragma unroll
        for (int j = 0; j < 8; ++j) {                 // replay: emit G hi/lo
            int c = 8 * oct + j;
            float gre = 2.0f * (cre * sre - cim * sim);
            float gim = -2.0f * (cre * sim + cim * sre);
            unsigned short g0 = f2bf(gre);
            unsigned short g1 = f2bf(gim);
            zsh[c * ZP + 2 * n]     = g0;
            zsh[c * ZP + 2 * n + 1] = g1;
            zsl[c * ZP + 2 * n]     = f2bf(gre - bf2f(g0));
            zsl[c * ZP + 2 * n + 1] = f2bf(gim - bf2f(g1));
            float nr = fmaf(wr, sre, fmaf(-wi, sim, e[j].x));
            float ni = fmaf(wr, sim, fmaf(wi, sre, e[j].y));
            sre = nr; sim = ni;
        }
    }
    float Dh = Dp[lh];
    __syncthreads();

    // ---- Pass B: Y += G x T2F
    #pragma unroll
    for (int ct = 0; ct < 4; ++ct) {
        int ar = (ct * 16 + lr) * ZP;
        bf16x8 gh0 = BCB(*(const u16x8*)&zsh[ar + lg * 8]);
        bf16x8 gl0 = BCB(*(const u16x8*)&zsl[ar + lg * 8]);
        bf16x8 gh1 = BCB(*(const u16x8*)&zsh[ar + 32 + lg * 8]);
        bf16x8 gl1 = BCB(*(const u16x8*)&zsl[ar + 32 + lg * 8]);
        accC[ct] = MFMA(gh0, T2h0, accC[ct]);
        accC[ct] = MFMA(gl0, T2h0, accC[ct]);
        accC[ct] = MFMA(gh0, T2l0, accC[ct]);
        accC[ct] = MFMA(gh1, T2h1, accC[ct]);
        accC[ct] = MFMA(gl1, T2h1, accC[ct]);
        accC[ct] = MFMA(gh1, T2l1, accC[ct]);
    }

    // ---- epilogue: + D*z, GELU, store y bf16
    unsigned short* yb = (unsigned short*)(ws + OFF_Y) + ((size_t)b * H_ + h) * L_;
    #pragma unroll
    for (int ct = 0; ct < 4; ++ct)
        #pragma unroll
        for (int r = 0; r < 4; ++r) {
            float acc = fmaf(Dh, zep[ct * 4 + r], accC[ct][r]);
            float g = 0.5f * acc * (1.0f + erff(acc * 0.70710678118654752f));
            yb[(ct * 16 + lg * 4 + r) * 64 + w * 16 + lr] = f2bf(g);
        }
}

// ---------------------------------------------------------------------------
// Channel mix via bf16 MFMA + GLU + residual(f32) + LN. B-frags from
// transposed XOR-swizzled LDS yt[l][h]; vector b128 reads, balanced banks.
// ---------------------------------------------------------------------------
__global__ __launch_bounds__(256) void conv_glu_ln_mfma(const float* conv_b, const float* ln_w,
                                                        const float* ln_b, float* ws, int layer) {
    __shared__ unsigned short yt[64 * 128];   // [l][h], swizzled
    __shared__ float wsum[4][64];
    __shared__ float wsq[4][64];

    int t    = threadIdx.x;
    int b    = blockIdx.x >> 6;
    int l0   = (blockIdx.x & 63) * 64;
    int w    = t >> 6;
    int lam  = t & 63;
    int g4   = lam >> 4;
    int ncol = lam & 15;

    const unsigned short* yg = (const unsigned short*)(ws + OFF_Y) + (size_t)b * H_ * L_;
    const unsigned short* wb = (const unsigned short*)(ws + OFF_WB) + (size_t)layer * 256 * 128;

    // ---- stage y transposed: column loads (coalesced across lanes), b128 writes
    {
        int ll = t & 63;
        int hb = (t >> 6) * 32;
        const unsigned short* ycol = yg + l0 + ll;
        #pragma unroll
        for (int g = 0; g < 4; ++g) {
            u16x8 tmp;
            #pragma unroll
            for (int i = 0; i < 8; ++i)
                tmp[i] = ycol[(size_t)(hb + g * 8 + i) * L_];
            *(u16x8*)&yt[yswz(ll, hb + g * 8)] = tmp;
        }
    }

    // ---- bias init
    const float* cb = conv_b + layer * 256;
    f32x4 dA[2][4], dG[2][4];
    #pragma unroll
    for (int oa = 0; oa < 2; ++oa) {
        int ba = w * 32 + oa * 16 + g4 * 4;
        f32x4 bA, bG;
        #pragma unroll
        for (int r = 0; r < 4; ++r) { bA[r] = cb[ba + r]; bG[r] = cb[128 + ba + r]; }
        #pragma unroll
        for (int nt = 0; nt < 4; ++nt) { dA[oa][nt] = bA; dG[oa][nt] = bG; }
    }
    __syncthreads();

    // ---- K loop: per kt, A-frags from global (L2), B-frags via b128 LDS reads
    #pragma unroll
    for (int kt = 0; kt < 4; ++kt) {
        bf16x8 aAk[2], aGk[2];
        #pragma unroll
        for (int oa = 0; oa < 2; ++oa) {
            int oA = w * 32 + oa * 16 + ncol;
            aAk[oa] = BCB(*(const u16x8*)&wb[(size_t)oA * 128 + kt * 32 + g4 * 8]);
            aGk[oa] = BCB(*(const u16x8*)&wb[(size_t)(128 + oA) * 128 + kt * 32 + g4 * 8]);
        }
        #pragma unroll
        for (int nt = 0; nt < 4; ++nt) {
            bf16x8 bfr = BCB(*(const u16x8*)&yt[yswz(nt * 16 + ncol, kt * 32 + g4 * 8)]);
            #pragma unroll
            for (int oa = 0; oa < 2; ++oa) {
                dA[oa][nt] = MFMA(aAk[oa], bfr, dA[oa][nt]);
                dG[oa][nt] = MFMA(aGk[oa], bfr, dG[oa][nt]);
            }
        }
    }

    // ---- epilogue: GLU + residual (f32); LN over 128 channels
    float* ug = ws + OFF_U + (size_t)b * H_ * L_;
    float lwv[2][4], lbv[2][4];
    #pragma unroll
    for (int oa = 0; oa < 2; ++oa)
        #pragma unroll
        for (int r = 0; r < 4; ++r) {
            int hh = layer * 128 + w * 32 + oa * 16 + g4 * 4 + r;
            lwv[oa][r] = ln_w[hh]; lbv[oa][r] = ln_b[hh];
        }

    #pragma unroll
    for (int nt = 0; nt < 4; ++nt) {
        int l = l0 + nt * 16 + ncol;
        float s = 0.f, q = 0.f;
        #pragma unroll
        for (int oa = 0; oa < 2; ++oa)
            #pragma unroll
            for (int r = 0; r < 4; ++r) {
                int h = w * 32 + oa * 16 + g4 * 4 + r;
                float a = dA[oa][nt][r], g = dG[oa][nt][r];
                float val = a / (1.0f + expf(-g)) + ug[(size_t)h * L_ + l];
                dA[oa][nt][r] = val;
                s += val; q += val * val;
            }
        s += __shfl_xor(s, 16, 64); q += __shfl_xor(q, 16, 64);
        s += __shfl_xor(s, 32, 64); q += __shfl_xor(q, 32, 64);
        if (g4 == 0) { wsum[w][nt * 16 + ncol] = s; wsq[w][nt * 16 + ncol] = q; }
    }
    __syncthreads();

    #pragma unroll
    for (int nt = 0; nt < 4; ++nt) {
        int ll = nt * 16 + ncol;
        int l  = l0 + ll;
        float S = wsum[0][ll] + wsum[1][ll] + wsum[2][ll] + wsum[3][ll];
        float Q = wsq[0][ll] + wsq[1][ll] + wsq[2][ll] + wsq[3][ll];
        float mu = S * (1.0f / 128.0f);
        float var = Q * (1.0f / 128.0f) - mu * mu;
        float rstd = rsqrtf(var + 1e-5f);
        #pragma unroll
        for (int oa = 0; oa < 2; ++oa)
            #pragma unroll
            for (int r = 0; r < 4; ++r) {
                int h = w * 32 + oa * 16 + g4 * 4 + r;
                float v = (dA[oa][nt][r] - mu) * rstd * lwv[oa][r] + lbv[oa][r];
                ug[(size_t)h * L_ + l] = v;
            }
    }
}

// ---------------------------------------------------------------------------
// Mean-pool over L per (b,h)
// ---------------------------------------------------------------------------
__global__ __launch_bounds__(256) void pool_kernel(float* ws) {
    int bh = blockIdx.x;
    const float* u = ws + OFF_U + (size_t)bh * L_;
    int t = threadIdx.x;
    float s = 0.0f;
    for (int i = t; i < L_; i += 256) s += u[i];
    #pragma unroll
    for (int m = 1; m <= 32; m <<= 1) s += __shfl_xor(s, m, 64);
    __shared__ float part[4];
    if ((t & 63) == 0) part[t >> 6] = s;
    __syncthreads();
    if (t == 0) ws[OFF_PL + bh] = (part[0] + part[1] + part[2] + part[3]) * (1.0f / L_);
}

// ---------------------------------------------------------------------------
// Decoder (f32 out)
// ---------------------------------------------------------------------------
__global__ __launch_bounds__(256) void decode_kernel(const float* dec_w, const float* dec_b,
                                                     const float* ws, float* out) {
    int t = threadIdx.x;
    int b = t >> 3, o = t & 7;
    const float* p = ws + OFF_PL + b * 128;
    float acc = dec_b[o];
    for (int h = 0; h < 128; ++h) acc += p[h] * dec_w[o * 128 + h];
    out[t] = 1.0f / (1.0f + expf(-acc));
}

// ---------------------------------------------------------------------------
// emb output: out[b][l][h] = u[b][h][l]  (f32, LDS tile transpose)
// ---------------------------------------------------------------------------
__global__ __launch_bounds__(256) void emb_out(const float* uws, float* out) {
    __shared__ float T[32 * 65];
    int t  = threadIdx.x;
    int bi = blockIdx.x;
    int lt = bi & 63;
    int ht = (bi >> 6) & 3;
    int b  = bi >> 8;
    int l0 = lt * 64, h0 = ht * 32;
    const float* u = uws + ((size_t)b * H_ + h0) * L_ + l0;
    #pragma unroll
    for (int p = 0; p < 8; ++p) {
        int rr = p * 4 + (t >> 6), cc = t & 63;
        T[rr * 65 + cc] = u[(size_t)rr * L_ + cc];
    }
    __syncthreads();
    #pragma unroll
    for (int q = 0; q < 8; ++q) {
        int hh = t & 31, ll = (t >> 5) + q * 8;
        out[((size_t)(b * L_) + l0 + ll) * H_ + h0 + hh] = T[hh * 65 + ll];
    }
}

// ---------------------------------------------------------------------------
extern "C" void kernel_launch(void* const* d_in, const int* in_sizes, int n_in,
                              void* d_out, int out_size, void* d_ws, size_t ws_size,
                              hipStream_t stream) {
    const float* x          = (const float*)d_in[0];
    const float* enc_w      = (const float*)d_in[2];
    const float* enc_b      = (const float*)d_in[3];
    const float* log_dt     = (const float*)d_in[4];
    const float* log_A_real = (const float*)d_in[5];
    const float* A_imag     = (const float*)d_in[6];
    const float* C_re       = (const float*)d_in[7];
    const float* C_im       = (const float*)d_in[8];
    const float* Dp         = (const float*)d_in[9];
    const float* conv_w     = (const float*)d_in[10];
    const float* conv_b     = (const float*)d_in[11];
    const float* ln_w       = (const float*)d_in[12];
    const float* ln_b       = (const float*)d_in[13];
    const float* dec_w      = (const float*)d_in[14];
    const float* dec_b      = (const float*)d_in[15];
    float* ws = (float*)d_ws;
    float* out = (float*)d_out;

    prep_tables<<<(NL_ * H_ * N2_ + 255) / 256, 256, 0, stream>>>(log_dt, log_A_real, A_imag,
                                                                  C_re, C_im, ws);
    compute_k<<<(NL_ * H_ * 64 + 255) / 256, 256, 0, stream>>>(ws);
    prep_tkf<<<(NL_ * H_ * 64 + 255) / 256, 256, 0, stream>>>(ws);
    prep_wbf<<<(NL_ * 256 * 128) / 256, 256, 0, stream>>>(conv_w, ws);
    encoder_kernel<<<B_ * (L_ / 256), 256, 0, stream>>>(x, enc_w, enc_b, ws);
    for (int l = 0; l < NL_; ++l) {
        s4d_mfma<<<B_ * H_, 256, 0, stream>>>(Dp, ws, l);
        conv_glu_ln_mfma<<<B_ * (L_ / 64), 256, 0, stream>>>(conv_b, ln_w, ln_b, ws, l);
    }
    pool_kernel<<<B_ * H_, 256, 0, stream>>>(ws);
    decode_kernel<<<1, 256, 0, stream>>>(dec_w, dec_b, ws, out);
    emb_out<<<B_ * 4 * 64, 256, 0, stream>>>(ws + OFF_U, out + 256);
}

// Round 9
// 431.164 us; speedup vs baseline: 26.1821x; 1.0600x over previous
//
#include <hip/hip_runtime.h>
#include <hip/hip_bf16.h>

#define B_ 32
#define L_ 4096
#define DIN 16
#define H_ 128
#define N2_ 32
#define NL_ 4
#define CL 64
#define NC 64

// ---- workspace layout (float slots) ----
#define OFF_U   ((size_t)0)                   // u f32, [b][h][l]
#define SZ_U    ((size_t)B_*H_*L_)
#define OFF_Y   (OFF_U + SZ_U)                // y bf16 (u16), [b][h][l]
#define SZ_Y    ((size_t)B_*H_*L_/2)
#define OFF_T1  (OFF_Y + SZ_Y)                // f32 [lh][e][np] for compute_k
#define SZ_T1   ((size_t)NL_*H_*64*64)
#define OFF_K   (OFF_T1 + SZ_T1)
#define SZ_K    ((size_t)NL_*H_*64)
#define OFF_CP  (OFF_K + SZ_K)
#define SZ_CP   ((size_t)NL_*H_*64)
#define OFF_W64 (OFF_CP + SZ_CP)
#define SZ_W64  ((size_t)NL_*H_*64)
#define OFF_W5  (OFF_W64 + SZ_W64)            // w^512 [lh][n][2]
#define SZ_W5   ((size_t)NL_*H_*64)
#define OFF_DTA (OFF_W5 + SZ_W5)              // (dre,dim,wre,wim) per (lh,n)
#define SZ_DTA  ((size_t)NL_*H_*N2_*4)
#define OFF_PL  (OFF_DTA + SZ_DTA)
#define SZ_PL   ((size_t)B_*H_)
#define OFF_WB  (OFF_PL + SZ_PL)
#define SZ_WB   ((size_t)NL_*256*128/2)
// frag tables: per (lh): 8192 u16 = 4096 float slots. layout: (k>>3)*1024 + col*16 + (k&7), +8 = lo
#define OFF_T1F (OFF_WB + SZ_WB)
#define SZ_TF   ((size_t)NL_*H_*4096)
#define OFF_TKF (OFF_T1F + SZ_TF)
#define OFF_T2F (OFF_TKF + SZ_TF)

#define ZP 72   // u16 pitch, z/G hi-lo LDS
#define EP 68   // f32 pitch, E LDS

typedef __bf16 bf16_t;
typedef bf16_t bf16x8 __attribute__((ext_vector_type(8)));
typedef float f32x4 __attribute__((ext_vector_type(4)));
typedef unsigned short u16x8 __attribute__((ext_vector_type(8)));

#define MFMA(a, b, c) __builtin_amdgcn_mfma_f32_16x16x32_bf16(a, b, c, 0, 0, 0)
#define BCB(v) __builtin_bit_cast(bf16x8, v)

__device__ __forceinline__ unsigned short f2bf(float f) {
    return __builtin_bit_cast(unsigned short, (__bf16)f);   // native RNE cvt
}
__device__ __forceinline__ float bf2f(unsigned short u) {
    return __builtin_bit_cast(float, (unsigned int)u << 16);
}
__device__ __forceinline__ void store_hl(unsigned short* p, int idx, float v) {
    unsigned short hi = f2bf(v);
    p[idx]     = hi;
    p[idx + 8] = f2bf(v - bf2f(hi));
}
// yt[l][h] XOR swizzle (u16 index); h must be mult of 8 for 16B access
__device__ __forceinline__ int yswz(int l, int h) {
    return (l * 128 + h) ^ ((l & 7) << 3);
}

// ---------------------------------------------------------------------------
// P0a: per (lh,n): C', dtA cache, w, w^64, w^512 (all direct, no serial chain)
// ---------------------------------------------------------------------------
__global__ __launch_bounds__(256) void prep_params(const float* log_dt, const float* log_A_real,
                                                   const float* A_imag, const float* C_re,
                                                   const float* C_im, float* ws) {
    int idx = blockIdx.x * 256 + threadIdx.x;        // (lh,n)
    if (idx >= NL_ * H_ * N2_) return;
    int n  = idx & 31;
    int lh = idx >> 5;

    float dt  = expf(log_dt[lh]);
    float Are = -expf(log_A_real[idx]);
    float Aim = A_imag[idx];
    float dre = Are * dt, dim = Aim * dt;
    float er  = expf(dre);
    float sw, cw; sincosf(dim, &sw, &cw);
    float wre = er * cw, wim = er * sw;
    float nre = wre - 1.0f, nim = wim;
    float den = Are * Are + Aim * Aim;
    float qre = (nre * Are + nim * Aim) / den;
    float qim = (nim * Are - nre * Aim) / den;
    float cre = C_re[idx], cim = C_im[idx];

    float* cp  = ws + OFF_CP  + (size_t)lh * 64;
    float* w64 = ws + OFF_W64 + (size_t)lh * 64;
    float* w5  = ws + OFF_W5  + (size_t)lh * 64;
    cp[2 * n]     = cre * qre - cim * qim;
    cp[2 * n + 1] = cre * qim + cim * qre;
    *((float4*)(ws + OFF_DTA) + (size_t)lh * 32 + n) = make_float4(dre, dim, wre, wim);

    // w^64 direct
    float e64 = expf(64.0f * dre);
    float s64, c64; sincosf(64.0f * dim, &s64, &c64);
    float ar = e64 * c64, ai = e64 * s64;
    w64[2 * n] = ar; w64[2 * n + 1] = ai;
    // w^512 = ((w64^2)^2)^2
    #pragma unroll
    for (int q = 0; q < 3; ++q) {
        float nr = ar * ar - ai * ai;
        float ni = 2.0f * ar * ai;
        ar = nr; ai = ni;
    }
    w5[2 * n] = ar; w5[2 * n + 1] = ai;
}

// ---------------------------------------------------------------------------
// P0b: per (lh,e,n): w^e direct -> t1 f32 + T1F frag; w^{e+1} -> T2F frag
// ---------------------------------------------------------------------------
__global__ __launch_bounds__(256) void prep_pow(float* ws) {
    int idx = blockIdx.x * 256 + threadIdx.x;        // lh*2048 + e*32 + n
    int n  = idx & 31;
    int e  = (idx >> 5) & 63;
    int lh = idx >> 11;
    float4 dw = *((const float4*)(ws + OFF_DTA) + (size_t)lh * 32 + n);
    float ew = expf((float)e * dw.x);
    float sn, cs; sincosf((float)e * dw.y, &sn, &cs);
    float pr = ew * cs, pi = ew * sn;

    float* t1 = ws + OFF_T1 + (size_t)lh * 4096;
    *(float2*)&t1[e * 64 + 2 * n] = make_float2(pr, pi);

    unsigned short* t1f = (unsigned short*)(ws + OFF_T1F) + (size_t)lh * 8192;
    unsigned short* t2f = (unsigned short*)(ws + OFF_T2F) + (size_t)lh * 8192;
    int k1 = 63 - e;                                 // T1F[k1][np] = w^e
    store_hl(t1f, (k1 >> 3) * 1024 + (2 * n) * 16 + (k1 & 7), pr);
    store_hl(t1f, (k1 >> 3) * 1024 + (2 * n + 1) * 16 + (k1 & 7), pi);
    float qr = pr * dw.z - pi * dw.w;                // w^{e+1}
    float qi = pr * dw.w + pi * dw.z;
    store_hl(t2f, ((2 * n) >> 3) * 1024 + e * 16 + ((2 * n) & 7), qr);
    store_hl(t2f, ((2 * n + 1) >> 3) * 1024 + e * 16 + ((2 * n + 1) & 7), qi);
}

// ---------------------------------------------------------------------------
// P0c: k[h][s] = 2*Re( sum_n C'_n w_n^s )
// ---------------------------------------------------------------------------
__global__ __launch_bounds__(256) void compute_k(float* ws) {
    int idx = blockIdx.x * 256 + threadIdx.x;        // (l,h,s)
    if (idx >= NL_ * H_ * 64) return;
    int s  = idx & 63;
    int lh = idx >> 6;
    const float* t1 = ws + OFF_T1 + (size_t)lh * 4096 + (size_t)s * 64;
    const float* cp = ws + OFF_CP + (size_t)lh * 64;
    float acc = 0.0f;
    #pragma unroll
    for (int n = 0; n < 32; ++n)
        acc += cp[2 * n] * t1[2 * n] - cp[2 * n + 1] * t1[2 * n + 1];
    ws[OFF_K + (size_t)lh * 64 + s] = 2.0f * acc;
}

// ---------------------------------------------------------------------------
// P0d: Toeplitz frag table TKF[s][tau] = (tau>=s) ? k[tau-s] : 0  (parallel)
// ---------------------------------------------------------------------------
__global__ __launch_bounds__(256) void prep_tkf(float* ws) {
    int idx = blockIdx.x * 256 + threadIdx.x;        // lh*4096 + s*64 + tau
    int tau = idx & 63;
    int s   = (idx >> 6) & 63;
    int lh  = idx >> 12;
    float v = (tau >= s) ? ws[OFF_K + (size_t)lh * 64 + (tau - s)] : 0.0f;
    unsigned short* dst = (unsigned short*)(ws + OFF_TKF) + (size_t)lh * 8192;
    store_hl(dst, (s >> 3) * 1024 + (s & 7) + tau * 16, v);
}

// ---------------------------------------------------------------------------
// P0e: conv_w -> bf16
// ---------------------------------------------------------------------------
__global__ __launch_bounds__(256) void prep_wbf(const float* conv_w, float* ws) {
    int i = blockIdx.x * 256 + threadIdx.x;
    ((unsigned short*)(ws + OFF_WB))[i] = f2bf(conv_w[i]);
}

// ---------------------------------------------------------------------------
// Encoder -> u f32
// ---------------------------------------------------------------------------
__global__ __launch_bounds__(256) void encoder_kernel(const float* x, const float* enc_w,
                                                      const float* enc_b, float* ws) {
    __shared__ float wlds[H_ * DIN];
    __shared__ float blds[H_];
    int t  = threadIdx.x;
    int b  = blockIdx.x >> 4;
    int l0 = (blockIdx.x & 15) * 256;
    for (int i = t; i < H_ * DIN; i += 256) wlds[i] = enc_w[i];
    if (t < H_) blds[t] = enc_b[t];
    float xr[16];
    const float* xp = x + ((size_t)b * L_ + l0 + t) * DIN;
    #pragma unroll
    for (int d = 0; d < 16; ++d) xr[d] = xp[d];
    __syncthreads();
    float* u = ws + OFF_U + (size_t)b * H_ * L_ + l0 + t;
    for (int h = 0; h < H_; ++h) {
        float acc = blds[h];
        #pragma unroll
        for (int d = 0; d < 16; ++d) acc += xr[d] * wlds[h * 16 + d];
        u[(size_t)h * L_] = acc;
    }
}

// ---------------------------------------------------------------------------
// S4D via split-bf16 MFMA. One block per (b,h).
// Parallel 3-level cross-chunk scan: 256 threads = 32 n x 8 octaves.
// ---------------------------------------------------------------------------
__global__ __launch_bounds__(256) void s4d_mfma(const float* Dp, float* ws, int layer) {
    __shared__ unsigned short zsh[64 * ZP];   // z hi, then G hi
    __shared__ unsigned short zsl[64 * ZP];   // z lo, then G lo
    __shared__ float eg[64 * EP];             // E (f32)
    __shared__ float tex[8][64];              // octave totals (complex packed [o][2n])
    __shared__ float bex[8][64];              // exclusive octave bases

    int t  = threadIdx.x;
    int b  = blockIdx.x >> 7;
    int h  = blockIdx.x & 127;
    int lh = layer * H_ + h;
    int w  = t >> 6;
    int l  = t & 63;
    int lr = l & 15;
    int lg = l >> 4;

    const float* ug = ws + OFF_U + ((size_t)b * H_ + h) * L_;

    // stage z: f32 -> hi/lo (16 consecutive elements per thread)
    {
        int base = t * 16;
        int c = base >> 6, s0 = base & 63;
        u16x8 hh0, hh1, ll0, ll1;
        #pragma unroll
        for (int j = 0; j < 8; ++j) {
            float f = ug[base + j];
            unsigned short hi = f2bf(f);
            hh0[j] = hi; ll0[j] = f2bf(f - bf2f(hi));
        }
        #pragma unroll
        for (int j = 0; j < 8; ++j) {
            float f = ug[base + 8 + j];
            unsigned short hi = f2bf(f);
            hh1[j] = hi; ll1[j] = f2bf(f - bf2f(hi));
        }
        *(u16x8*)&zsh[c * ZP + s0]     = hh0;
        *(u16x8*)&zsh[c * ZP + s0 + 8] = hh1;
        *(u16x8*)&zsl[c * ZP + s0]     = ll0;
        *(u16x8*)&zsl[c * ZP + s0 + 8] = ll1;
    }

    // preload B-frags (global, L2-hot): T1F + TKF, kblk 0/1
    const unsigned short* t1f = (const unsigned short*)(ws + OFF_T1F) + (size_t)lh * 8192;
    const unsigned short* tkf = (const unsigned short*)(ws + OFF_TKF) + (size_t)lh * 8192;
    const unsigned short* t2f = (const unsigned short*)(ws + OFF_T2F) + (size_t)lh * 8192;
    int bo = lg * 1024 + (w * 16 + lr) * 16;
    bf16x8 T1h0 = BCB(*(const u16x8*)&t1f[bo]);
    bf16x8 T1l0 = BCB(*(const u16x8*)&t1f[bo + 8]);
    bf16x8 T1h1 = BCB(*(const u16x8*)&t1f[bo + 4096]);
    bf16x8 T1l1 = BCB(*(const u16x8*)&t1f[bo + 4096 + 8]);
    bf16x8 TKh0 = BCB(*(const u16x8*)&tkf[bo]);
    bf16x8 TKl0 = BCB(*(const u16x8*)&tkf[bo + 8]);
    bf16x8 TKh1 = BCB(*(const u16x8*)&tkf[bo + 4096]);
    bf16x8 TKl1 = BCB(*(const u16x8*)&tkf[bo + 4096 + 8]);

    f32x4 accE[4], accC[4];
    #pragma unroll
    for (int ct = 0; ct < 4; ++ct) { accE[ct] = (f32x4)0.0f; accC[ct] = (f32x4)0.0f; }

    __syncthreads();

    // ---- Pass A: E = z x T1F ; Yconv = z x TKF
    #pragma unroll
    for (int ct = 0; ct < 4; ++ct) {
        int ar = (ct * 16 + lr) * ZP;
        bf16x8 ah0 = BCB(*(const u16x8*)&zsh[ar + lg * 8]);
        bf16x8 al0 = BCB(*(const u16x8*)&zsl[ar + lg * 8]);
        bf16x8 ah1 = BCB(*(const u16x8*)&zsh[ar + 32 + lg * 8]);
        bf16x8 al1 = BCB(*(const u16x8*)&zsl[ar + 32 + lg * 8]);
        accE[ct] = MFMA(ah0, T1h0, accE[ct]);
        accE[ct] = MFMA(al0, T1h0, accE[ct]);
        accE[ct] = MFMA(ah0, T1l0, accE[ct]);
        accE[ct] = MFMA(ah1, T1h1, accE[ct]);
        accE[ct] = MFMA(al1, T1h1, accE[ct]);
        accE[ct] = MFMA(ah1, T1l1, accE[ct]);
        accC[ct] = MFMA(ah0, TKh0, accC[ct]);
        accC[ct] = MFMA(al0, TKh0, accC[ct]);
        accC[ct] = MFMA(ah0, TKl0, accC[ct]);
        accC[ct] = MFMA(ah1, TKh1, accC[ct]);
        accC[ct] = MFMA(al1, TKh1, accC[ct]);
        accC[ct] = MFMA(ah1, TKl1, accC[ct]);
    }
    // write E (D-frag: row=(lg*4+r), col=lr)
    #pragma unroll
    for (int ct = 0; ct < 4; ++ct)
        #pragma unroll
        for (int r = 0; r < 4; ++r)
            eg[(ct * 16 + lg * 4 + r) * EP + w * 16 + lr] = accE[ct][r];

    // preload T2F frags; pre-extract epilogue z (zsh/zsl reused for G after)
    bf16x8 T2h0 = BCB(*(const u16x8*)&t2f[bo]);
    bf16x8 T2l0 = BCB(*(const u16x8*)&t2f[bo + 8]);
    bf16x8 T2h1 = BCB(*(const u16x8*)&t2f[bo + 4096]);
    bf16x8 T2l1 = BCB(*(const u16x8*)&t2f[bo + 4096 + 8]);
    float zep[16];
    #pragma unroll
    for (int ct = 0; ct < 4; ++ct)
        #pragma unroll
        for (int r = 0; r < 4; ++r) {
            int c = ct * 16 + lg * 4 + r, tau = w * 16 + lr;
            zep[ct * 4 + r] = bf2f(zsh[c * ZP + tau]) + bf2f(zsl[c * ZP + tau]);
        }
    __syncthreads();

    // ---- Parallel scan: thread = (n = t&31, oct = t>>5); 8 chunks each
    {
        int n   = t & 31;
        int oct = t >> 5;
        const float* cp   = ws + OFF_CP  + (size_t)lh * 64;
        const float* w64p = ws + OFF_W64 + (size_t)lh * 64;
        const float* w5p  = ws + OFF_W5  + (size_t)lh * 64;
        float cre = cp[2 * n], cim = cp[2 * n + 1];
        float wr  = w64p[2 * n], wi = w64p[2 * n + 1];
        float2 e[8];
        float sre = 0.f, sim = 0.f;
        #pragma unroll
        for (int j = 0; j < 8; ++j) {                 // local octave scan
            e[j] = *(const float2*)&eg[(8 * oct + j) * EP + 2 * n];
            float nr = fmaf(wr, sre, fmaf(-wi, sim, e[j].x));
            float ni = fmaf(wr, sim, fmaf(wi, sre, e[j].y));
            sre = nr; sim = ni;
        }
        *(float2*)&tex[oct][2 * n] = make_float2(sre, sim);
        __syncthreads();
        if (t < 32) {                                 // exclusive base scan over octaves
            float Wr = w5p[2 * n], Wi = w5p[2 * n + 1];
            float br = 0.f, bi = 0.f;
            #pragma unroll
            for (int o = 0; o < 8; ++o) {
                *(float2*)&bex[o][2 * n] = make_float2(br, bi);
                float2 T = *(const float2*)&tex[o][2 * n];
                float nr = fmaf(Wr, br, fmaf(-Wi, bi, T.x));
                float ni = fmaf(Wr, bi, fmaf(Wi, br, T.y));
                br = nr; bi = ni;
            }
        }
        __syncthreads();
        float2 Sb = *(const float2*)&bex[oct][2 * n];
        sre = Sb.x; sim = Sb.y;
        #pragma unroll
        for (int j = 0; j < 8; ++j) {                 // replay: emit G hi/lo
            int c = 8 * oct + j;
            float gre = 2.0f * (cre * sre - cim * sim);
            float gim = -2.0f * (cre * sim + cim * sre);
            unsigned short g0 = f2bf(gre);
            unsigned short g1 = f2bf(gim);
            zsh[c * ZP + 2 * n]     = g0;
            zsh[c * ZP + 2 * n + 1] = g1;
            zsl[c * ZP + 2 * n]     = f2bf(gre - bf2f(g0));
            zsl[c * ZP + 2 * n + 1] = f2bf(gim - bf2f(g1));
            float nr = fmaf(wr, sre, fmaf(-wi, sim, e[j].x));
            float ni = fmaf(wr, sim, fmaf(wi, sre, e[j].y));
            sre = nr; sim = ni;
        }
    }
    float Dh = Dp[lh];
    __syncthreads();

    // ---- Pass B: Y += G x T2F
    #pragma unroll
    for (int ct = 0; ct < 4; ++ct) {
        int ar = (ct * 16 + lr) * ZP;
        bf16x8 gh0 = BCB(*(const u16x8*)&zsh[ar + lg * 8]);
        bf16x8 gl0 = BCB(*(const u16x8*)&zsl[ar + lg * 8]);
        bf16x8 gh1 = BCB(*(const u16x8*)&zsh[ar + 32 + lg * 8]);
        bf16x8 gl1 = BCB(*(const u16x8*)&zsl[ar + 32 + lg * 8]);
        accC[ct] = MFMA(gh0, T2h0, accC[ct]);
        accC[ct] = MFMA(gl0, T2h0, accC[ct]);
        accC[ct] = MFMA(gh0, T2l0, accC[ct]);
        accC[ct] = MFMA(gh1, T2h1, accC[ct]);
        accC[ct] = MFMA(gl1, T2h1, accC[ct]);
        accC[ct] = MFMA(gh1, T2l1, accC[ct]);
    }

    // ---- epilogue: + D*z, GELU, store y bf16
    unsigned short* yb = (unsigned short*)(ws + OFF_Y) + ((size_t)b * H_ + h) * L_;
    #pragma unroll
    for (int ct = 0; ct < 4; ++ct)
        #pragma unroll
        for (int r = 0; r < 4; ++r) {
            float acc = fmaf(Dh, zep[ct * 4 + r], accC[ct][r]);
            float g = 0.5f * acc * (1.0f + erff(acc * 0.70710678118654752f));
            yb[(ct * 16 + lg * 4 + r) * 64 + w * 16 + lr] = f2bf(g);
        }
}

// ---------------------------------------------------------------------------
// Channel mix via bf16 MFMA + GLU + residual(f32) + LN. B-frags from
// transposed XOR-swizzled LDS yt[l][h]; vector b128 reads, balanced banks.
// ---------------------------------------------------------------------------
__global__ __launch_bounds__(256) void conv_glu_ln_mfma(const float* conv_b, const float* ln_w,
                                                        const float* ln_b, float* ws, int layer) {
    __shared__ unsigned short yt[64 * 128];   // [l][h], swizzled
    __shared__ float wsum[4][64];
    __shared__ float wsq[4][64];

    int t    = threadIdx.x;
    int b    = blockIdx.x >> 6;
    int l0   = (blockIdx.x & 63) * 64;
    int w    = t >> 6;
    int lam  = t & 63;
    int g4   = lam >> 4;
    int ncol = lam & 15;

    const unsigned short* yg = (const unsigned short*)(ws + OFF_Y) + (size_t)b * H_ * L_;
    const unsigned short* wb = (const unsigned short*)(ws + OFF_WB) + (size_t)layer * 256 * 128;

    // ---- stage y transposed: column loads (coalesced across lanes), b128 writes
    {
        int ll = t & 63;
        int hb = (t >> 6) * 32;
        const unsigned short* ycol = yg + l0 + ll;
        #pragma unroll
        for (int g = 0; g < 4; ++g) {
            u16x8 tmp;
            #pragma unroll
            for (int i = 0; i < 8; ++i)
                tmp[i] = ycol[(size_t)(hb + g * 8 + i) * L_];
            *(u16x8*)&yt[yswz(ll, hb + g * 8)] = tmp;
        }
    }

    // ---- bias init
    const float* cb = conv_b + layer * 256;
    f32x4 dA[2][4], dG[2][4];
    #pragma unroll
    for (int oa = 0; oa < 2; ++oa) {
        int ba = w * 32 + oa * 16 + g4 * 4;
        f32x4 bA, bG;
        #pragma unroll
        for (int r = 0; r < 4; ++r) { bA[r] = cb[ba + r]; bG[r] = cb[128 + ba + r]; }
        #pragma unroll
        for (int nt = 0; nt < 4; ++nt) { dA[oa][nt] = bA; dG[oa][nt] = bG; }
    }
    __syncthreads();

    // ---- K loop: per kt, A-frags from global (L2), B-frags via b128 LDS reads
    #pragma unroll
    for (int kt = 0; kt < 4; ++kt) {
        bf16x8 aAk[2], aGk[2];
        #pragma unroll
        for (int oa = 0; oa < 2; ++oa) {
            int oA = w * 32 + oa * 16 + ncol;
            aAk[oa] = BCB(*(const u16x8*)&wb[(size_t)oA * 128 + kt * 32 + g4 * 8]);
            aGk[oa] = BCB(*(const u16x8*)&wb[(size_t)(128 + oA) * 128 + kt * 32 + g4 * 8]);
        }
        #pragma unroll
        for (int nt = 0; nt < 4; ++nt) {
            bf16x8 bfr = BCB(*(const u16x8*)&yt[yswz(nt * 16 + ncol, kt * 32 + g4 * 8)]);
            #pragma unroll
            for (int oa = 0; oa < 2; ++oa) {
                dA[oa][nt] = MFMA(aAk[oa], bfr, dA[oa][nt]);
                dG[oa][nt] = MFMA(aGk[oa], bfr, dG[oa][nt]);
            }
        }
    }

    // ---- epilogue: GLU + residual (f32); LN over 128 channels
    float* ug = ws + OFF_U + (size_t)b * H_ * L_;
    float lwv[2][4], lbv[2][4];
    #pragma unroll
    for (int oa = 0; oa < 2; ++oa)
        #pragma unroll
        for (int r = 0; r < 4; ++r) {
            int hh = layer * 128 + w * 32 + oa * 16 + g4 * 4 + r;
            lwv[oa][r] = ln_w[hh]; lbv[oa][r] = ln_b[hh];
        }

    #pragma unroll
    for (int nt = 0; nt < 4; ++nt) {
        int l = l0 + nt * 16 + ncol;
        float s = 0.f, q = 0.f;
        #pragma unroll
        for (int oa = 0; oa < 2; ++oa)
            #pragma unroll
            for (int r = 0; r < 4; ++r) {
                int h = w * 32 + oa * 16 + g4 * 4 + r;
                float a = dA[oa][nt][r], g = dG[oa][nt][r];
                float val = a / (1.0f + expf(-g)) + ug[(size_t)h * L_ + l];
                dA[oa][nt][r] = val;
                s += val; q += val * val;
            }
        s += __shfl_xor(s, 16, 64); q += __shfl_xor(q, 16, 64);
        s += __shfl_xor(s, 32, 64); q += __shfl_xor(q, 32, 64);
        if (g4 == 0) { wsum[w][nt * 16 + ncol] = s; wsq[w][nt * 16 + ncol] = q; }
    }
    __syncthreads();

    #pragma unroll
    for (int nt = 0; nt < 4; ++nt) {
        int ll = nt * 16 + ncol;
        int l  = l0 + ll;
        float S = wsum[0][ll] + wsum[1][ll] + wsum[2][ll] + wsum[3][ll];
        float Q = wsq[0][ll] + wsq[1][ll] + wsq[2][ll] + wsq[3][ll];
        float mu = S * (1.0f / 128.0f);
        float var = Q * (1.0f / 128.0f) - mu * mu;
        float rstd = rsqrtf(var + 1e-5f);
        #pragma unroll
        for (int oa = 0; oa < 2; ++oa)
            #pragma unroll
            for (int r = 0; r < 4; ++r) {
                int h = w * 32 + oa * 16 + g4 * 4 + r;
                float v = (dA[oa][nt][r] - mu) * rstd * lwv[oa][r] + lbv[oa][r];
                ug[(size_t)h * L_ + l] = v;
            }
    }
}

// ---------------------------------------------------------------------------
// Mean-pool over L per (b,h)
// ---------------------------------------------------------------------------
__global__ __launch_bounds__(256) void pool_kernel(float* ws) {
    int bh = blockIdx.x;
    const float* u = ws + OFF_U + (size_t)bh * L_;
    int t = threadIdx.x;
    float s = 0.0f;
    for (int i = t; i < L_; i += 256) s += u[i];
    #pragma unroll
    for (int m = 1; m <= 32; m <<= 1) s += __shfl_xor(s, m, 64);
    __shared__ float part[4];
    if ((t & 63) == 0) part[t >> 6] = s;
    __syncthreads();
    if (t == 0) ws[OFF_PL + bh] = (part[0] + part[1] + part[2] + part[3]) * (1.0f / L_);
}

// ---------------------------------------------------------------------------
// Decoder (f32 out)
// ---------------------------------------------------------------------------
__global__ __launch_bounds__(256) void decode_kernel(const float* dec_w, const float* dec_b,
                                                     const float* ws, float* out) {
    int t = threadIdx.x;
    int b = t >> 3, o = t & 7;
    const float* p = ws + OFF_PL + b * 128;
    float acc = dec_b[o];
    for (int h = 0; h < 128; ++h) acc += p[h] * dec_w[o * 128 + h];
    out[t] = 1.0f / (1.0f + expf(-acc));
}

// ---------------------------------------------------------------------------
// emb output: out[b][l][h] = u[b][h][l]  (f32, LDS tile transpose)
// ---------------------------------------------------------------------------
__global__ __launch_bounds__(256) void emb_out(const float* uws, float* out) {
    __shared__ float T[32 * 65];
    int t  = threadIdx.x;
    int bi = blockIdx.x;
    int lt = bi & 63;
    int ht = (bi >> 6) & 3;
    int b  = bi >> 8;
    int l0 = lt * 64, h0 = ht * 32;
    const float* u = uws + ((size_t)b * H_ + h0) * L_ + l0;
    #pragma unroll
    for (int p = 0; p < 8; ++p) {
        int rr = p * 4 + (t >> 6), cc = t & 63;
        T[rr * 65 + cc] = u[(size_t)rr * L_ + cc];
    }
    __syncthreads();
    #pragma unroll
    for (int q = 0; q < 8; ++q) {
        int hh = t & 31, ll = (t >> 5) + q * 8;
        out[((size_t)(b * L_) + l0 + ll) * H_ + h0 + hh] = T[hh * 65 + ll];
    }
}

// ---------------------------------------------------------------------------
extern "C" void kernel_launch(void* const* d_in, const int* in_sizes, int n_in,
                              void* d_out, int out_size, void* d_ws, size_t ws_size,
                              hipStream_t stream) {
    const float* x          = (const float*)d_in[0];
    const float* enc_w      = (const float*)d_in[2];
    const float* enc_b      = (const float*)d_in[3];
    const float* log_dt     = (const float*)d_in[4];
    const float* log_A_real = (const float*)d_in[5];
    const float* A_imag     = (const float*)d_in[6];
    const float* C_re       = (const float*)d_in[7];
    const float* C_im       = (const float*)d_in[8];
    const float* Dp         = (const float*)d_in[9];
    const float* conv_w     = (const float*)d_in[10];
    const float* conv_b     = (const float*)d_in[11];
    const float* ln_w       = (const float*)d_in[12];
    const float* ln_b       = (const float*)d_in[13];
    const float* dec_w      = (const float*)d_in[14];
    const float* dec_b      = (const float*)d_in[15];
    float* ws = (float*)d_ws;
    float* out = (float*)d_out;

    prep_params<<<(NL_ * H_ * N2_ + 255) / 256, 256, 0, stream>>>(log_dt, log_A_real, A_imag,
                                                                  C_re, C_im, ws);
    prep_pow<<<(NL_ * H_ * N2_ * 64) / 256, 256, 0, stream>>>(ws);
    compute_k<<<(NL_ * H_ * 64 + 255) / 256, 256, 0, stream>>>(ws);
    prep_tkf<<<(NL_ * H_ * 64 * 64) / 256, 256, 0, stream>>>(ws);
    prep_wbf<<<(NL_ * 256 * 128) / 256, 256, 0, stream>>>(conv_w, ws);
    encoder_kernel<<<B_ * (L_ / 256), 256, 0, stream>>>(x, enc_w, enc_b, ws);
    for (int l = 0; l < NL_; ++l) {
        s4d_mfma<<<B_ * H_, 256, 0, stream>>>(Dp, ws, l);
        conv_glu_ln_mfma<<<B_ * (L_ / 64), 256, 0, stream>>>(conv_b, ln_w, ln_b, ws, l);
    }
    pool_kernel<<<B_ * H_, 256, 0, stream>>>(ws);
    decode_kernel<<<1, 256, 0, stream>>>(dec_w, dec_b, ws, out);
    emb_out<<<B_ * 4 * 64, 256, 0, stream>>>(ws + OFF_U, out + 256);
}

// Round 10
// 359.024 us; speedup vs baseline: 31.4430x; 1.2009x over previous
//
#include <hip/hip_runtime.h>
#include <hip/hip_bf16.h>

#define B_ 32
#define L_ 4096
#define DIN 16
#define H_ 128
#define N2_ 32
#define NL_ 4
#define CL 64
#define NC 64

// ---- workspace layout (float slots) ----
#define OFF_U   ((size_t)0)                   // u bf16 (u16), [b][h][l]
#define SZ_U    ((size_t)B_*H_*L_/2)
#define OFF_Y   (OFF_U + SZ_U)                // y bf16 (u16), [b][h][l]
#define SZ_Y    ((size_t)B_*H_*L_/2)
#define OFF_T1  (OFF_Y + SZ_Y)                // f32 [lh][e][np] for compute_k
#define SZ_T1   ((size_t)NL_*H_*64*64)
#define OFF_K   (OFF_T1 + SZ_T1)
#define SZ_K    ((size_t)NL_*H_*64)
#define OFF_CP  (OFF_K + SZ_K)
#define SZ_CP   ((size_t)NL_*H_*64)
#define OFF_W64 (OFF_CP + SZ_CP)
#define SZ_W64  ((size_t)NL_*H_*64)
#define OFF_W5  (OFF_W64 + SZ_W64)            // w^512 [lh][n][2]
#define SZ_W5   ((size_t)NL_*H_*64)
#define OFF_DTA (OFF_W5 + SZ_W5)              // (dre,dim,wre,wim) per (lh,n)
#define SZ_DTA  ((size_t)NL_*H_*N2_*4)
#define OFF_PL  (OFF_DTA + SZ_DTA)
#define SZ_PL   ((size_t)B_*H_)
#define OFF_WB  (OFF_PL + SZ_PL)
#define SZ_WB   ((size_t)NL_*256*128/2)
// frag tables: per (lh): 8192 u16 = 4096 float slots. layout: (k>>3)*1024 + col*16 + (k&7), +8 = lo
#define OFF_T1F (OFF_WB + SZ_WB)
#define SZ_TF   ((size_t)NL_*H_*4096)
#define OFF_TKF (OFF_T1F + SZ_TF)
#define OFF_T2F (OFF_TKF + SZ_TF)

#define ZP 72   // u16 pitch, z/G LDS
#define EP 68   // f32 pitch, E LDS

typedef __bf16 bf16_t;
typedef bf16_t bf16x8 __attribute__((ext_vector_type(8)));
typedef float f32x4 __attribute__((ext_vector_type(4)));
typedef unsigned short u16x8 __attribute__((ext_vector_type(8)));

#define MFMA(a, b, c) __builtin_amdgcn_mfma_f32_16x16x32_bf16(a, b, c, 0, 0, 0)
#define BCB(v) __builtin_bit_cast(bf16x8, v)

__device__ __forceinline__ unsigned short f2bf(float f) {
    return __builtin_bit_cast(unsigned short, (__bf16)f);   // native RNE cvt
}
__device__ __forceinline__ float bf2f(unsigned short u) {
    return __builtin_bit_cast(float, (unsigned int)u << 16);
}
__device__ __forceinline__ void store_hl(unsigned short* p, int idx, float v) {
    unsigned short hi = f2bf(v);
    p[idx]     = hi;
    p[idx + 8] = f2bf(v - bf2f(hi));
}
// tanh-GELU: max abs err ~3e-4 (invisible under bf16), branchless, HW exp
__device__ __forceinline__ float gelu_f(float a) {
    float uu = a * fmaf(0.0356774081f, a * a, 0.7978845608f);
    float e  = __expf(2.0f * uu);
    float th = 1.0f - 2.0f / (e + 1.0f);
    return 0.5f * a * (1.0f + th);
}
// yt[l][h] XOR swizzle (u16 index); h must be mult of 8 for 16B access
__device__ __forceinline__ int yswz(int l, int h) {
    return (l * 128 + h) ^ ((l & 7) << 3);
}

// ---------------------------------------------------------------------------
// P0a: per (lh,n): C', dtA cache, w, w^64, w^512 (all direct, no serial chain)
// ---------------------------------------------------------------------------
__global__ __launch_bounds__(256) void prep_params(const float* log_dt, const float* log_A_real,
                                                   const float* A_imag, const float* C_re,
                                                   const float* C_im, float* ws) {
    int idx = blockIdx.x * 256 + threadIdx.x;        // (lh,n)
    if (idx >= NL_ * H_ * N2_) return;
    int n  = idx & 31;
    int lh = idx >> 5;

    float dt  = expf(log_dt[lh]);
    float Are = -expf(log_A_real[idx]);
    float Aim = A_imag[idx];
    float dre = Are * dt, dim = Aim * dt;
    float er  = expf(dre);
    float sw, cw; sincosf(dim, &sw, &cw);
    float wre = er * cw, wim = er * sw;
    float nre = wre - 1.0f, nim = wim;
    float den = Are * Are + Aim * Aim;
    float qre = (nre * Are + nim * Aim) / den;
    float qim = (nim * Are - nre * Aim) / den;
    float cre = C_re[idx], cim = C_im[idx];

    float* cp  = ws + OFF_CP  + (size_t)lh * 64;
    float* w64 = ws + OFF_W64 + (size_t)lh * 64;
    float* w5  = ws + OFF_W5  + (size_t)lh * 64;
    cp[2 * n]     = cre * qre - cim * qim;
    cp[2 * n + 1] = cre * qim + cim * qre;
    *((float4*)(ws + OFF_DTA) + (size_t)lh * 32 + n) = make_float4(dre, dim, wre, wim);

    float e64 = expf(64.0f * dre);
    float s64, c64; sincosf(64.0f * dim, &s64, &c64);
    float ar = e64 * c64, ai = e64 * s64;
    w64[2 * n] = ar; w64[2 * n + 1] = ai;
    #pragma unroll
    for (int q = 0; q < 3; ++q) {
        float nr = ar * ar - ai * ai;
        float ni = 2.0f * ar * ai;
        ar = nr; ai = ni;
    }
    w5[2 * n] = ar; w5[2 * n + 1] = ai;
}

// ---------------------------------------------------------------------------
// P0b: per (lh,e,n): w^e direct -> t1 f32 + T1F frag; w^{e+1} -> T2F frag
// ---------------------------------------------------------------------------
__global__ __launch_bounds__(256) void prep_pow(float* ws) {
    int idx = blockIdx.x * 256 + threadIdx.x;        // lh*2048 + e*32 + n
    int n  = idx & 31;
    int e  = (idx >> 5) & 63;
    int lh = idx >> 11;
    float4 dw = *((const float4*)(ws + OFF_DTA) + (size_t)lh * 32 + n);
    float ew = expf((float)e * dw.x);
    float sn, cs; sincosf((float)e * dw.y, &sn, &cs);
    float pr = ew * cs, pi = ew * sn;

    float* t1 = ws + OFF_T1 + (size_t)lh * 4096;
    *(float2*)&t1[e * 64 + 2 * n] = make_float2(pr, pi);

    unsigned short* t1f = (unsigned short*)(ws + OFF_T1F) + (size_t)lh * 8192;
    unsigned short* t2f = (unsigned short*)(ws + OFF_T2F) + (size_t)lh * 8192;
    int k1 = 63 - e;                                 // T1F[k1][np] = w^e
    store_hl(t1f, (k1 >> 3) * 1024 + (2 * n) * 16 + (k1 & 7), pr);
    store_hl(t1f, (k1 >> 3) * 1024 + (2 * n + 1) * 16 + (k1 & 7), pi);
    float qr = pr * dw.z - pi * dw.w;                // w^{e+1}
    float qi = pr * dw.w + pi * dw.z;
    store_hl(t2f, ((2 * n) >> 3) * 1024 + e * 16 + ((2 * n) & 7), qr);
    store_hl(t2f, ((2 * n + 1) >> 3) * 1024 + e * 16 + ((2 * n + 1) & 7), qi);
}

// ---------------------------------------------------------------------------
// P0c: k[h][s] = 2*Re( sum_n C'_n w_n^s )
// ---------------------------------------------------------------------------
__global__ __launch_bounds__(256) void compute_k(float* ws) {
    int idx = blockIdx.x * 256 + threadIdx.x;        // (l,h,s)
    if (idx >= NL_ * H_ * 64) return;
    int s  = idx & 63;
    int lh = idx >> 6;
    const float* t1 = ws + OFF_T1 + (size_t)lh * 4096 + (size_t)s * 64;
    const float* cp = ws + OFF_CP + (size_t)lh * 64;
    float acc = 0.0f;
    #pragma unroll
    for (int n = 0; n < 32; ++n)
        acc += cp[2 * n] * t1[2 * n] - cp[2 * n + 1] * t1[2 * n + 1];
    ws[OFF_K + (size_t)lh * 64 + s] = 2.0f * acc;
}

// ---------------------------------------------------------------------------
// P0d: Toeplitz frag table TKF[s][tau] = (tau>=s) ? k[tau-s] : 0  (parallel)
// ---------------------------------------------------------------------------
__global__ __launch_bounds__(256) void prep_tkf(float* ws) {
    int idx = blockIdx.x * 256 + threadIdx.x;        // lh*4096 + s*64 + tau
    int tau = idx & 63;
    int s   = (idx >> 6) & 63;
    int lh  = idx >> 12;
    float v = (tau >= s) ? ws[OFF_K + (size_t)lh * 64 + (tau - s)] : 0.0f;
    unsigned short* dst = (unsigned short*)(ws + OFF_TKF) + (size_t)lh * 8192;
    store_hl(dst, (s >> 3) * 1024 + (s & 7) + tau * 16, v);
}

// ---------------------------------------------------------------------------
// P0e: conv_w -> bf16
// ---------------------------------------------------------------------------
__global__ __launch_bounds__(256) void prep_wbf(const float* conv_w, float* ws) {
    int i = blockIdx.x * 256 + threadIdx.x;
    ((unsigned short*)(ws + OFF_WB))[i] = f2bf(conv_w[i]);
}

// ---------------------------------------------------------------------------
// Encoder -> u bf16
// ---------------------------------------------------------------------------
__global__ __launch_bounds__(256) void encoder_kernel(const float* x, const float* enc_w,
                                                      const float* enc_b, float* ws) {
    __shared__ float wlds[H_ * DIN];
    __shared__ float blds[H_];
    int t  = threadIdx.x;
    int b  = blockIdx.x >> 4;
    int l0 = (blockIdx.x & 15) * 256;
    for (int i = t; i < H_ * DIN; i += 256) wlds[i] = enc_w[i];
    if (t < H_) blds[t] = enc_b[t];
    float xr[16];
    const float* xp = x + ((size_t)b * L_ + l0 + t) * DIN;
    #pragma unroll
    for (int d = 0; d < 16; ++d) xr[d] = xp[d];
    __syncthreads();
    unsigned short* u = (unsigned short*)(ws + OFF_U) + (size_t)b * H_ * L_ + l0 + t;
    for (int h = 0; h < H_; ++h) {
        float acc = blds[h];
        #pragma unroll
        for (int d = 0; d < 16; ++d) acc += xr[d] * wlds[h * 16 + d];
        u[(size_t)h * L_] = f2bf(acc);
    }
}

// ---------------------------------------------------------------------------
// S4D via bf16 MFMA (T tables hi/lo corrected; z/G pure bf16).
// One block per (b,h). Parallel 3-level cross-chunk scan.
// ---------------------------------------------------------------------------
__global__ __launch_bounds__(256) void s4d_mfma(const float* Dp, float* ws, int layer) {
    __shared__ unsigned short zsh[64 * ZP];   // z, then G (bf16)
    __shared__ float eg[64 * EP];             // E (f32)
    __shared__ float tex[8][64];              // octave totals (complex packed)
    __shared__ float bex[8][64];              // exclusive octave bases

    int t  = threadIdx.x;
    int b  = blockIdx.x >> 7;
    int h  = blockIdx.x & 127;
    int lh = layer * H_ + h;
    int w  = t >> 6;
    int l  = t & 63;
    int lr = l & 15;
    int lg = l >> 4;

    const unsigned short* ug = (const unsigned short*)(ws + OFF_U) + ((size_t)b * H_ + h) * L_;

    // stage z: straight bf16 copy (16 elements per thread)
    {
        int base = t * 16;
        int c = base >> 6, s0 = base & 63;
        *(u16x8*)&zsh[c * ZP + s0]     = *(const u16x8*)&ug[base];
        *(u16x8*)&zsh[c * ZP + s0 + 8] = *(const u16x8*)&ug[base + 8];
    }

    // preload B-frags (global, L2-hot): T1F + TKF, kblk 0/1
    const unsigned short* t1f = (const unsigned short*)(ws + OFF_T1F) + (size_t)lh * 8192;
    const unsigned short* tkf = (const unsigned short*)(ws + OFF_TKF) + (size_t)lh * 8192;
    const unsigned short* t2f = (const unsigned short*)(ws + OFF_T2F) + (size_t)lh * 8192;
    int bo = lg * 1024 + (w * 16 + lr) * 16;
    bf16x8 T1h0 = BCB(*(const u16x8*)&t1f[bo]);
    bf16x8 T1l0 = BCB(*(const u16x8*)&t1f[bo + 8]);
    bf16x8 T1h1 = BCB(*(const u16x8*)&t1f[bo + 4096]);
    bf16x8 T1l1 = BCB(*(const u16x8*)&t1f[bo + 4096 + 8]);
    bf16x8 TKh0 = BCB(*(const u16x8*)&tkf[bo]);
    bf16x8 TKl0 = BCB(*(const u16x8*)&tkf[bo + 8]);
    bf16x8 TKh1 = BCB(*(const u16x8*)&tkf[bo + 4096]);
    bf16x8 TKl1 = BCB(*(const u16x8*)&tkf[bo + 4096 + 8]);

    f32x4 accE[4], accC[4];
    #pragma unroll
    for (int ct = 0; ct < 4; ++ct) { accE[ct] = (f32x4)0.0f; accC[ct] = (f32x4)0.0f; }

    __syncthreads();

    // ---- Pass A: E = z x (T1h+T1l) ; Yconv = z x (TKh+TKl)
    #pragma unroll
    for (int ct = 0; ct < 4; ++ct) {
        int ar = (ct * 16 + lr) * ZP;
        bf16x8 ah0 = BCB(*(const u16x8*)&zsh[ar + lg * 8]);
        bf16x8 ah1 = BCB(*(const u16x8*)&zsh[ar + 32 + lg * 8]);
        accE[ct] = MFMA(ah0, T1h0, accE[ct]);
        accE[ct] = MFMA(ah0, T1l0, accE[ct]);
        accE[ct] = MFMA(ah1, T1h1, accE[ct]);
        accE[ct] = MFMA(ah1, T1l1, accE[ct]);
        accC[ct] = MFMA(ah0, TKh0, accC[ct]);
        accC[ct] = MFMA(ah0, TKl0, accC[ct]);
        accC[ct] = MFMA(ah1, TKh1, accC[ct]);
        accC[ct] = MFMA(ah1, TKl1, accC[ct]);
    }
    // write E (D-frag: row=(lg*4+r), col=lr)
    #pragma unroll
    for (int ct = 0; ct < 4; ++ct)
        #pragma unroll
        for (int r = 0; r < 4; ++r)
            eg[(ct * 16 + lg * 4 + r) * EP + w * 16 + lr] = accE[ct][r];

    // preload T2F frags; pre-extract epilogue z (zsh reused for G after)
    bf16x8 T2h0 = BCB(*(const u16x8*)&t2f[bo]);
    bf16x8 T2l0 = BCB(*(const u16x8*)&t2f[bo + 8]);
    bf16x8 T2h1 = BCB(*(const u16x8*)&t2f[bo + 4096]);
    bf16x8 T2l1 = BCB(*(const u16x8*)&t2f[bo + 4096 + 8]);
    float zep[16];
    #pragma unroll
    for (int ct = 0; ct < 4; ++ct)
        #pragma unroll
        for (int r = 0; r < 4; ++r) {
            int c = ct * 16 + lg * 4 + r, tau = w * 16 + lr;
            zep[ct * 4 + r] = bf2f(zsh[c * ZP + tau]);
        }
    __syncthreads();

    // ---- Parallel scan: thread = (n = t&31, oct = t>>5); 8 chunks each
    {
        int n   = t & 31;
        int oct = t >> 5;
        const float* cp   = ws + OFF_CP  + (size_t)lh * 64;
        const float* w64p = ws + OFF_W64 + (size_t)lh * 64;
        const float* w5p  = ws + OFF_W5  + (size_t)lh * 64;
        float cre = cp[2 * n], cim = cp[2 * n + 1];
        float wr  = w64p[2 * n], wi = w64p[2 * n + 1];
        float2 e[8];
        float sre = 0.f, sim = 0.f;
        #pragma unroll
        for (int j = 0; j < 8; ++j) {                 // local octave scan
            e[j] = *(const float2*)&eg[(8 * oct + j) * EP + 2 * n];
            float nr = fmaf(wr, sre, fmaf(-wi, sim, e[j].x));
            float ni = fmaf(wr, sim, fmaf(wi, sre, e[j].y));
            sre = nr; sim = ni;
        }
        *(float2*)&tex[oct][2 * n] = make_float2(sre, sim);
        __syncthreads();
        if (t < 32) {                                 // exclusive base scan over octaves
            float Wr = w5p[2 * n], Wi = w5p[2 * n + 1];
            float br = 0.f, bi = 0.f;
            #pragma unroll
            for (int o = 0; o < 8; ++o) {
                *(float2*)&bex[o][2 * n] = make_float2(br, bi);
                float2 T = *(const float2*)&tex[o][2 * n];
                float nr = fmaf(Wr, br, fmaf(-Wi, bi, T.x));
                float ni = fmaf(Wr, bi, fmaf(Wi, br, T.y));
                br = nr; bi = ni;
            }
        }
        __syncthreads();
        float2 Sb = *(const float2*)&bex[oct][2 * n];
        sre = Sb.x; sim = Sb.y;
        #pragma unroll
        for (int j = 0; j < 8; ++j) {                 // replay: emit G bf16 (packed u32)
            int c = 8 * oct + j;
            float gre = 2.0f * (cre * sre - cim * sim);
            float gim = -2.0f * (cre * sim + cim * sre);
            unsigned int pk = (unsigned int)f2bf(gre) | ((unsigned int)f2bf(gim) << 16);
            *(unsigned int*)&zsh[c * ZP + 2 * n] = pk;
            float nr = fmaf(wr, sre, fmaf(-wi, sim, e[j].x));
            float ni = fmaf(wr, sim, fmaf(wi, sre, e[j].y));
            sre = nr; sim = ni;
        }
    }
    float Dh = Dp[lh];
    __syncthreads();

    // ---- Pass B: Y += G x (T2h+T2l)
    #pragma unroll
    for (int ct = 0; ct < 4; ++ct) {
        int ar = (ct * 16 + lr) * ZP;
        bf16x8 gh0 = BCB(*(const u16x8*)&zsh[ar + lg * 8]);
        bf16x8 gh1 = BCB(*(const u16x8*)&zsh[ar + 32 + lg * 8]);
        accC[ct] = MFMA(gh0, T2h0, accC[ct]);
        accC[ct] = MFMA(gh0, T2l0, accC[ct]);
        accC[ct] = MFMA(gh1, T2h1, accC[ct]);
        accC[ct] = MFMA(gh1, T2l1, accC[ct]);
    }

    // ---- epilogue: + D*z, tanh-GELU, store y bf16
    unsigned short* yb = (unsigned short*)(ws + OFF_Y) + ((size_t)b * H_ + h) * L_;
    #pragma unroll
    for (int ct = 0; ct < 4; ++ct)
        #pragma unroll
        for (int r = 0; r < 4; ++r) {
            float acc = fmaf(Dh, zep[ct * 4 + r], accC[ct][r]);
            yb[(ct * 16 + lg * 4 + r) * 64 + w * 16 + lr] = f2bf(gelu_f(acc));
        }
}

// ---------------------------------------------------------------------------
// Channel mix via bf16 MFMA + GLU + residual(bf16) + LN -> u bf16.
// ---------------------------------------------------------------------------
__global__ __launch_bounds__(256) void conv_glu_ln_mfma(const float* conv_b, const float* ln_w,
                                                        const float* ln_b, float* ws, int layer) {
    __shared__ unsigned short yt[64 * 128];   // [l][h], swizzled
    __shared__ float wsum[4][64];
    __shared__ float wsq[4][64];

    int t    = threadIdx.x;
    int b    = blockIdx.x >> 6;
    int l0   = (blockIdx.x & 63) * 64;
    int w    = t >> 6;
    int lam  = t & 63;
    int g4   = lam >> 4;
    int ncol = lam & 15;

    const unsigned short* yg = (const unsigned short*)(ws + OFF_Y) + (size_t)b * H_ * L_;
    const unsigned short* wb = (const unsigned short*)(ws + OFF_WB) + (size_t)layer * 256 * 128;

    // ---- stage y transposed: column loads (coalesced across lanes), b128 writes
    {
        int ll = t & 63;
        int hb = (t >> 6) * 32;
        const unsigned short* ycol = yg + l0 + ll;
        #pragma unroll
        for (int g = 0; g < 4; ++g) {
            u16x8 tmp;
            #pragma unroll
            for (int i = 0; i < 8; ++i)
                tmp[i] = ycol[(size_t)(hb + g * 8 + i) * L_];
            *(u16x8*)&yt[yswz(ll, hb + g * 8)] = tmp;
        }
    }

    // ---- bias init
    const float* cb = conv_b + layer * 256;
    f32x4 dA[2][4], dG[2][4];
    #pragma unroll
    for (int oa = 0; oa < 2; ++oa) {
        int ba = w * 32 + oa * 16 + g4 * 4;
        f32x4 bA, bG;
        #pragma unroll
        for (int r = 0; r < 4; ++r) { bA[r] = cb[ba + r]; bG[r] = cb[128 + ba + r]; }
        #pragma unroll
        for (int nt = 0; nt < 4; ++nt) { dA[oa][nt] = bA; dG[oa][nt] = bG; }
    }
    __syncthreads();

    // ---- K loop: per kt, A-frags from global (L2), B-frags via b128 LDS reads
    #pragma unroll
    for (int kt = 0; kt < 4; ++kt) {
        bf16x8 aAk[2], aGk[2];
        #pragma unroll
        for (int oa = 0; oa < 2; ++oa) {
            int oA = w * 32 + oa * 16 + ncol;
            aAk[oa] = BCB(*(const u16x8*)&wb[(size_t)oA * 128 + kt * 32 + g4 * 8]);
            aGk[oa] = BCB(*(const u16x8*)&wb[(size_t)(128 + oA) * 128 + kt * 32 + g4 * 8]);
        }
        #pragma unroll
        for (int nt = 0; nt < 4; ++nt) {
            bf16x8 bfr = BCB(*(const u16x8*)&yt[yswz(nt * 16 + ncol, kt * 32 + g4 * 8)]);
            #pragma unroll
            for (int oa = 0; oa < 2; ++oa) {
                dA[oa][nt] = MFMA(aAk[oa], bfr, dA[oa][nt]);
                dG[oa][nt] = MFMA(aGk[oa], bfr, dG[oa][nt]);
            }
        }
    }

    // ---- epilogue: GLU + residual (bf16); LN over 128 channels
    unsigned short* ug = (unsigned short*)(ws + OFF_U) + (size_t)b * H_ * L_;
    float lwv[2][4], lbv[2][4];
    #pragma unroll
    for (int oa = 0; oa < 2; ++oa)
        #pragma unroll
        for (int r = 0; r < 4; ++r) {
            int hh = layer * 128 + w * 32 + oa * 16 + g4 * 4 + r;
            lwv[oa][r] = ln_w[hh]; lbv[oa][r] = ln_b[hh];
        }

    #pragma unroll
    for (int nt = 0; nt < 4; ++nt) {
        int l = l0 + nt * 16 + ncol;
        float s = 0.f, q = 0.f;
        #pragma unroll
        for (int oa = 0; oa < 2; ++oa)
            #pragma unroll
            for (int r = 0; r < 4; ++r) {
                int h = w * 32 + oa * 16 + g4 * 4 + r;
                float a = dA[oa][nt][r], g = dG[oa][nt][r];
                float val = a / (1.0f + __expf(-g)) + bf2f(ug[(size_t)h * L_ + l]);
                dA[oa][nt][r] = val;
                s += val; q += val * val;
            }
        s += __shfl_xor(s, 16, 64); q += __shfl_xor(q, 16, 64);
        s += __shfl_xor(s, 32, 64); q += __shfl_xor(q, 32, 64);
        if (g4 == 0) { wsum[w][nt * 16 + ncol] = s; wsq[w][nt * 16 + ncol] = q; }
    }
    __syncthreads();

    #pragma unroll
    for (int nt = 0; nt < 4; ++nt) {
        int ll = nt * 16 + ncol;
        int l  = l0 + ll;
        float S = wsum[0][ll] + wsum[1][ll] + wsum[2][ll] + wsum[3][ll];
        float Q = wsq[0][ll] + wsq[1][ll] + wsq[2][ll] + wsq[3][ll];
        float mu = S * (1.0f / 128.0f);
        float var = Q * (1.0f / 128.0f) - mu * mu;
        float rstd = rsqrtf(var + 1e-5f);
        #pragma unroll
        for (int oa = 0; oa < 2; ++oa)
            #pragma unroll
            for (int r = 0; r < 4; ++r) {
                int h = w * 32 + oa * 16 + g4 * 4 + r;
                float v = (dA[oa][nt][r] - mu) * rstd * lwv[oa][r] + lbv[oa][r];
                ug[(size_t)h * L_ + l] = f2bf(v);
            }
    }
}

// ---------------------------------------------------------------------------
// Mean-pool over L per (b,h)
// ---------------------------------------------------------------------------
__global__ __launch_bounds__(256) void pool_kernel(float* ws) {
    int bh = blockIdx.x;
    const unsigned short* u = (const unsigned short*)(ws + OFF_U) + (size_t)bh * L_;
    int t = threadIdx.x;
    float s = 0.0f;
    for (int i = t; i < L_; i += 256) s += bf2f(u[i]);
    #pragma unroll
    for (int m = 1; m <= 32; m <<= 1) s += __shfl_xor(s, m, 64);
    __shared__ float part[4];
    if ((t & 63) == 0) part[t >> 6] = s;
    __syncthreads();
    if (t == 0) ws[OFF_PL + bh] = (part[0] + part[1] + part[2] + part[3]) * (1.0f / L_);
}

// ---------------------------------------------------------------------------
// Decoder (f32 out)
// ---------------------------------------------------------------------------
__global__ __launch_bounds__(256) void decode_kernel(const float* dec_w, const float* dec_b,
                                                     const float* ws, float* out) {
    int t = threadIdx.x;
    int b = t >> 3, o = t & 7;
    const float* p = ws + OFF_PL + b * 128;
    float acc = dec_b[o];
    for (int h = 0; h < 128; ++h) acc += p[h] * dec_w[o * 128 + h];
    out[t] = 1.0f / (1.0f + __expf(-acc));
}

// ---------------------------------------------------------------------------
// emb output: out[b][l][h] = u[b][h][l]  (bf16 -> f32, LDS tile transpose)
// ---------------------------------------------------------------------------
__global__ __launch_bounds__(256) void emb_out(const float* ws, float* out) {
    __shared__ float T[32 * 65];
    int t  = threadIdx.x;
    int bi = blockIdx.x;
    int lt = bi & 63;
    int ht = (bi >> 6) & 3;
    int b  = bi >> 8;
    int l0 = lt * 64, h0 = ht * 32;
    const unsigned short* u = (const unsigned short*)(ws + OFF_U) + ((size_t)b * H_ + h0) * L_ + l0;
    #pragma unroll
    for (int p = 0; p < 8; ++p) {
        int rr = p * 4 + (t >> 6), cc = t & 63;
        T[rr * 65 + cc] = bf2f(u[(size_t)rr * L_ + cc]);
    }
    __syncthreads();
    #pragma unroll
    for (int q = 0; q < 8; ++q) {
        int hh = t & 31, ll = (t >> 5) + q * 8;
        out[((size_t)(b * L_) + l0 + ll) * H_ + h0 + hh] = T[hh * 65 + ll];
    }
}

// ---------------------------------------------------------------------------
extern "C" void kernel_launch(void* const* d_in, const int* in_sizes, int n_in,
                              void* d_out, int out_size, void* d_ws, size_t ws_size,
                              hipStream_t stream) {
    const float* x          = (const float*)d_in[0];
    const float* enc_w      = (const float*)d_in[2];
    const float* enc_b      = (const float*)d_in[3];
    const float* log_dt     = (const float*)d_in[4];
    const float* log_A_real = (const float*)d_in[5];
    const float* A_imag     = (const float*)d_in[6];
    const float* C_re       = (const float*)d_in[7];
    const float* C_im       = (const float*)d_in[8];
    const float* Dp         = (const float*)d_in[9];
    const float* conv_w     = (const float*)d_in[10];
    const float* conv_b     = (const float*)d_in[11];
    const float* ln_w       = (const float*)d_in[12];
    const float* ln_b       = (const float*)d_in[13];
    const float* dec_w      = (const float*)d_in[14];
    const float* dec_b      = (const float*)d_in[15];
    float* ws = (float*)d_ws;
    float* out = (float*)d_out;

    prep_params<<<(NL_ * H_ * N2_ + 255) / 256, 256, 0, stream>>>(log_dt, log_A_real, A_imag,
                                                                  C_re, C_im, ws);
    prep_pow<<<(NL_ * H_ * N2_ * 64) / 256, 256, 0, stream>>>(ws);
    compute_k<<<(NL_ * H_ * 64 + 255) / 256, 256, 0, stream>>>(ws);
    prep_tkf<<<(NL_ * H_ * 64 * 64) / 256, 256, 0, stream>>>(ws);
    prep_wbf<<<(NL_ * 256 * 128) / 256, 256, 0, stream>>>(conv_w, ws);
    encoder_kernel<<<B_ * (L_ / 256), 256, 0, stream>>>(x, enc_w, enc_b, ws);
    for (int l = 0; l < NL_; ++l) {
        s4d_mfma<<<B_ * H_, 256, 0, stream>>>(Dp, ws, l);
        conv_glu_ln_mfma<<<B_ * (L_ / 64), 256, 0, stream>>>(conv_b, ln_w, ln_b, ws, l);
    }
    pool_kernel<<<B_ * H_, 256, 0, stream>>>(ws);
    decode_kernel<<<1, 256, 0, stream>>>(dec_w, dec_b, ws, out);
    emb_out<<<B_ * 4 * 64, 256, 0, stream>>>(ws, out + 256);
}

// Round 12
// 355.240 us; speedup vs baseline: 31.7779x; 1.0107x over previous
//
#include <hip/hip_runtime.h>
#include <hip/hip_bf16.h>

#define B_ 32
#define L_ 4096
#define DIN 16
#define H_ 128
#define N2_ 32
#define NL_ 4
#define CL 64
#define NC 64

// ---- workspace layout (float slots) ----
#define OFF_U   ((size_t)0)                   // u bf16 (u16), [b][h][l]
#define SZ_U    ((size_t)B_*H_*L_/2)
#define OFF_Y   (OFF_U + SZ_U)                // y bf16 (u16), [b][h][l]
#define SZ_Y    ((size_t)B_*H_*L_/2)
#define OFF_K   (OFF_Y + SZ_Y)
#define SZ_K    ((size_t)NL_*H_*64)
#define OFF_CP  (OFF_K + SZ_K)
#define SZ_CP   ((size_t)NL_*H_*64)
#define OFF_W64 (OFF_CP + SZ_CP)
#define SZ_W64  ((size_t)NL_*H_*64)
#define OFF_W5  (OFF_W64 + SZ_W64)            // w^512 [lh][n][2]
#define SZ_W5   ((size_t)NL_*H_*64)
#define OFF_DTA (OFF_W5 + SZ_W5)              // (dre,dim,wre,wim) per (lh,n)
#define SZ_DTA  ((size_t)NL_*H_*N2_*4)
#define OFF_PL  (OFF_DTA + SZ_DTA)
#define SZ_PL   ((size_t)B_*H_)
#define OFF_WB  (OFF_PL + SZ_PL)
#define SZ_WB   ((size_t)NL_*256*128/2)
// frag tables: per (lh): 8192 u16 = 4096 float slots. layout: (k>>3)*1024 + col*16 + (k&7), +8 = lo
#define OFF_T1F (OFF_WB + SZ_WB)
#define SZ_TF   ((size_t)NL_*H_*4096)
#define OFF_TKF (OFF_T1F + SZ_TF)
#define OFF_T2F (OFF_TKF + SZ_TF)

#define ZP 72   // u16 pitch, z/G LDS
#define EP 68   // f32 pitch, E LDS

typedef __bf16 bf16_t;
typedef bf16_t bf16x8 __attribute__((ext_vector_type(8)));
typedef float f32x4 __attribute__((ext_vector_type(4)));
typedef unsigned short u16x8 __attribute__((ext_vector_type(8)));

#define MFMA(a, b, c) __builtin_amdgcn_mfma_f32_16x16x32_bf16(a, b, c, 0, 0, 0)
#define BCB(v) __builtin_bit_cast(bf16x8, v)

__device__ __forceinline__ unsigned short f2bf(float f) {
    return __builtin_bit_cast(unsigned short, (__bf16)f);   // native RNE cvt
}
__device__ __forceinline__ float bf2f(unsigned short u) {
    return __builtin_bit_cast(float, (unsigned int)u << 16);
}
__device__ __forceinline__ void store_hl(unsigned short* p, int idx, float v) {
    unsigned short hi = f2bf(v);
    p[idx]     = hi;
    p[idx + 8] = f2bf(v - bf2f(hi));
}
// tanh-GELU: max abs err ~3e-4 (invisible under bf16), branchless, HW exp
__device__ __forceinline__ float gelu_f(float a) {
    float uu = a * fmaf(0.0356774081f, a * a, 0.7978845608f);
    float e  = __expf(2.0f * uu);
    float th = 1.0f - 2.0f / (e + 1.0f);
    return 0.5f * a * (1.0f + th);
}
// yt[l][h] XOR swizzle (u16 index); h must be mult of 8 for 16B access
__device__ __forceinline__ int yswz(int l, int h) {
    return (l * 128 + h) ^ ((l & 7) << 3);
}

// ---------------------------------------------------------------------------
// P0a: per (lh,n): C', dtA cache, w, w^64, w^512 (all direct, no serial chain)
// ---------------------------------------------------------------------------
__global__ __launch_bounds__(256) void prep_params(const float* log_dt, const float* log_A_real,
                                                   const float* A_imag, const float* C_re,
                                                   const float* C_im, float* ws) {
    int idx = blockIdx.x * 256 + threadIdx.x;        // (lh,n)
    if (idx >= NL_ * H_ * N2_) return;
    int n  = idx & 31;
    int lh = idx >> 5;

    float dt  = expf(log_dt[lh]);
    float Are = -expf(log_A_real[idx]);
    float Aim = A_imag[idx];
    float dre = Are * dt, dim = Aim * dt;
    float er  = expf(dre);
    float sw, cw; sincosf(dim, &sw, &cw);
    float wre = er * cw, wim = er * sw;
    float nre = wre - 1.0f, nim = wim;
    float den = Are * Are + Aim * Aim;
    float qre = (nre * Are + nim * Aim) / den;
    float qim = (nim * Are - nre * Aim) / den;
    float cre = C_re[idx], cim = C_im[idx];

    float* cp  = ws + OFF_CP  + (size_t)lh * 64;
    float* w64 = ws + OFF_W64 + (size_t)lh * 64;
    float* w5  = ws + OFF_W5  + (size_t)lh * 64;
    cp[2 * n]     = cre * qre - cim * qim;
    cp[2 * n + 1] = cre * qim + cim * qre;
    *((float4*)(ws + OFF_DTA) + (size_t)lh * 32 + n) = make_float4(dre, dim, wre, wim);

    float e64 = expf(64.0f * dre);
    float s64, c64; sincosf(64.0f * dim, &s64, &c64);
    float ar = e64 * c64, ai = e64 * s64;
    w64[2 * n] = ar; w64[2 * n + 1] = ai;
    #pragma unroll
    for (int q = 0; q < 3; ++q) {
        float nr = ar * ar - ai * ai;
        float ni = 2.0f * ar * ai;
        ar = nr; ai = ni;
    }
    w5[2 * n] = ar; w5[2 * n + 1] = ai;
}

// ---------------------------------------------------------------------------
// P0b: per (lh,e,n): w^e direct -> T1F frag; w^{e+1} -> T2F frag
// ---------------------------------------------------------------------------
__global__ __launch_bounds__(256) void prep_pow(float* ws) {
    int idx = blockIdx.x * 256 + threadIdx.x;        // lh*2048 + e*32 + n
    int n  = idx & 31;
    int e  = (idx >> 5) & 63;
    int lh = idx >> 11;
    float4 dw = *((const float4*)(ws + OFF_DTA) + (size_t)lh * 32 + n);
    float ew = expf((float)e * dw.x);
    float sn, cs; sincosf((float)e * dw.y, &sn, &cs);
    float pr = ew * cs, pi = ew * sn;

    unsigned short* t1f = (unsigned short*)(ws + OFF_T1F) + (size_t)lh * 8192;
    unsigned short* t2f = (unsigned short*)(ws + OFF_T2F) + (size_t)lh * 8192;
    int k1 = 63 - e;                                 // T1F[k1][np] = w^e
    store_hl(t1f, (k1 >> 3) * 1024 + (2 * n) * 16 + (k1 & 7), pr);
    store_hl(t1f, (k1 >> 3) * 1024 + (2 * n + 1) * 16 + (k1 & 7), pi);
    float qr = pr * dw.z - pi * dw.w;                // w^{e+1}
    float qi = pr * dw.w + pi * dw.z;
    store_hl(t2f, ((2 * n) >> 3) * 1024 + e * 16 + ((2 * n) & 7), qr);
    store_hl(t2f, ((2 * n + 1) >> 3) * 1024 + e * 16 + ((2 * n + 1) & 7), qi);
}

// ---------------------------------------------------------------------------
// P0c: k[lh][s] = 2*Re( sum_n C'_n w_n^s ); w^s recomputed with the exact
// same expf/sincosf expressions as prep_pow; serial n-sum (round-10 order).
// ---------------------------------------------------------------------------
__global__ __launch_bounds__(256) void compute_k(float* ws) {
    int idx = blockIdx.x * 256 + threadIdx.x;        // (lh, s)
    if (idx >= NL_ * H_ * 64) return;
    int s  = idx & 63;
    int lh = idx >> 6;
    const float* cp = ws + OFF_CP + (size_t)lh * 64;
    const float4* dta = (const float4*)(ws + OFF_DTA) + (size_t)lh * 32;
    float acc = 0.0f;
    #pragma unroll 8
    for (int n = 0; n < 32; ++n) {
        float4 dw = dta[n];
        float ew = expf((float)s * dw.x);
        float sn, cs; sincosf((float)s * dw.y, &sn, &cs);
        acc += cp[2 * n] * (ew * cs) - cp[2 * n + 1] * (ew * sn);
    }
    ws[OFF_K + (size_t)lh * 64 + s] = 2.0f * acc;
}

// ---------------------------------------------------------------------------
// P0d: Toeplitz frag table TKF[s][tau] = (tau>=s) ? k[tau-s] : 0  (parallel)
// ---------------------------------------------------------------------------
__global__ __launch_bounds__(256) void prep_tkf(float* ws) {
    int idx = blockIdx.x * 256 + threadIdx.x;        // lh*4096 + s*64 + tau
    int tau = idx & 63;
    int s   = (idx >> 6) & 63;
    int lh  = idx >> 12;
    float v = (tau >= s) ? ws[OFF_K + (size_t)lh * 64 + (tau - s)] : 0.0f;
    unsigned short* dst = (unsigned short*)(ws + OFF_TKF) + (size_t)lh * 8192;
    store_hl(dst, (s >> 3) * 1024 + (s & 7) + tau * 16, v);
}

// ---------------------------------------------------------------------------
// P0e: conv_w -> bf16
// ---------------------------------------------------------------------------
__global__ __launch_bounds__(256) void prep_wbf(const float* conv_w, float* ws) {
    int i = blockIdx.x * 256 + threadIdx.x;
    ((unsigned short*)(ws + OFF_WB))[i] = f2bf(conv_w[i]);
}

// ---------------------------------------------------------------------------
// Encoder -> u bf16
// ---------------------------------------------------------------------------
__global__ __launch_bounds__(256) void encoder_kernel(const float* x, const float* enc_w,
                                                      const float* enc_b, float* ws) {
    __shared__ float wlds[H_ * DIN];
    __shared__ float blds[H_];
    int t  = threadIdx.x;
    int b  = blockIdx.x >> 4;
    int l0 = (blockIdx.x & 15) * 256;
    for (int i = t; i < H_ * DIN; i += 256) wlds[i] = enc_w[i];
    if (t < H_) blds[t] = enc_b[t];
    float xr[16];
    const float* xp = x + ((size_t)b * L_ + l0 + t) * DIN;
    #pragma unroll
    for (int d = 0; d < 16; ++d) xr[d] = xp[d];
    __syncthreads();
    unsigned short* u = (unsigned short*)(ws + OFF_U) + (size_t)b * H_ * L_ + l0 + t;
    for (int h = 0; h < H_; ++h) {
        float acc = blds[h];
        #pragma unroll
        for (int d = 0; d < 16; ++d) acc += xr[d] * wlds[h * 16 + d];
        u[(size_t)h * L_] = f2bf(acc);
    }
}

// ---------------------------------------------------------------------------
// S4D via bf16 MFMA (T tables hi/lo corrected; z/G pure bf16).
// One block per (b,h). Parallel 3-level cross-chunk scan.
// (round-10 structure: separate tex/bex arrays, no eg overlay)
// ---------------------------------------------------------------------------
__global__ __launch_bounds__(256) void s4d_mfma(const float* Dp, float* ws, int layer) {
    __shared__ unsigned short zsh[64 * ZP];   // z, then G (bf16)
    __shared__ float eg[64 * EP];             // E (f32)
    __shared__ float tex[8][64];              // octave totals (complex packed)
    __shared__ float bex[8][64];              // exclusive octave bases

    int t  = threadIdx.x;
    int b  = blockIdx.x >> 7;
    int h  = blockIdx.x & 127;
    int lh = layer * H_ + h;
    int w  = t >> 6;
    int l  = t & 63;
    int lr = l & 15;
    int lg = l >> 4;

    const unsigned short* ug = (const unsigned short*)(ws + OFF_U) + ((size_t)b * H_ + h) * L_;

    // stage z: straight bf16 copy (16 elements per thread)
    {
        int base = t * 16;
        int c = base >> 6, s0 = base & 63;
        *(u16x8*)&zsh[c * ZP + s0]     = *(const u16x8*)&ug[base];
        *(u16x8*)&zsh[c * ZP + s0 + 8] = *(const u16x8*)&ug[base + 8];
    }

    // preload B-frags (global, L2-hot): T1F + TKF, kblk 0/1
    const unsigned short* t1f = (const unsigned short*)(ws + OFF_T1F) + (size_t)lh * 8192;
    const unsigned short* tkf = (const unsigned short*)(ws + OFF_TKF) + (size_t)lh * 8192;
    const unsigned short* t2f = (const unsigned short*)(ws + OFF_T2F) + (size_t)lh * 8192;
    int bo = lg * 1024 + (w * 16 + lr) * 16;
    bf16x8 T1h0 = BCB(*(const u16x8*)&t1f[bo]);
    bf16x8 T1l0 = BCB(*(const u16x8*)&t1f[bo + 8]);
    bf16x8 T1h1 = BCB(*(const u16x8*)&t1f[bo + 4096]);
    bf16x8 T1l1 = BCB(*(const u16x8*)&t1f[bo + 4096 + 8]);
    bf16x8 TKh0 = BCB(*(const u16x8*)&tkf[bo]);
    bf16x8 TKl0 = BCB(*(const u16x8*)&tkf[bo + 8]);
    bf16x8 TKh1 = BCB(*(const u16x8*)&tkf[bo + 4096]);
    bf16x8 TKl1 = BCB(*(const u16x8*)&tkf[bo + 4096 + 8]);

    f32x4 accE[4], accC[4];
    #pragma unroll
    for (int ct = 0; ct < 4; ++ct) { accE[ct] = (f32x4)0.0f; accC[ct] = (f32x4)0.0f; }

    __syncthreads();

    // ---- Pass A: E = z x (T1h+T1l) ; Yconv = z x (TKh+TKl)
    #pragma unroll
    for (int ct = 0; ct < 4; ++ct) {
        int ar = (ct * 16 + lr) * ZP;
        bf16x8 ah0 = BCB(*(const u16x8*)&zsh[ar + lg * 8]);
        bf16x8 ah1 = BCB(*(const u16x8*)&zsh[ar + 32 + lg * 8]);
        accE[ct] = MFMA(ah0, T1h0, accE[ct]);
        accE[ct] = MFMA(ah0, T1l0, accE[ct]);
        accE[ct] = MFMA(ah1, T1h1, accE[ct]);
        accE[ct] = MFMA(ah1, T1l1, accE[ct]);
        accC[ct] = MFMA(ah0, TKh0, accC[ct]);
        accC[ct] = MFMA(ah0, TKl0, accC[ct]);
        accC[ct] = MFMA(ah1, TKh1, accC[ct]);
        accC[ct] = MFMA(ah1, TKl1, accC[ct]);
    }
    // write E (D-frag: row=(lg*4+r), col=lr)
    #pragma unroll
    for (int ct = 0; ct < 4; ++ct)
        #pragma unroll
        for (int r = 0; r < 4; ++r)
            eg[(ct * 16 + lg * 4 + r) * EP + w * 16 + lr] = accE[ct][r];

    // preload T2F frags; pre-extract epilogue z (zsh reused for G after)
    bf16x8 T2h0 = BCB(*(const u16x8*)&t2f[bo]);
    bf16x8 T2l0 = BCB(*(const u16x8*)&t2f[bo + 8]);
    bf16x8 T2h1 = BCB(*(const u16x8*)&t2f[bo + 4096]);
    bf16x8 T2l1 = BCB(*(const u16x8*)&t2f[bo + 4096 + 8]);
    float zep[16];
    #pragma unroll
    for (int ct = 0; ct < 4; ++ct)
        #pragma unroll
        for (int r = 0; r < 4; ++r) {
            int c = ct * 16 + lg * 4 + r, tau = w * 16 + lr;
            zep[ct * 4 + r] = bf2f(zsh[c * ZP + tau]);
        }
    __syncthreads();

    // ---- Parallel scan: thread = (n = t&31, oct = t>>5); 8 chunks each
    {
        int n   = t & 31;
        int oct = t >> 5;
        const float* cp   = ws + OFF_CP  + (size_t)lh * 64;
        const float* w64p = ws + OFF_W64 + (size_t)lh * 64;
        const float* w5p  = ws + OFF_W5  + (size_t)lh * 64;
        float cre = cp[2 * n], cim = cp[2 * n + 1];
        float wr  = w64p[2 * n], wi = w64p[2 * n + 1];
        float2 e[8];
        float sre = 0.f, sim = 0.f;
        #pragma unroll
        for (int j = 0; j < 8; ++j) {                 // local octave scan
            e[j] = *(const float2*)&eg[(8 * oct + j) * EP + 2 * n];
            float nr = fmaf(wr, sre, fmaf(-wi, sim, e[j].x));
            float ni = fmaf(wr, sim, fmaf(wi, sre, e[j].y));
            sre = nr; sim = ni;
        }
        *(float2*)&tex[oct][2 * n] = make_float2(sre, sim);
        __syncthreads();
        if (t < 32) {                                 // exclusive base scan over octaves
            float Wr = w5p[2 * n], Wi = w5p[2 * n + 1];
            float br = 0.f, bi = 0.f;
            #pragma unroll
            for (int o = 0; o < 8; ++o) {
                *(float2*)&bex[o][2 * n] = make_float2(br, bi);
                float2 T = *(const float2*)&tex[o][2 * n];
                float nr = fmaf(Wr, br, fmaf(-Wi, bi, T.x));
                float ni = fmaf(Wr, bi, fmaf(Wi, br, T.y));
                br = nr; bi = ni;
            }
        }
        __syncthreads();
        float2 Sb = *(const float2*)&bex[oct][2 * n];
        sre = Sb.x; sim = Sb.y;
        #pragma unroll
        for (int j = 0; j < 8; ++j) {                 // replay: emit G bf16 (packed u32)
            int c = 8 * oct + j;
            float gre = 2.0f * (cre * sre - cim * sim);
            float gim = -2.0f * (cre * sim + cim * sre);
            unsigned int pk = (unsigned int)f2bf(gre) | ((unsigned int)f2bf(gim) << 16);
            *(unsigned int*)&zsh[c * ZP + 2 * n] = pk;
            float nr = fmaf(wr, sre, fmaf(-wi, sim, e[j].x));
            float ni = fmaf(wr, sim, fmaf(wi, sre, e[j].y));
            sre = nr; sim = ni;
        }
    }
    float Dh = Dp[lh];
    __syncthreads();

    // ---- Pass B: Y += G x (T2h+T2l)
    #pragma unroll
    for (int ct = 0; ct < 4; ++ct) {
        int ar = (ct * 16 + lr) * ZP;
        bf16x8 gh0 = BCB(*(const u16x8*)&zsh[ar + lg * 8]);
        bf16x8 gh1 = BCB(*(const u16x8*)&zsh[ar + 32 + lg * 8]);
        accC[ct] = MFMA(gh0, T2h0, accC[ct]);
        accC[ct] = MFMA(gh0, T2l0, accC[ct]);
        accC[ct] = MFMA(gh1, T2h1, accC[ct]);
        accC[ct] = MFMA(gh1, T2l1, accC[ct]);
    }

    // ---- epilogue: + D*z, tanh-GELU, store y bf16
    unsigned short* yb = (unsigned short*)(ws + OFF_Y) + ((size_t)b * H_ + h) * L_;
    #pragma unroll
    for (int ct = 0; ct < 4; ++ct)
        #pragma unroll
        for (int r = 0; r < 4; ++r) {
            float acc = fmaf(Dh, zep[ct * 4 + r], accC[ct][r]);
            yb[(ct * 16 + lg * 4 + r) * 64 + w * 16 + lr] = f2bf(gelu_f(acc));
        }
}

// ---------------------------------------------------------------------------
// Channel mix via bf16 MFMA + GLU + residual(bf16) + LN -> u bf16.
// If last!=0, also write emb output f32 [b][l][h] directly from registers.
// ---------------------------------------------------------------------------
__global__ __launch_bounds__(256) void conv_glu_ln_mfma(const float* conv_b, const float* ln_w,
                                                        const float* ln_b, float* ws, float* outp,
                                                        int layer, int last) {
    __shared__ unsigned short yt[64 * 128];   // [l][h], swizzled
    __shared__ float wsum[4][64];
    __shared__ float wsq[4][64];

    int t    = threadIdx.x;
    int b    = blockIdx.x >> 6;
    int l0   = (blockIdx.x & 63) * 64;
    int w    = t >> 6;
    int lam  = t & 63;
    int g4   = lam >> 4;
    int ncol = lam & 15;

    const unsigned short* yg = (const unsigned short*)(ws + OFF_Y) + (size_t)b * H_ * L_;
    const unsigned short* wb = (const unsigned short*)(ws + OFF_WB) + (size_t)layer * 256 * 128;

    // ---- stage y transposed: column loads (coalesced across lanes), b128 writes
    {
        int ll = t & 63;
        int hb = (t >> 6) * 32;
        const unsigned short* ycol = yg + l0 + ll;
        #pragma unroll
        for (int g = 0; g < 4; ++g) {
            u16x8 tmp;
            #pragma unroll
            for (int i = 0; i < 8; ++i)
                tmp[i] = ycol[(size_t)(hb + g * 8 + i) * L_];
            *(u16x8*)&yt[yswz(ll, hb + g * 8)] = tmp;
        }
    }

    // ---- bias init
    const float* cb = conv_b + layer * 256;
    f32x4 dA[2][4], dG[2][4];
    #pragma unroll
    for (int oa = 0; oa < 2; ++oa) {
        int ba = w * 32 + oa * 16 + g4 * 4;
        f32x4 bA, bG;
        #pragma unroll
        for (int r = 0; r < 4; ++r) { bA[r] = cb[ba + r]; bG[r] = cb[128 + ba + r]; }
        #pragma unroll
        for (int nt = 0; nt < 4; ++nt) { dA[oa][nt] = bA; dG[oa][nt] = bG; }
    }
    __syncthreads();

    // ---- K loop: per kt, A-frags from global (L2), B-frags via b128 LDS reads
    #pragma unroll
    for (int kt = 0; kt < 4; ++kt) {
        bf16x8 aAk[2], aGk[2];
        #pragma unroll
        for (int oa = 0; oa < 2; ++oa) {
            int oA = w * 32 + oa * 16 + ncol;
            aAk[oa] = BCB(*(const u16x8*)&wb[(size_t)oA * 128 + kt * 32 + g4 * 8]);
            aGk[oa] = BCB(*(const u16x8*)&wb[(size_t)(128 + oA) * 128 + kt * 32 + g4 * 8]);
        }
        #pragma unroll
        for (int nt = 0; nt < 4; ++nt) {
            bf16x8 bfr = BCB(*(const u16x8*)&yt[yswz(nt * 16 + ncol, kt * 32 + g4 * 8)]);
            #pragma unroll
            for (int oa = 0; oa < 2; ++oa) {
                dA[oa][nt] = MFMA(aAk[oa], bfr, dA[oa][nt]);
                dG[oa][nt] = MFMA(aGk[oa], bfr, dG[oa][nt]);
            }
        }
    }

    // ---- epilogue: GLU + residual (bf16); LN over 128 channels
    unsigned short* ug = (unsigned short*)(ws + OFF_U) + (size_t)b * H_ * L_;
    float lwv[2][4], lbv[2][4];
    #pragma unroll
    for (int oa = 0; oa < 2; ++oa)
        #pragma unroll
        for (int r = 0; r < 4; ++r) {
            int hh = layer * 128 + w * 32 + oa * 16 + g4 * 4 + r;
            lwv[oa][r] = ln_w[hh]; lbv[oa][r] = ln_b[hh];
        }

    #pragma unroll
    for (int nt = 0; nt < 4; ++nt) {
        int l = l0 + nt * 16 + ncol;
        float s = 0.f, q = 0.f;
        #pragma unroll
        for (int oa = 0; oa < 2; ++oa)
            #pragma unroll
            for (int r = 0; r < 4; ++r) {
                int h = w * 32 + oa * 16 + g4 * 4 + r;
                float a = dA[oa][nt][r], g = dG[oa][nt][r];
                float val = a / (1.0f + __expf(-g)) + bf2f(ug[(size_t)h * L_ + l]);
                dA[oa][nt][r] = val;
                s += val; q += val * val;
            }
        s += __shfl_xor(s, 16, 64); q += __shfl_xor(q, 16, 64);
        s += __shfl_xor(s, 32, 64); q += __shfl_xor(q, 32, 64);
        if (g4 == 0) { wsum[w][nt * 16 + ncol] = s; wsq[w][nt * 16 + ncol] = q; }
    }
    __syncthreads();

    #pragma unroll
    for (int nt = 0; nt < 4; ++nt) {
        int ll = nt * 16 + ncol;
        int l  = l0 + ll;
        float S = wsum[0][ll] + wsum[1][ll] + wsum[2][ll] + wsum[3][ll];
        float Q = wsq[0][ll] + wsq[1][ll] + wsq[2][ll] + wsq[3][ll];
        float mu = S * (1.0f / 128.0f);
        float var = Q * (1.0f / 128.0f) - mu * mu;
        float rstd = rsqrtf(var + 1e-5f);
        #pragma unroll
        for (int oa = 0; oa < 2; ++oa) {
            float vv[4];
            #pragma unroll
            for (int r = 0; r < 4; ++r) {
                int h = w * 32 + oa * 16 + g4 * 4 + r;
                float v = (dA[oa][nt][r] - mu) * rstd * lwv[oa][r] + lbv[oa][r];
                vv[r] = v;
                ug[(size_t)h * L_ + l] = f2bf(v);
            }
            if (last) {
                // emb out[b][l][h..h+3] f32; g4 quads fill full 64B lines
                *(float4*)&outp[((size_t)(b * L_ + l)) * H_ + w * 32 + oa * 16 + g4 * 4] =
                    make_float4(vv[0], vv[1], vv[2], vv[3]);
            }
        }
    }
}

// ---------------------------------------------------------------------------
// Mean-pool over L per (b,h)
// ---------------------------------------------------------------------------
__global__ __launch_bounds__(256) void pool_kernel(float* ws) {
    int bh = blockIdx.x;
    const unsigned short* u = (const unsigned short*)(ws + OFF_U) + (size_t)bh * L_;
    int t = threadIdx.x;
    float s = 0.0f;
    for (int i = t; i < L_; i += 256) s += bf2f(u[i]);
    #pragma unroll
    for (int m = 1; m <= 32; m <<= 1) s += __shfl_xor(s, m, 64);
    __shared__ float part[4];
    if ((t & 63) == 0) part[t >> 6] = s;
    __syncthreads();
    if (t == 0) ws[OFF_PL + bh] = (part[0] + part[1] + part[2] + part[3]) * (1.0f / L_);
}

// ---------------------------------------------------------------------------
// Decoder (f32 out)
// ---------------------------------------------------------------------------
__global__ __launch_bounds__(256) void decode_kernel(const float* dec_w, const float* dec_b,
                                                     const float* ws, float* out) {
    int t = threadIdx.x;
    int b = t >> 3, o = t & 7;
    const float* p = ws + OFF_PL + b * 128;
    float acc = dec_b[o];
    for (int h = 0; h < 128; ++h) acc += p[h] * dec_w[o * 128 + h];
    out[t] = 1.0f / (1.0f + __expf(-acc));
}

// ---------------------------------------------------------------------------
extern "C" void kernel_launch(void* const* d_in, const int* in_sizes, int n_in,
                              void* d_out, int out_size, void* d_ws, size_t ws_size,
                              hipStream_t stream) {
    const float* x          = (const float*)d_in[0];
    const float* enc_w      = (const float*)d_in[2];
    const float* enc_b      = (const float*)d_in[3];
    const float* log_dt     = (const float*)d_in[4];
    const float* log_A_real = (const float*)d_in[5];
    const float* A_imag     = (const float*)d_in[6];
    const float* C_re       = (const float*)d_in[7];
    const float* C_im       = (const float*)d_in[8];
    const float* Dp         = (const float*)d_in[9];
    const float* conv_w     = (const float*)d_in[10];
    const float* conv_b     = (const float*)d_in[11];
    const float* ln_w       = (const float*)d_in[12];
    const float* ln_b       = (const float*)d_in[13];
    const float* dec_w      = (const float*)d_in[14];
    const float* dec_b      = (const float*)d_in[15];
    float* ws = (float*)d_ws;
    float* out = (float*)d_out;

    prep_params<<<(NL_ * H_ * N2_ + 255) / 256, 256, 0, stream>>>(log_dt, log_A_real, A_imag,
                                                                  C_re, C_im, ws);
    prep_pow<<<(NL_ * H_ * N2_ * 64) / 256, 256, 0, stream>>>(ws);
    compute_k<<<(NL_ * H_ * 64 + 255) / 256, 256, 0, stream>>>(ws);
    prep_tkf<<<(NL_ * H_ * 64 * 64) / 256, 256, 0, stream>>>(ws);
    prep_wbf<<<(NL_ * 256 * 128) / 256, 256, 0, stream>>>(conv_w, ws);
    encoder_kernel<<<B_ * (L_ / 256), 256, 0, stream>>>(x, enc_w, enc_b, ws);
    for (int l = 0; l < NL_; ++l) {
        s4d_mfma<<<B_ * H_, 256, 0, stream>>>(Dp, ws, l);
        conv_glu_ln_mfma<<<B_ * (L_ / 64), 256, 0, stream>>>(conv_b, ln_w, ln_b, ws,
                                                             out + 256, l, l == NL_ - 1);
    }
    pool_kernel<<<B_ * H_, 256, 0, stream>>>(ws);
    decode_kernel<<<1, 256, 0, stream>>>(dec_w, dec_b, ws, out);
}